// Round 2
// 1055.289 us; speedup vs baseline: 1.1486x; 1.1486x over previous
//
#include <hip/hip_runtime.h>
#include <hip/hip_bf16.h>
#include <math.h>

// TitanLongTermMemory — round 9 (resubmit; r9 bench hit GPUAcquisitionTimeout).
// r8 rocprof: the two M=4 VALU gemm_kernel dispatches (kp, vp) are the top-5
// at 82.5us EACH (grid=16 blocks, 64 serialized K-iters, occupancy 0.66%).
// Replaced with one fused wave-per-column GEMV (2048 waves, coalesced bf16x8
// weight reads, L1-hot pm, butterfly reduce). Expected: 1212 -> ~1050us.

using bf16 = __hip_bfloat16;

typedef __attribute__((ext_vector_type(8))) short bf16x8;
typedef __attribute__((ext_vector_type(4))) float f32x4;

__device__ __forceinline__ float ldf(const bf16* p) { return __bfloat162float(*p); }
__device__ __forceinline__ float ldf(const float* p) { return *p; }
__device__ __forceinline__ void stf(bf16* p, float v) { *p = __float2bfloat16(v); }
__device__ __forceinline__ void stf(float* p, float v) { *p = v; }
__device__ __forceinline__ float b2f(const bf16& b) { return __bfloat162float(b); }
__device__ __forceinline__ float bsf(short s) {
  union { unsigned u; float f; } cv;
  cv.u = (unsigned)(unsigned short)s << 16;
  return cv.f;
}

enum { ACT_NONE = 0, ACT_SILU = 1, ACT_SIGMOID = 2, ACT_GATE = 3 };

__global__ void detect_kernel(const unsigned short* g, int* flag) {
  if (threadIdx.x == 0) *flag = (g[0] != 0) ? 1 : 0;
}

// ---- single fused dtype-normalize for all non-x inputs ----------------------
struct ConvArgs {
  const void* src[29];
  bf16* dst[29];
  int n[29];
  int bstart[30];
};

__global__ __launch_bounds__(256) void convall_kernel(ConvArgs a, const int* __restrict__ flag) {
  int b = blockIdx.x;
  int ti = 0;
  while (ti < 28 && b >= a.bstart[ti + 1]) ++ti;
  int i = (b - a.bstart[ti]) * 256 + threadIdx.x;
  if (i >= a.n[ti]) return;
  if (*flag) a.dst[ti][i] = ((const bf16*)a.src[ti])[i];
  else a.dst[ti][i] = __float2bfloat16(((const float*)a.src[ti])[i]);
}

__global__ __launch_bounds__(256) void conv_kernel(
    const void* __restrict__ src, bf16* __restrict__ dst, int n, size_t src_off,
    const int* __restrict__ flag) {
  int i = blockIdx.x * 256 + threadIdx.x;
  if (i >= n) return;
  if (*flag) dst[i] = ((const bf16*)src)[src_off + i];
  else dst[i] = __float2bfloat16(((const float*)src)[src_off + i]);
}

// bias3 = [0(1024) | bk(1024) | bv(1024)]
__global__ __launch_bounds__(256) void pack_bias3(
    const bf16* __restrict__ bk, const bf16* __restrict__ bv, bf16* __restrict__ o) {
  int j = blockIdx.x * 256 + threadIdx.x;
  if (j >= 3072) return;
  float v = 0.f;
  if (j >= 2048) v = b2f(bv[j - 2048]);
  else if (j >= 1024) v = b2f(bk[j - 1024]);
  o[j] = __float2bfloat16(v);
}

// 64x64-tile transpose: dst[n][k] = src[k][n], 1024x1024
__global__ __launch_bounds__(256) void transpose_kernel(
    const bf16* __restrict__ srcb, bf16* __restrict__ dstb) {
  __shared__ unsigned short t[64][72];  // 144B row stride (16B-aligned)
  const unsigned short* src = (const unsigned short*)srcb;
  unsigned short* dst = (unsigned short*)dstb;
  const int r0 = blockIdx.y * 64, c0 = blockIdx.x * 64;
  for (int e = threadIdx.x; e < 64 * 8; e += 256) {
    int r = e >> 3, c8 = e & 7;
    uint4 v = *(const uint4*)(src + (size_t)(r0 + r) * 1024 + c0 + c8 * 8);
    *(uint4*)&t[r][c8 * 8] = v;
  }
  __syncthreads();
  for (int e = threadIdx.x; e < 64 * 8; e += 256) {
    int c = e >> 3, r8 = (e & 7) * 8;
    unsigned short v[8];
#pragma unroll
    for (int j = 0; j < 8; ++j) v[j] = t[r8 + j][c];
    *(uint4*)(dst + (size_t)(c0 + c) * 1024 + r0 + r8) = *(uint4*)v;
  }
}

// ---- fused kp/vp GEMV: out cols 0..1023 -> kp (Wkk,bk), 1024..2047 -> vp ----
// out[m][c] = sum_k pm[m][k] * W[c][k] + bias; one wave per column.
__global__ __launch_bounds__(256) void kpvp_kernel(
    const bf16* __restrict__ pmb, const bf16* __restrict__ Wq3b,
    const bf16* __restrict__ bias3b, bf16* __restrict__ kp, bf16* __restrict__ vp)
{
  const short* pm = (const short*)pmb;
  const short* W = (const short*)Wq3b;
  const int wave = threadIdx.x >> 6, lane = threadIdx.x & 63;
  const int c = blockIdx.x * 4 + wave;  // 0..2047
  const short* wrow = W + (size_t)(1024 + c) * 1024 + lane * 16;
  const bf16x8 w0 = *(const bf16x8*)wrow;
  const bf16x8 w1 = *(const bf16x8*)(wrow + 8);
  float acc[4];
#pragma unroll
  for (int m = 0; m < 4; ++m) {
    const short* prow = pm + m * 1024 + lane * 16;
    const bf16x8 p0 = *(const bf16x8*)prow;
    const bf16x8 p1 = *(const bf16x8*)(prow + 8);
    float s = 0.f;
#pragma unroll
    for (int j = 0; j < 8; ++j) s += bsf(w0[j]) * bsf(p0[j]) + bsf(w1[j]) * bsf(p1[j]);
    acc[m] = s;
  }
#pragma unroll
  for (int d = 1; d < 64; d <<= 1) {
#pragma unroll
    for (int m = 0; m < 4; ++m) acc[m] += __shfl_xor(acc[m], d);
  }
  if (lane == 0) {
    const float bv = b2f(bias3b[1024 + c]);
    bf16* dst = (c < 1024) ? (kp + c) : (vp + (c - 1024));
#pragma unroll
    for (int m = 0; m < 4; ++m) stf(dst + m * 1024, acc[m] + bv);
  }
}

// ---------------- MFMA GEMM: C[M,N] = act(A[M,K] @ B[N,K]^T + bias) ----------
__device__ __forceinline__ void gl_lds16(const short* g, short* l) {
  __builtin_amdgcn_global_load_lds(
      (const __attribute__((address_space(1))) void*)g,
      (__attribute__((address_space(3))) void*)l, 16, 0, 0);
}

// ACT_GATE epilogue: t = sigmoid(acc+bias) * ao[m,n] + x[m,n]; C bf16.
template <typename TC, int ACT, bool HAS_BIAS>
__global__ __launch_bounds__(256) void mgemm(
    const bf16* __restrict__ Ab, const bf16* __restrict__ Bw,
    const bf16* __restrict__ bias, TC* __restrict__ C,
    int M, int N, int K, int lda, int ldc,
    const bf16* __restrict__ ao, const void* __restrict__ xsrc, size_t xoff,
    const int* __restrict__ flag)
{
  __shared__ short As[128 * 32];
  __shared__ short Bs[128 * 32];
  const short* A = (const short*)Ab;
  const short* B = (const short*)Bw;
  const int tid = threadIdx.x;
  const int m0 = blockIdx.y * 128, n0 = blockIdx.x * 128;
  const int wave = tid >> 6, lane = tid & 63;
  const int wm = (wave & 1) * 64, wn = (wave >> 1) * 64;
  const int fm = lane & 15;
  const int fk = (lane >> 4) * 8;

  const int srow = tid >> 2, scol = (tid & 3) * 8;
  const short* gA0 = A + (size_t)(m0 + srow) * lda + scol;
  const short* gA1 = A + (size_t)(m0 + 64 + srow) * lda + scol;
  const short* gB0 = B + (size_t)(n0 + srow) * K + scol;
  const short* gB1 = B + (size_t)(n0 + 64 + srow) * K + scol;
  short* lA0 = As + tid * 8;
  short* lA1 = As + (256 + tid) * 8;
  short* lB0 = Bs + tid * 8;
  short* lB1 = Bs + (256 + tid) * 8;

  f32x4 acc[4][4] = {};

  for (int k0 = 0; k0 < K; k0 += 32) {
    gl_lds16(gA0 + k0, lA0);
    gl_lds16(gA1 + k0, lA1);
    gl_lds16(gB0 + k0, lB0);
    gl_lds16(gB1 + k0, lB1);
    __syncthreads();
    bf16x8 af[4], bfr[4];
#pragma unroll
    for (int i = 0; i < 4; ++i)
      af[i] = *(const bf16x8*)&As[(wm + i * 16 + fm) * 32 + fk];
#pragma unroll
    for (int j = 0; j < 4; ++j)
      bfr[j] = *(const bf16x8*)&Bs[(wn + j * 16 + fm) * 32 + fk];
#pragma unroll
    for (int i = 0; i < 4; ++i)
#pragma unroll
      for (int j = 0; j < 4; ++j)
        acc[i][j] = __builtin_amdgcn_mfma_f32_16x16x32_bf16(af[i], bfr[j], acc[i][j], 0, 0, 0);
    __syncthreads();
  }

  const int rg = (lane >> 4) * 4;
#pragma unroll
  for (int i = 0; i < 4; ++i) {
#pragma unroll
    for (int j = 0; j < 4; ++j) {
      const int n = n0 + wn + j * 16 + fm;
      float bv = 0.f;
      if (HAS_BIAS) bv = b2f(bias[n]);
#pragma unroll
      for (int r = 0; r < 4; ++r) {
        const int m = m0 + wm + i * 16 + rg + r;
        float v = acc[i][j][r] + bv;
        if (ACT == ACT_SILU) v = v / (1.f + __expf(-v));
        if (ACT == ACT_SIGMOID) v = 1.f / (1.f + __expf(-v));
        if (ACT == ACT_GATE) {
          v = 1.f / (1.f + __expf(-v));
          const size_t e = (size_t)m * 1024 + n;
          const float xv = *flag ? b2f(((const bf16*)xsrc)[xoff + e])
                                 : ((const float*)xsrc)[xoff + e];
          v = v * b2f(ao[e]) + xv;
        }
        stf(&C[(size_t)m * ldc + n], v);
      }
    }
  }
}

// Row LayerNorm over width W; optional post-LN add of a bf16 vector.
template <typename TI, typename TO, bool ADD, int W, int BS>
__global__ __launch_bounds__(BS) void ln_kernel(
    const TI* __restrict__ in, const bf16* __restrict__ g, const bf16* __restrict__ b,
    const bf16* __restrict__ addv, TO* __restrict__ out, int ldin)
{
  __shared__ float red[BS];
  const int row = blockIdx.x;
  const TI* rin = in + (size_t)row * ldin;
  TO* rout = out + (size_t)row * W;
  const int NP = W / BS;
  float v[NP];
  float s = 0.f;
#pragma unroll
  for (int i = 0; i < NP; ++i) { v[i] = ldf(&rin[threadIdx.x + i * BS]); s += v[i]; }
  red[threadIdx.x] = s; __syncthreads();
  for (int o = BS / 2; o > 0; o >>= 1) {
    if (threadIdx.x < o) red[threadIdx.x] += red[threadIdx.x + o];
    __syncthreads();
  }
  const float mean = red[0] / W;
  __syncthreads();
  float sq = 0.f;
#pragma unroll
  for (int i = 0; i < NP; ++i) { float d = v[i] - mean; sq += d * d; }
  red[threadIdx.x] = sq; __syncthreads();
  for (int o = BS / 2; o > 0; o >>= 1) {
    if (threadIdx.x < o) red[threadIdx.x] += red[threadIdx.x + o];
    __syncthreads();
  }
  const float rstd = rsqrtf(red[0] / W + 1e-5f);
#pragma unroll
  for (int i = 0; i < NP; ++i) {
    int c = threadIdx.x + i * BS;
    float o_ = (v[i] - mean) * rstd * b2f(g[c]) + b2f(b[c]);
    if (ADD) o_ += b2f(addv[c]);
    stf(&rout[c], o_);
  }
}

// ---------------- MFMA attention (r7 structure + source strides) ------------
__global__ __launch_bounds__(512) void attn_kernel(
    const bf16* __restrict__ qg, const bf16* __restrict__ krv, int str_r,
    const bf16* __restrict__ kxv, int str_x, const bf16* __restrict__ kpg,
    const bf16* __restrict__ vpg, bf16* __restrict__ outg)
{
  __shared__ short qs[4 * 64 * 32];
  __shared__ short ksl[4 * 144 * 32];
  __shared__ short vt[128 * 168];
  __shared__ short pl[64 * 168];

  const int tid = threadIdx.x;
  const int seg = blockIdx.x >> 3, h = blockIdx.x & 7;
  const unsigned short* q = (const unsigned short*)qg;
  const unsigned short* kv_r = (const unsigned short*)krv + (size_t)seg * 64 * str_r + h * 128;
  const unsigned short* kv_x = (const unsigned short*)kxv + (size_t)seg * 64 * str_x + h * 128;
  const unsigned short* kp = (const unsigned short*)kpg;
  const unsigned short* vp = (const unsigned short*)vpg;
  const size_t qbase = (size_t)seg * 64 * 1024 + h * 128;

  for (int ch = tid; ch < 64 * 16; ch += 512) {
    int row = ch >> 4, k8 = ch & 15;
    uint4 v = *(const uint4*)(q + qbase + (size_t)row * 1024 + k8 * 8);
    *(uint4*)&qs[((k8 >> 2) * 64 + row) * 32 + (k8 & 3) * 8] = v;
  }
  for (int ch = tid; ch < 132 * 16; ch += 512) {
    int t = ch >> 4, k8 = ch & 15;
    const unsigned short* src;
    if (t < 64) src = kv_r + (size_t)t * str_r;
    else if (t < 68) src = kp + (size_t)(t - 64) * 1024 + h * 128;
    else src = kv_x + (size_t)(t - 68) * str_x;
    uint4 v = *(const uint4*)(src + k8 * 8);
    *(uint4*)&ksl[((k8 >> 2) * 144 + t) * 32 + (k8 & 3) * 8] = v;
  }
  __syncthreads();

  const int wave = tid >> 6, lane = tid & 63;
  const int fm = lane & 15, fq = lane >> 4;

  if (wave < 4) {
    const int s0 = wave * 16;
    f32x4 acc[10];
#pragma unroll
    for (int tt = 0; tt < 10; ++tt) acc[tt] = (f32x4){0.f, 0.f, 0.f, 0.f};
#pragma unroll
    for (int kb = 0; kb < 4; ++kb) {
      const bf16x8 a = *(const bf16x8*)&qs[(kb * 64 + s0 + fm) * 32 + fq * 8];
#pragma unroll
      for (int tt = 0; tt < 9; ++tt) {
        const bf16x8 b = *(const bf16x8*)&ksl[(kb * 144 + tt * 16 + fm) * 32 + fq * 8];
        acc[tt] = __builtin_amdgcn_mfma_f32_16x16x32_bf16(a, b, acc[tt], 0, 0, 0);
      }
    }
    const float scale = 0.08838834764831845f;
#pragma unroll
    for (int r = 0; r < 4; ++r) {
      float m = -3.0e38f;
#pragma unroll
      for (int tt = 0; tt < 9; ++tt) {
        int t = tt * 16 + fm;
        if (t < 132) m = fmaxf(m, acc[tt][r] * scale);
      }
      for (int d = 1; d < 16; d <<= 1) m = fmaxf(m, __shfl_xor(m, d));
      float e[10];
      float sum = 0.f;
#pragma unroll
      for (int tt = 0; tt < 10; ++tt) {
        int t = tt * 16 + fm;
        float ev = 0.f;
        if (t < 132) ev = __expf(acc[tt][r] * scale - m);
        e[tt] = ev; sum += ev;
      }
      for (int d = 1; d < 16; d <<= 1) sum += __shfl_xor(sum, d);
      const float inv = 1.f / sum;
      const int s = s0 + fq * 4 + r;
#pragma unroll
      for (int tt = 0; tt < 10; ++tt) {
        bf16 pv = __float2bfloat16(e[tt] * inv);
        pl[s * 168 + tt * 16 + fm] = *(const short*)&pv;
      }
    }
  } else {
    for (int ch = tid - 256; ch < 132 * 32; ch += 256) {
      int t = ch >> 5, d4 = (ch & 31) * 4;
      const unsigned short* src;
      if (t < 64) src = kv_r + 1024 + (size_t)t * str_r;
      else if (t < 68) src = vp + (size_t)(t - 64) * 1024 + h * 128;
      else src = kv_x + 1024 + (size_t)(t - 68) * str_x;
      uint2 w = *(const uint2*)(src + d4);
      vt[(d4 + 0) * 168 + t] = (short)(w.x & 0xffffu);
      vt[(d4 + 1) * 168 + t] = (short)(w.x >> 16);
      vt[(d4 + 2) * 168 + t] = (short)(w.y & 0xffffu);
      vt[(d4 + 3) * 168 + t] = (short)(w.y >> 16);
    }
    for (int ch = tid - 256; ch < 128 * 32; ch += 256) {
      int d = ch >> 5, tp = 132 + (ch & 31);
      vt[d * 168 + tp] = 0;
    }
  }
  __syncthreads();

  const int dt = wave;
  bf16x8 af[5];
#pragma unroll
  for (int kb = 0; kb < 5; ++kb)
    af[kb] = *(const bf16x8*)&vt[(dt * 16 + fm) * 168 + kb * 32 + fq * 8];
#pragma unroll
  for (int st = 0; st < 4; ++st) {
    f32x4 o = (f32x4){0.f, 0.f, 0.f, 0.f};
#pragma unroll
    for (int kb = 0; kb < 5; ++kb) {
      const bf16x8 bp = *(const bf16x8*)&pl[(st * 16 + fm) * 168 + kb * 32 + fq * 8];
      o = __builtin_amdgcn_mfma_f32_16x16x32_bf16(af[kb], bp, o, 0, 0, 0);
    }
    const int s = st * 16 + fm;
    bf16 b0 = __float2bfloat16(o[0]), b1 = __float2bfloat16(o[1]);
    bf16 b2 = __float2bfloat16(o[2]), b3 = __float2bfloat16(o[3]);
    uint2 w;
    w.x = ((unsigned)(*(unsigned short*)&b1) << 16) | (*(unsigned short*)&b0);
    w.y = ((unsigned)(*(unsigned short*)&b3) << 16) | (*(unsigned short*)&b2);
    *(uint2*)((unsigned short*)outg + qbase + (size_t)s * 1024 + dt * 16 + fq * 4) = w;
  }
}

extern "C" void kernel_launch(void* const* d_in, const int* in_sizes, int n_in,
                              void* d_out, int out_size, void* d_ws, size_t ws_size,
                              hipStream_t stream)
{
  (void)n_in; (void)out_size;
  const int R = 16384, Cd = 1024, Md = 128;

  char* ws = (char*)d_ws;
  size_t off = 0;
  auto alloc = [&](size_t bytes) -> void* {
    void* p = ws + off;
    off += (bytes + 255) & ~(size_t)255;
    return p;
  };

  int* flag = (int*)alloc(256);
  // packed projection weights [Wq | Wkk | Wvv] rows (3072 x 1024)
  bf16* Wq3   = (bf16*)alloc((size_t)3072 * Cd * sizeof(bf16));
  bf16* bias3 = (bf16*)alloc(3072 * sizeof(bf16));
  bf16* WkT   = (bf16*)alloc((size_t)Cd * Cd * sizeof(bf16));
  bf16* WvT   = (bf16*)alloc((size_t)Cd * Cd * sizeof(bf16));
  bf16* kp    = (bf16*)alloc((size_t)4 * Cd * sizeof(bf16));
  bf16* vp    = (bf16*)alloc((size_t)4 * Cd * sizeof(bf16));
  bf16* nb[30];
  nb[0] = nullptr;
  for (int i = 1; i < 30; ++i) nb[i] = (bf16*)alloc((size_t)in_sizes[i] * sizeof(bf16));
  nb[2] = Wq3;  // Wq converts straight into the packed block (rows 0..1023)
  const size_t fixed_end = off;

  // balanced chunk sizing; per-row scratch = 16896 B
  size_t avail = (ws_size > fixed_end + (1u << 20)) ? (ws_size - fixed_end - (1u << 20)) : 0;
  int crmax = (int)(avail / 16896);
  if (crmax > R) crmax = R;
  if (crmax < 128) crmax = 128;
  int nch = (R + crmax - 1) / crmax;
  int CR = ((R / nch + 127) / 128) * 128;
  while (CR * nch < R) CR += 128;

  const size_t RB = (size_t)CR * Cd * sizeof(bf16);
  bf16* Xc  = (bf16*)alloc(RB);              // x(bf16) -> attn out -> t
  bf16* QS3 = (bf16*)alloc(3 * RB);          // [q_seg | k_x | v_x]
  bf16* h1b = (bf16*)alloc((size_t)CR * Md * sizeof(bf16));
  bf16* h2b = (bf16*)alloc((size_t)CR * Md * sizeof(bf16));
  bf16* Bb  = (bf16*)alloc(RB);              // retrieved -> ao
  bf16* KVr = (bf16*)alloc(2 * RB);          // [k_r | v_r]
  bf16* Cc  = (bf16*)alloc(RB);              // q -> gin

  dim3 blk(256);
  auto g128 = [](int M_, int N_) { return dim3((unsigned)(N_ / 128), (unsigned)(M_ / 128)); };

  // ---- preamble ----
  detect_kernel<<<1, 64, 0, stream>>>((const unsigned short*)d_in[24], flag);
  {
    ConvArgs a;
    int bs = 0;
    for (int i = 1; i < 30; ++i) {
      a.src[i - 1] = d_in[i];
      a.dst[i - 1] = nb[i];
      a.n[i - 1] = in_sizes[i];
      a.bstart[i - 1] = bs;
      bs += (in_sizes[i] + 255) / 256;
    }
    a.bstart[29] = bs;
    convall_kernel<<<dim3((unsigned)bs), blk, 0, stream>>>(a, flag);
  }
  const bf16 *pm = nb[1], *Wk = nb[3], *Wv = nb[4];
  const bf16 *mem_W1 = nb[5], *mem_b1 = nb[6], *ln1g = nb[7], *ln1b = nb[8];
  const bf16 *mem_W2 = nb[9], *mem_b2 = nb[10], *ln2g = nb[11], *ln2b = nb[12];
  const bf16 *mem_oW = nb[13], *mem_ob = nb[14], *mstate = nb[15];
  const bf16 *mhaWq = nb[16], *mhabq = nb[17], *mhaWk = nb[18], *mhabk = nb[19];
  const bf16 *mhaWv = nb[20], *mhabv = nb[21], *mhaWo = nb[22], *mhabo = nb[23];
  const bf16 *gn_g = nb[24], *gn_b = nb[25], *gateW = nb[26], *gateb = nb[27];
  const bf16 *outW = nb[28], *outb = nb[29];
  bf16* Wkk = Wq3 + (size_t)1024 * Cd;
  bf16* Wvv = Wq3 + (size_t)2048 * Cd;

  transpose_kernel<<<dim3(16, 16), blk, 0, stream>>>(Wk, WkT);
  transpose_kernel<<<dim3(16, 16), blk, 0, stream>>>(Wv, WvT);
  mgemm<bf16, ACT_NONE, false><<<g128(Cd, Cd), blk, 0, stream>>>(
      mhaWk, WkT, nullptr, Wkk, Cd, Cd, Cd, Cd, Cd, nullptr, nullptr, 0, nullptr);
  mgemm<bf16, ACT_NONE, false><<<g128(Cd, Cd), blk, 0, stream>>>(
      mhaWv, WvT, nullptr, Wvv, Cd, Cd, Cd, Cd, Cd, nullptr, nullptr, 0, nullptr);
  pack_bias3<<<12, blk, 0, stream>>>(mhabk, mhabv, bias3);
  // fused kp/vp GEMV: one wave per output column, 2048 waves total
  kpvp_kernel<<<dim3(512), blk, 0, stream>>>(pm, Wq3, bias3, kp, vp);

  for (int r0 = 0; r0 < R; r0 += CR) {
    const int cr = (R - r0 < CR) ? (R - r0) : CR;
    const int n = cr * Cd;
    conv_kernel<<<dim3((n + 255) / 256), blk, 0, stream>>>(d_in[0], Xc, n, (size_t)r0 * Cd, flag);

    // packed x-projection: [q_seg | k_x | v_x]
    mgemm<bf16, ACT_NONE, true><<<g128(cr, 3072), blk, 0, stream>>>(
        Xc, Wq3, bias3, QS3, cr, 3072, Cd, Cd, 3072, nullptr, nullptr, 0, nullptr);

    // memory net on q_seg (lda = 3072) -> retrieved (Bb)
    mgemm<bf16, ACT_SILU, true><<<g128(cr, Md), blk, 0, stream>>>(
        QS3, mem_W1, mem_b1, h1b, cr, Md, Cd, 3072, Md, nullptr, nullptr, 0, nullptr);
    ln_kernel<bf16, bf16, false, 128, 128><<<cr, 128, 0, stream>>>(h1b, ln1g, ln1b, nullptr, h2b, Md);
    mgemm<bf16, ACT_NONE, true><<<g128(cr, Md), blk, 0, stream>>>(
        h2b, mem_W2, mem_b2, h1b, cr, Md, Md, Md, Md, nullptr, nullptr, 0, nullptr);
    ln_kernel<bf16, bf16, true, 128, 128><<<cr, 128, 0, stream>>>(h1b, ln2g, ln2b, mstate, h2b, Md);
    mgemm<bf16, ACT_NONE, true><<<g128(cr, Cd), blk, 0, stream>>>(
        h2b, mem_oW, mem_ob, Bb, cr, Cd, Md, Md, Cd, nullptr, nullptr, 0, nullptr);

    // q (from q_seg) and KVr (from retrieved)
    mgemm<bf16, ACT_NONE, true><<<g128(cr, Cd), blk, 0, stream>>>(
        QS3, mhaWq, mhabq, Cc, cr, Cd, Cd, 3072, Cd, nullptr, nullptr, 0, nullptr);
    mgemm<bf16, ACT_NONE, true><<<g128(cr, 2048), blk, 0, stream>>>(
        Bb, Wkk, bias3 + 1024, KVr, cr, 2048, Cd, Cd, 2048, nullptr, nullptr, 0, nullptr);

    attn_kernel<<<dim3((cr / 64) * 8), dim3(512), 0, stream>>>(
        Cc, KVr, 2048, QS3 + 1024, 3072, kp, vp, Xc);

    // ao, gate-norm, fused gate*ao+x, final projection
    mgemm<bf16, ACT_NONE, true><<<g128(cr, Cd), blk, 0, stream>>>(
        Xc, mhaWo, mhabo, Bb, cr, Cd, Cd, Cd, Cd, nullptr, nullptr, 0, nullptr);
    ln_kernel<bf16, bf16, false, 1024, 256><<<cr, 256, 0, stream>>>(Bb, gn_g, gn_b, nullptr, Cc, Cd);
    mgemm<bf16, ACT_GATE, true><<<g128(cr, Cd), blk, 0, stream>>>(
        Cc, gateW, gateb, Xc, cr, Cd, Cd, Cd, Cd, Bb, d_in[0], (size_t)r0 * Cd, flag);
    mgemm<float, ACT_NONE, true><<<g128(cr, Cd), blk, 0, stream>>>(
        Xc, outW, outb, (float*)d_out + (size_t)r0 * Cd, cr, Cd, Cd, Cd, Cd,
        nullptr, nullptr, 0, nullptr);
  }
}

// Round 3
// 952.686 us; speedup vs baseline: 1.2723x; 1.1077x over previous
//
#include <hip/hip_runtime.h>
#include <hip/hip_bf16.h>
#include <math.h>

// TitanLongTermMemory — round 10: algebraic FLOP deletion.
// r9 rocprof: top-5 all the N=3072 x-proj mgemm @81us, 634 TF (25% peak).
// This round removes ~31% of GEMM FLOPs by weight folding:
//  - retrieved is only consumed by K/V projs -> Wc = [Wkk;Wvv]@mem_out_W,
//    KVr = h2s @ Wc^T (K=128, was K=1024; mem_out GEMM deleted).
//  - q_seg only feeds mha-q and mem_W1 -> fold through Wq:
//    Wqq = mhaWq@Wq, Wm1 = mem_W1@Wq; packed x-proj = [k_x|v_x|q|h1], N=3200
//    (q GEMM and mem_W1 GEMM deleted; partial-SiLU epilogue for h1 cols).
//  - bias folds: bkv via 5th row (mem_out_b) in the kpvp GEMV.
// Expected: 1055 -> ~860us.

using bf16 = __hip_bfloat16;

typedef __attribute__((ext_vector_type(8))) short bf16x8;
typedef __attribute__((ext_vector_type(4))) float f32x4;

__device__ __forceinline__ float ldf(const bf16* p) { return __bfloat162float(*p); }
__device__ __forceinline__ float ldf(const float* p) { return *p; }
__device__ __forceinline__ void stf(bf16* p, float v) { *p = __float2bfloat16(v); }
__device__ __forceinline__ void stf(float* p, float v) { *p = v; }
__device__ __forceinline__ float b2f(const bf16& b) { return __bfloat162float(b); }
__device__ __forceinline__ float bsf(short s) {
  union { unsigned u; float f; } cv;
  cv.u = (unsigned)(unsigned short)s << 16;
  return cv.f;
}

enum { ACT_NONE = 0, ACT_SILU = 1, ACT_SIGMOID = 2, ACT_GATE = 3, ACT_PSILU = 4 };

__global__ void detect_kernel(const unsigned short* g, int* flag) {
  if (threadIdx.x == 0) *flag = (g[0] != 0) ? 1 : 0;
}

// ---- single fused dtype-normalize for all non-x inputs ----------------------
struct ConvArgs {
  const void* src[29];
  bf16* dst[29];
  int n[29];
  int bstart[30];
};

__global__ __launch_bounds__(256) void convall_kernel(ConvArgs a, const int* __restrict__ flag) {
  int b = blockIdx.x;
  int ti = 0;
  while (ti < 28 && b >= a.bstart[ti + 1]) ++ti;
  int i = (b - a.bstart[ti]) * 256 + threadIdx.x;
  if (i >= a.n[ti]) return;
  if (*flag) a.dst[ti][i] = ((const bf16*)a.src[ti])[i];
  else a.dst[ti][i] = __float2bfloat16(((const float*)a.src[ti])[i]);
}

__global__ __launch_bounds__(256) void conv_kernel(
    const void* __restrict__ src, bf16* __restrict__ dst, int n, size_t src_off,
    const int* __restrict__ flag) {
  int i = blockIdx.x * 256 + threadIdx.x;
  if (i >= n) return;
  if (*flag) dst[i] = ((const bf16*)src)[src_off + i];
  else dst[i] = __float2bfloat16(((const float*)src)[src_off + i]);
}

// bias4 = [bk(1024) | bv(1024) | bq(1024) | mem_b1(128)]
__global__ __launch_bounds__(256) void pack_bias4(
    const bf16* __restrict__ bk, const bf16* __restrict__ bv,
    const bf16* __restrict__ bq, const bf16* __restrict__ b1,
    bf16* __restrict__ o) {
  int j = blockIdx.x * 256 + threadIdx.x;
  if (j >= 3200) return;
  float v;
  if (j < 1024) v = b2f(bk[j]);
  else if (j < 2048) v = b2f(bv[j - 1024]);
  else if (j < 3072) v = b2f(bq[j - 2048]);
  else v = b2f(b1[j - 3072]);
  o[j] = __float2bfloat16(v);
}

// 64x64-tile transpose: dst[c][r] = src[r][c]; src rows x cols (ld=cols).
__global__ __launch_bounds__(256) void transpose_kernel(
    const bf16* __restrict__ srcb, bf16* __restrict__ dstb, int rows, int cols) {
  __shared__ unsigned short t[64][72];  // 144B row stride (16B-aligned)
  const unsigned short* src = (const unsigned short*)srcb;
  unsigned short* dst = (unsigned short*)dstb;
  const int r0 = blockIdx.y * 64, c0 = blockIdx.x * 64;
  for (int e = threadIdx.x; e < 64 * 8; e += 256) {
    int r = e >> 3, c8 = e & 7;
    uint4 v = *(const uint4*)(src + (size_t)(r0 + r) * cols + c0 + c8 * 8);
    *(uint4*)&t[r][c8 * 8] = v;
  }
  __syncthreads();
  for (int e = threadIdx.x; e < 64 * 8; e += 256) {
    int c = e >> 3, r8 = (e & 7) * 8;
    unsigned short v[8];
#pragma unroll
    for (int j = 0; j < 8; ++j) v[j] = t[r8 + j][c];
    *(uint4*)(dst + (size_t)(c0 + c) * rows + r0 + r8) = *(uint4*)v;
  }
}

// ---- fused kp/vp/bkv GEMV over W4 rows 0..2047 ([Wkk|Wvv]) ------------------
// rows pm[0..3] -> kp/vp; row mob -> bkv (the folded mem_out_b @ Wkv^T term).
__global__ __launch_bounds__(256) void kpvp_kernel(
    const bf16* __restrict__ pmb, const bf16* __restrict__ mobb,
    const bf16* __restrict__ Wb, const bf16* __restrict__ bias4b,
    bf16* __restrict__ kp, bf16* __restrict__ vp, bf16* __restrict__ bkv)
{
  const short* pm = (const short*)pmb;
  const short* mob = (const short*)mobb;
  const short* W = (const short*)Wb;
  const int wave = threadIdx.x >> 6, lane = threadIdx.x & 63;
  const int c = blockIdx.x * 4 + wave;  // 0..2047
  const short* wrow = W + (size_t)c * 1024 + lane * 16;
  const bf16x8 w0 = *(const bf16x8*)wrow;
  const bf16x8 w1 = *(const bf16x8*)(wrow + 8);
  float acc[5];
#pragma unroll
  for (int m = 0; m < 5; ++m) {
    const short* prow = (m < 4) ? (pm + m * 1024 + lane * 16) : (mob + lane * 16);
    const bf16x8 p0 = *(const bf16x8*)prow;
    const bf16x8 p1 = *(const bf16x8*)(prow + 8);
    float s = 0.f;
#pragma unroll
    for (int j = 0; j < 8; ++j) s += bsf(w0[j]) * bsf(p0[j]) + bsf(w1[j]) * bsf(p1[j]);
    acc[m] = s;
  }
#pragma unroll
  for (int d = 1; d < 64; d <<= 1) {
#pragma unroll
    for (int m = 0; m < 5; ++m) acc[m] += __shfl_xor(acc[m], d);
  }
  if (lane == 0) {
    const float bv = b2f(bias4b[c]);
    bf16* dst = (c < 1024) ? (kp + c) : (vp + (c - 1024));
#pragma unroll
    for (int m = 0; m < 4; ++m) stf(dst + m * 1024, acc[m] + bv);
    stf(&bkv[c], acc[4] + bv);
  }
}

// ---------------- MFMA GEMM: C[M,N] = act(A[M,K] @ B[N,K]^T + bias) ----------
__device__ __forceinline__ void gl_lds16(const short* g, short* l) {
  __builtin_amdgcn_global_load_lds(
      (const __attribute__((address_space(1))) void*)g,
      (__attribute__((address_space(3))) void*)l, 16, 0, 0);
}

// ACT_GATE epilogue: t = sigmoid(acc+bias) * ao[m,n] + x[m,n]; C bf16.
// ACT_PSILU: silu applied only to columns n >= pn.
template <typename TC, int ACT, bool HAS_BIAS>
__global__ __launch_bounds__(256) void mgemm(
    const bf16* __restrict__ Ab, const bf16* __restrict__ Bw,
    const bf16* __restrict__ bias, TC* __restrict__ C,
    int M, int N, int K, int lda, int ldc,
    const bf16* __restrict__ ao, const void* __restrict__ xsrc, size_t xoff,
    const int* __restrict__ flag, int pn)
{
  __shared__ short As[128 * 32];
  __shared__ short Bs[128 * 32];
  const short* A = (const short*)Ab;
  const short* B = (const short*)Bw;
  const int tid = threadIdx.x;
  const int m0 = blockIdx.y * 128, n0 = blockIdx.x * 128;
  const int wave = tid >> 6, lane = tid & 63;
  const int wm = (wave & 1) * 64, wn = (wave >> 1) * 64;
  const int fm = lane & 15;
  const int fk = (lane >> 4) * 8;

  const int srow = tid >> 2, scol = (tid & 3) * 8;
  const short* gA0 = A + (size_t)(m0 + srow) * lda + scol;
  const short* gA1 = A + (size_t)(m0 + 64 + srow) * lda + scol;
  const short* gB0 = B + (size_t)(n0 + srow) * K + scol;
  const short* gB1 = B + (size_t)(n0 + 64 + srow) * K + scol;
  short* lA0 = As + tid * 8;
  short* lA1 = As + (256 + tid) * 8;
  short* lB0 = Bs + tid * 8;
  short* lB1 = Bs + (256 + tid) * 8;

  f32x4 acc[4][4] = {};

  for (int k0 = 0; k0 < K; k0 += 32) {
    gl_lds16(gA0 + k0, lA0);
    gl_lds16(gA1 + k0, lA1);
    gl_lds16(gB0 + k0, lB0);
    gl_lds16(gB1 + k0, lB1);
    __syncthreads();
    bf16x8 af[4], bfr[4];
#pragma unroll
    for (int i = 0; i < 4; ++i)
      af[i] = *(const bf16x8*)&As[(wm + i * 16 + fm) * 32 + fk];
#pragma unroll
    for (int j = 0; j < 4; ++j)
      bfr[j] = *(const bf16x8*)&Bs[(wn + j * 16 + fm) * 32 + fk];
#pragma unroll
    for (int i = 0; i < 4; ++i)
#pragma unroll
      for (int j = 0; j < 4; ++j)
        acc[i][j] = __builtin_amdgcn_mfma_f32_16x16x32_bf16(af[i], bfr[j], acc[i][j], 0, 0, 0);
    __syncthreads();
  }

  const int rg = (lane >> 4) * 4;
#pragma unroll
  for (int i = 0; i < 4; ++i) {
#pragma unroll
    for (int j = 0; j < 4; ++j) {
      const int n = n0 + wn + j * 16 + fm;
      float bv = 0.f;
      if (HAS_BIAS) bv = b2f(bias[n]);
#pragma unroll
      for (int r = 0; r < 4; ++r) {
        const int m = m0 + wm + i * 16 + rg + r;
        float v = acc[i][j][r] + bv;
        if (ACT == ACT_SILU) v = v / (1.f + __expf(-v));
        if (ACT == ACT_PSILU) { if (n >= pn) v = v / (1.f + __expf(-v)); }
        if (ACT == ACT_SIGMOID) v = 1.f / (1.f + __expf(-v));
        if (ACT == ACT_GATE) {
          v = 1.f / (1.f + __expf(-v));
          const size_t e = (size_t)m * 1024 + n;
          const float xv = *flag ? b2f(((const bf16*)xsrc)[xoff + e])
                                 : ((const float*)xsrc)[xoff + e];
          v = v * b2f(ao[e]) + xv;
        }
        stf(&C[(size_t)m * ldc + n], v);
      }
    }
  }
}

// Row LayerNorm over width W; optional post-LN add of a bf16 vector.
template <typename TI, typename TO, bool ADD, int W, int BS>
__global__ __launch_bounds__(BS) void ln_kernel(
    const TI* __restrict__ in, const bf16* __restrict__ g, const bf16* __restrict__ b,
    const bf16* __restrict__ addv, TO* __restrict__ out, int ldin)
{
  __shared__ float red[BS];
  const int row = blockIdx.x;
  const TI* rin = in + (size_t)row * ldin;
  TO* rout = out + (size_t)row * W;
  const int NP = W / BS;
  float v[NP];
  float s = 0.f;
#pragma unroll
  for (int i = 0; i < NP; ++i) { v[i] = ldf(&rin[threadIdx.x + i * BS]); s += v[i]; }
  red[threadIdx.x] = s; __syncthreads();
  for (int o = BS / 2; o > 0; o >>= 1) {
    if (threadIdx.x < o) red[threadIdx.x] += red[threadIdx.x + o];
    __syncthreads();
  }
  const float mean = red[0] / W;
  __syncthreads();
  float sq = 0.f;
#pragma unroll
  for (int i = 0; i < NP; ++i) { float d = v[i] - mean; sq += d * d; }
  red[threadIdx.x] = sq; __syncthreads();
  for (int o = BS / 2; o > 0; o >>= 1) {
    if (threadIdx.x < o) red[threadIdx.x] += red[threadIdx.x + o];
    __syncthreads();
  }
  const float rstd = rsqrtf(red[0] / W + 1e-5f);
#pragma unroll
  for (int i = 0; i < NP; ++i) {
    int c = threadIdx.x + i * BS;
    float o_ = (v[i] - mean) * rstd * b2f(g[c]) + b2f(b[c]);
    if (ADD) o_ += b2f(addv[c]);
    stf(&rout[c], o_);
  }
}

// ---------------- MFMA attention (param q stride; out stride fixed 1024) ----
__global__ __launch_bounds__(512) void attn_kernel(
    const bf16* __restrict__ qg, int str_q,
    const bf16* __restrict__ krv, int str_r,
    const bf16* __restrict__ kxv, int str_x, const bf16* __restrict__ kpg,
    const bf16* __restrict__ vpg, bf16* __restrict__ outg)
{
  __shared__ short qs[4 * 64 * 32];
  __shared__ short ksl[4 * 144 * 32];
  __shared__ short vt[128 * 168];
  __shared__ short pl[64 * 168];

  const int tid = threadIdx.x;
  const int seg = blockIdx.x >> 3, h = blockIdx.x & 7;
  const unsigned short* q = (const unsigned short*)qg + (size_t)seg * 64 * str_q + h * 128;
  const unsigned short* kv_r = (const unsigned short*)krv + (size_t)seg * 64 * str_r + h * 128;
  const unsigned short* kv_x = (const unsigned short*)kxv + (size_t)seg * 64 * str_x + h * 128;
  const unsigned short* kp = (const unsigned short*)kpg;
  const unsigned short* vp = (const unsigned short*)vpg;
  const size_t obase = (size_t)seg * 64 * 1024 + h * 128;

  for (int ch = tid; ch < 64 * 16; ch += 512) {
    int row = ch >> 4, k8 = ch & 15;
    uint4 v = *(const uint4*)(q + (size_t)row * str_q + k8 * 8);
    *(uint4*)&qs[((k8 >> 2) * 64 + row) * 32 + (k8 & 3) * 8] = v;
  }
  for (int ch = tid; ch < 132 * 16; ch += 512) {
    int t = ch >> 4, k8 = ch & 15;
    const unsigned short* src;
    if (t < 64) src = kv_r + (size_t)t * str_r;
    else if (t < 68) src = kp + (size_t)(t - 64) * 1024 + h * 128;
    else src = kv_x + (size_t)(t - 68) * str_x;
    uint4 v = *(const uint4*)(src + k8 * 8);
    *(uint4*)&ksl[((k8 >> 2) * 144 + t) * 32 + (k8 & 3) * 8] = v;
  }
  __syncthreads();

  const int wave = tid >> 6, lane = tid & 63;
  const int fm = lane & 15, fq = lane >> 4;

  if (wave < 4) {
    const int s0 = wave * 16;
    f32x4 acc[10];
#pragma unroll
    for (int tt = 0; tt < 10; ++tt) acc[tt] = (f32x4){0.f, 0.f, 0.f, 0.f};
#pragma unroll
    for (int kb = 0; kb < 4; ++kb) {
      const bf16x8 a = *(const bf16x8*)&qs[(kb * 64 + s0 + fm) * 32 + fq * 8];
#pragma unroll
      for (int tt = 0; tt < 9; ++tt) {
        const bf16x8 b = *(const bf16x8*)&ksl[(kb * 144 + tt * 16 + fm) * 32 + fq * 8];
        acc[tt] = __builtin_amdgcn_mfma_f32_16x16x32_bf16(a, b, acc[tt], 0, 0, 0);
      }
    }
    const float scale = 0.08838834764831845f;
#pragma unroll
    for (int r = 0; r < 4; ++r) {
      float m = -3.0e38f;
#pragma unroll
      for (int tt = 0; tt < 9; ++tt) {
        int t = tt * 16 + fm;
        if (t < 132) m = fmaxf(m, acc[tt][r] * scale);
      }
      for (int d = 1; d < 16; d <<= 1) m = fmaxf(m, __shfl_xor(m, d));
      float e[10];
      float sum = 0.f;
#pragma unroll
      for (int tt = 0; tt < 10; ++tt) {
        int t = tt * 16 + fm;
        float ev = 0.f;
        if (t < 132) ev = __expf(acc[tt][r] * scale - m);
        e[tt] = ev; sum += ev;
      }
      for (int d = 1; d < 16; d <<= 1) sum += __shfl_xor(sum, d);
      const float inv = 1.f / sum;
      const int s = s0 + fq * 4 + r;
#pragma unroll
      for (int tt = 0; tt < 10; ++tt) {
        bf16 pv = __float2bfloat16(e[tt] * inv);
        pl[s * 168 + tt * 16 + fm] = *(const short*)&pv;
      }
    }
  } else {
    for (int ch = tid - 256; ch < 132 * 32; ch += 256) {
      int t = ch >> 5, d4 = (ch & 31) * 4;
      const unsigned short* src;
      if (t < 64) src = kv_r + 1024 + (size_t)t * str_r;
      else if (t < 68) src = vp + (size_t)(t - 64) * 1024 + h * 128;
      else src = kv_x + 1024 + (size_t)(t - 68) * str_x;
      uint2 w = *(const uint2*)(src + d4);
      vt[(d4 + 0) * 168 + t] = (short)(w.x & 0xffffu);
      vt[(d4 + 1) * 168 + t] = (short)(w.x >> 16);
      vt[(d4 + 2) * 168 + t] = (short)(w.y & 0xffffu);
      vt[(d4 + 3) * 168 + t] = (short)(w.y >> 16);
    }
    for (int ch = tid - 256; ch < 128 * 32; ch += 256) {
      int d = ch >> 5, tp = 132 + (ch & 31);
      vt[d * 168 + tp] = 0;
    }
  }
  __syncthreads();

  const int dt = wave;
  bf16x8 af[5];
#pragma unroll
  for (int kb = 0; kb < 5; ++kb)
    af[kb] = *(const bf16x8*)&vt[(dt * 16 + fm) * 168 + kb * 32 + fq * 8];
#pragma unroll
  for (int st = 0; st < 4; ++st) {
    f32x4 o = (f32x4){0.f, 0.f, 0.f, 0.f};
#pragma unroll
    for (int kb = 0; kb < 5; ++kb) {
      const bf16x8 bp = *(const bf16x8*)&pl[(st * 16 + fm) * 168 + kb * 32 + fq * 8];
      o = __builtin_amdgcn_mfma_f32_16x16x32_bf16(af[kb], bp, o, 0, 0, 0);
    }
    const int s = st * 16 + fm;
    bf16 b0 = __float2bfloat16(o[0]), b1 = __float2bfloat16(o[1]);
    bf16 b2 = __float2bfloat16(o[2]), b3 = __float2bfloat16(o[3]);
    uint2 w;
    w.x = ((unsigned)(*(unsigned short*)&b1) << 16) | (*(unsigned short*)&b0);
    w.y = ((unsigned)(*(unsigned short*)&b3) << 16) | (*(unsigned short*)&b2);
    *(uint2*)((unsigned short*)outg + obase + (size_t)s * 1024 + dt * 16 + fq * 4) = w;
  }
}

extern "C" void kernel_launch(void* const* d_in, const int* in_sizes, int n_in,
                              void* d_out, int out_size, void* d_ws, size_t ws_size,
                              hipStream_t stream)
{
  (void)n_in; (void)out_size;
  const int R = 16384, Cd = 1024;

  char* ws = (char*)d_ws;
  size_t off = 0;
  auto alloc = [&](size_t bytes) -> void* {
    void* p = ws + off;
    off += (bytes + 255) & ~(size_t)255;
    return p;
  };

  int* flag = (int*)alloc(256);
  // packed x-projection weights [Wkk | Wvv | Wqq | Wm1] rows (3200 x 1024)
  bf16* W4    = (bf16*)alloc((size_t)3200 * Cd * sizeof(bf16));
  bf16* bias4 = (bf16*)alloc(3200 * sizeof(bf16));
  bf16* T     = (bf16*)alloc((size_t)Cd * Cd * sizeof(bf16));  // transpose scratch
  bf16* Wc    = (bf16*)alloc((size_t)2048 * 128 * sizeof(bf16));
  bf16* kp    = (bf16*)alloc((size_t)4 * Cd * sizeof(bf16));
  bf16* vp    = (bf16*)alloc((size_t)4 * Cd * sizeof(bf16));
  bf16* bkv   = (bf16*)alloc(2048 * sizeof(bf16));
  bf16* nb[30];
  nb[0] = nullptr;
  for (int i = 1; i < 30; ++i) nb[i] = (bf16*)alloc((size_t)in_sizes[i] * sizeof(bf16));
  const size_t fixed_end = off;

  // balanced chunk sizing; per-row scratch = 17152 B
  size_t avail = (ws_size > fixed_end + (1u << 20)) ? (ws_size - fixed_end - (1u << 20)) : 0;
  int crmax = (int)(avail / 17152);
  if (crmax > R) crmax = R;
  if (crmax < 128) crmax = 128;
  int nch = (R + crmax - 1) / crmax;
  int CR = ((R / nch + 127) / 128) * 128;
  while (CR * nch < R) CR += 128;

  const size_t RB = (size_t)CR * Cd * sizeof(bf16);
  bf16* Xc  = (bf16*)alloc(RB);                               // x(bf16) -> attn out
  bf16* QS4 = (bf16*)alloc((size_t)CR * 3200 * sizeof(bf16)); // [k_x|v_x|q|h1]
  bf16* h1b = (bf16*)alloc((size_t)CR * 128 * sizeof(bf16));
  bf16* h2b = (bf16*)alloc((size_t)CR * 128 * sizeof(bf16));
  bf16* Bb  = (bf16*)alloc(RB);                               // ao
  bf16* KVr = (bf16*)alloc(2 * RB);                           // [k_r | v_r]
  bf16* Cc  = (bf16*)alloc(RB);                               // gin

  dim3 blk(256);
  auto g128 = [](int M_, int N_) { return dim3((unsigned)(N_ / 128), (unsigned)(M_ / 128)); };

  // ---- preamble ----
  detect_kernel<<<1, 64, 0, stream>>>((const unsigned short*)d_in[24], flag);
  {
    ConvArgs a;
    int bs = 0;
    for (int i = 1; i < 30; ++i) {
      a.src[i - 1] = d_in[i];
      a.dst[i - 1] = nb[i];
      a.n[i - 1] = in_sizes[i];
      a.bstart[i - 1] = bs;
      bs += (in_sizes[i] + 255) / 256;
    }
    a.bstart[29] = bs;
    convall_kernel<<<dim3((unsigned)bs), blk, 0, stream>>>(a, flag);
  }
  const bf16 *pm = nb[1], *Wq = nb[2], *Wk = nb[3], *Wv = nb[4];
  const bf16 *mem_W1 = nb[5], *mem_b1 = nb[6], *ln1g = nb[7], *ln1b = nb[8];
  const bf16 *mem_W2 = nb[9], *mem_b2 = nb[10], *ln2g = nb[11], *ln2b = nb[12];
  const bf16 *mem_oW = nb[13], *mem_ob = nb[14], *mstate = nb[15];
  const bf16 *mhaWq = nb[16], *mhabq = nb[17], *mhaWk = nb[18], *mhabk = nb[19];
  const bf16 *mhaWv = nb[20], *mhabv = nb[21], *mhaWo = nb[22], *mhabo = nb[23];
  const bf16 *gn_g = nb[24], *gn_b = nb[25], *gateW = nb[26], *gateb = nb[27];
  const bf16 *outW = nb[28], *outb = nb[29];
  bf16* Wkk = W4;
  bf16* Wvv = W4 + (size_t)1024 * Cd;
  bf16* Wqq = W4 + (size_t)2048 * Cd;
  bf16* Wm1 = W4 + (size_t)3072 * Cd;

  // weight folds (T reused serially as the transpose scratch)
  transpose_kernel<<<dim3(16, 16), blk, 0, stream>>>(Wk, T, 1024, 1024);
  mgemm<bf16, ACT_NONE, false><<<g128(1024, 1024), blk, 0, stream>>>(
      mhaWk, T, nullptr, Wkk, 1024, 1024, 1024, 1024, 1024, nullptr, nullptr, 0, nullptr, 0);
  transpose_kernel<<<dim3(16, 16), blk, 0, stream>>>(Wv, T, 1024, 1024);
  mgemm<bf16, ACT_NONE, false><<<g128(1024, 1024), blk, 0, stream>>>(
      mhaWv, T, nullptr, Wvv, 1024, 1024, 1024, 1024, 1024, nullptr, nullptr, 0, nullptr, 0);
  transpose_kernel<<<dim3(16, 16), blk, 0, stream>>>(Wq, T, 1024, 1024);
  mgemm<bf16, ACT_NONE, false><<<g128(1024, 1024), blk, 0, stream>>>(
      mhaWq, T, nullptr, Wqq, 1024, 1024, 1024, 1024, 1024, nullptr, nullptr, 0, nullptr, 0);
  mgemm<bf16, ACT_NONE, false><<<g128(128, 1024), blk, 0, stream>>>(
      mem_W1, T, nullptr, Wm1, 128, 1024, 1024, 1024, 1024, nullptr, nullptr, 0, nullptr, 0);
  // Wc = [Wkk;Wvv] @ mem_out_W  (2048 x 128)
  transpose_kernel<<<dim3(2, 16), blk, 0, stream>>>(mem_oW, T, 1024, 128);
  mgemm<bf16, ACT_NONE, false><<<g128(2048, 128), blk, 0, stream>>>(
      W4, T, nullptr, Wc, 2048, 128, 1024, 1024, 128, nullptr, nullptr, 0, nullptr, 0);
  pack_bias4<<<13, blk, 0, stream>>>(mhabk, mhabv, mhabq, mem_b1, bias4);
  kpvp_kernel<<<dim3(512), blk, 0, stream>>>(pm, mem_ob, W4, bias4, kp, vp, bkv);

  for (int r0 = 0; r0 < R; r0 += CR) {
    const int cr = (R - r0 < CR) ? (R - r0) : CR;
    const int n = cr * Cd;
    conv_kernel<<<dim3((n + 255) / 256), blk, 0, stream>>>(d_in[0], Xc, n, (size_t)r0 * Cd, flag);

    // packed x-projection: [k_x | v_x | q | h1=silu(...)]
    mgemm<bf16, ACT_PSILU, true><<<g128(cr, 3200), blk, 0, stream>>>(
        Xc, W4, bias4, QS4, cr, 3200, 1024, 1024, 3200, nullptr, nullptr, 0, nullptr, 3072);

    // memory net tail: ln1 -> W2 -> ln2(+mstate) -> folded KVr (K=128)
    ln_kernel<bf16, bf16, false, 128, 128><<<cr, 128, 0, stream>>>(
        QS4 + 3072, ln1g, ln1b, nullptr, h2b, 3200);
    mgemm<bf16, ACT_NONE, true><<<g128(cr, 128), blk, 0, stream>>>(
        h2b, mem_W2, mem_b2, h1b, cr, 128, 128, 128, 128, nullptr, nullptr, 0, nullptr, 0);
    ln_kernel<bf16, bf16, true, 128, 128><<<cr, 128, 0, stream>>>(h1b, ln2g, ln2b, mstate, h2b, 128);
    mgemm<bf16, ACT_NONE, true><<<g128(cr, 2048), blk, 0, stream>>>(
        h2b, Wc, bkv, KVr, cr, 2048, 128, 128, 2048, nullptr, nullptr, 0, nullptr, 0);

    attn_kernel<<<dim3((cr / 64) * 8), dim3(512), 0, stream>>>(
        QS4 + 2048, 3200, KVr, 2048, QS4, 3200, kp, vp, Xc);

    // ao, gate-norm, fused gate*ao+x, final projection
    mgemm<bf16, ACT_NONE, true><<<g128(cr, Cd), blk, 0, stream>>>(
        Xc, mhaWo, mhabo, Bb, cr, Cd, Cd, Cd, Cd, nullptr, nullptr, 0, nullptr, 0);
    ln_kernel<bf16, bf16, false, 1024, 256><<<cr, 256, 0, stream>>>(Bb, gn_g, gn_b, nullptr, Cc, Cd);
    mgemm<bf16, ACT_GATE, true><<<g128(cr, Cd), blk, 0, stream>>>(
        Cc, gateW, gateb, Xc, cr, Cd, Cd, Cd, Cd, Bb, d_in[0], (size_t)r0 * Cd, flag, 0);
    mgemm<float, ACT_NONE, true><<<g128(cr, Cd), blk, 0, stream>>>(
        Xc, outW, outb, (float*)d_out + (size_t)r0 * Cd, cr, Cd, Cd, Cd, Cd,
        nullptr, nullptr, 0, nullptr, 0);
  }
}

// Round 4
// 884.117 us; speedup vs baseline: 1.3710x; 1.0776x over previous
//
#include <hip/hip_runtime.h>
#include <hip/hip_bf16.h>
#include <math.h>

// TitanLongTermMemory — round 11: locality + preamble surgery.
// r10 post-mortem: x-proj FETCH doubled (71->141 MB) because Nt=25 made the
// block->XCD column assignment drift (xcd=(x+25y)%8); and the new fold GEMMs
// added ~80us of tiny-grid latency-bound preamble.
//  - mgemm grid axes swapped: grid=(Mt,Nt), Mt=64 always => xcd=m%8 fixed;
//    each XCD keeps 8 A-panels L2-resident, B streamed once/XCD in lockstep.
//  - preamble folds via z=4 K-split kgemm + f32-partial sum (aliases dead
//    chunk scratch), [mhaWq;mem_W1] stacked into one M=1152 fold.
//  - attn: XCD-chunked bid swizzle (same-seg heads share L2).
// Expected: 952 -> ~840us.

using bf16 = __hip_bfloat16;

typedef __attribute__((ext_vector_type(8))) short bf16x8;
typedef __attribute__((ext_vector_type(4))) float f32x4;

__device__ __forceinline__ float ldf(const bf16* p) { return __bfloat162float(*p); }
__device__ __forceinline__ float ldf(const float* p) { return *p; }
__device__ __forceinline__ void stf(bf16* p, float v) { *p = __float2bfloat16(v); }
__device__ __forceinline__ void stf(float* p, float v) { *p = v; }
__device__ __forceinline__ float b2f(const bf16& b) { return __bfloat162float(b); }
__device__ __forceinline__ float bsf(short s) {
  union { unsigned u; float f; } cv;
  cv.u = (unsigned)(unsigned short)s << 16;
  return cv.f;
}

enum { ACT_NONE = 0, ACT_SILU = 1, ACT_SIGMOID = 2, ACT_GATE = 3, ACT_PSILU = 4 };

__global__ void detect_kernel(const unsigned short* g, int* flag) {
  if (threadIdx.x == 0) *flag = (g[0] != 0) ? 1 : 0;
}

// ---- single fused dtype-normalize for all non-x inputs ----------------------
struct ConvArgs {
  const void* src[29];
  bf16* dst[29];
  int n[29];
  int bstart[30];
};

__global__ __launch_bounds__(256) void convall_kernel(ConvArgs a, const int* __restrict__ flag) {
  int b = blockIdx.x;
  int ti = 0;
  while (ti < 28 && b >= a.bstart[ti + 1]) ++ti;
  int i = (b - a.bstart[ti]) * 256 + threadIdx.x;
  if (i >= a.n[ti]) return;
  if (*flag) a.dst[ti][i] = ((const bf16*)a.src[ti])[i];
  else a.dst[ti][i] = __float2bfloat16(((const float*)a.src[ti])[i]);
}

__global__ __launch_bounds__(256) void conv_kernel(
    const void* __restrict__ src, bf16* __restrict__ dst, int n, size_t src_off,
    const int* __restrict__ flag) {
  int i = blockIdx.x * 256 + threadIdx.x;
  if (i >= n) return;
  if (*flag) dst[i] = ((const bf16*)src)[src_off + i];
  else dst[i] = __float2bfloat16(((const float*)src)[src_off + i]);
}

// bias4 = [bk(1024) | bv(1024) | bq(1024) | mem_b1(128)]
__global__ __launch_bounds__(256) void pack_bias4(
    const bf16* __restrict__ bk, const bf16* __restrict__ bv,
    const bf16* __restrict__ bq, const bf16* __restrict__ b1,
    bf16* __restrict__ o) {
  int j = blockIdx.x * 256 + threadIdx.x;
  if (j >= 3200) return;
  float v;
  if (j < 1024) v = b2f(bk[j]);
  else if (j < 2048) v = b2f(bv[j - 1024]);
  else if (j < 3072) v = b2f(bq[j - 2048]);
  else v = b2f(b1[j - 3072]);
  o[j] = __float2bfloat16(v);
}

// 64x64-tile transpose: dst[c][r] = src[r][c]; src rows x cols (ld=cols).
__global__ __launch_bounds__(256) void transpose_kernel(
    const bf16* __restrict__ srcb, bf16* __restrict__ dstb, int rows, int cols) {
  __shared__ unsigned short t[64][72];  // 144B row stride (16B-aligned)
  const unsigned short* src = (const unsigned short*)srcb;
  unsigned short* dst = (unsigned short*)dstb;
  const int r0 = blockIdx.y * 64, c0 = blockIdx.x * 64;
  for (int e = threadIdx.x; e < 64 * 8; e += 256) {
    int r = e >> 3, c8 = e & 7;
    uint4 v = *(const uint4*)(src + (size_t)(r0 + r) * cols + c0 + c8 * 8);
    *(uint4*)&t[r][c8 * 8] = v;
  }
  __syncthreads();
  for (int e = threadIdx.x; e < 64 * 8; e += 256) {
    int c = e >> 3, r8 = (e & 7) * 8;
    unsigned short v[8];
#pragma unroll
    for (int j = 0; j < 8; ++j) v[j] = t[r8 + j][c];
    *(uint4*)(dst + (size_t)(c0 + c) * rows + r0 + r8) = *(uint4*)v;
  }
}

// ---- fused kp/vp/bkv GEMV over W4 rows 0..2047 ([Wkk|Wvv]) ------------------
__global__ __launch_bounds__(256) void kpvp_kernel(
    const bf16* __restrict__ pmb, const bf16* __restrict__ mobb,
    const bf16* __restrict__ Wb, const bf16* __restrict__ bias4b,
    bf16* __restrict__ kp, bf16* __restrict__ vp, bf16* __restrict__ bkv)
{
  const short* pm = (const short*)pmb;
  const short* mob = (const short*)mobb;
  const short* W = (const short*)Wb;
  const int wave = threadIdx.x >> 6, lane = threadIdx.x & 63;
  const int c = blockIdx.x * 4 + wave;  // 0..2047
  const short* wrow = W + (size_t)c * 1024 + lane * 16;
  const bf16x8 w0 = *(const bf16x8*)wrow;
  const bf16x8 w1 = *(const bf16x8*)(wrow + 8);
  float acc[5];
#pragma unroll
  for (int m = 0; m < 5; ++m) {
    const short* prow = (m < 4) ? (pm + m * 1024 + lane * 16) : (mob + lane * 16);
    const bf16x8 p0 = *(const bf16x8*)prow;
    const bf16x8 p1 = *(const bf16x8*)(prow + 8);
    float s = 0.f;
#pragma unroll
    for (int j = 0; j < 8; ++j) s += bsf(w0[j]) * bsf(p0[j]) + bsf(w1[j]) * bsf(p1[j]);
    acc[m] = s;
  }
#pragma unroll
  for (int d = 1; d < 64; d <<= 1) {
#pragma unroll
    for (int m = 0; m < 5; ++m) acc[m] += __shfl_xor(acc[m], d);
  }
  if (lane == 0) {
    const float bv = b2f(bias4b[c]);
    bf16* dst = (c < 1024) ? (kp + c) : (vp + (c - 1024));
#pragma unroll
    for (int m = 0; m < 4; ++m) stf(dst + m * 1024, acc[m] + bv);
    stf(&bkv[c], acc[4] + bv);
  }
}

// ---------------- MFMA GEMM: C[M,N] = act(A[M,K] @ B[N,K]^T + bias) ----------
// Grid = (Mt, Nt): m-tile fastest => xcd = m_tile % 8 fixed (Mt%8==0 for all
// main-loop GEMMs). Each XCD keeps its 8 A-panels L2-resident; B panels are
// fetched once per XCD and shared in lockstep by its 8 m-rows.
__device__ __forceinline__ void gl_lds16(const short* g, short* l) {
  __builtin_amdgcn_global_load_lds(
      (const __attribute__((address_space(1))) void*)g,
      (__attribute__((address_space(3))) void*)l, 16, 0, 0);
}

template <typename TC, int ACT, bool HAS_BIAS>
__global__ __launch_bounds__(256) void mgemm(
    const bf16* __restrict__ Ab, const bf16* __restrict__ Bw,
    const bf16* __restrict__ bias, TC* __restrict__ C,
    int M, int N, int K, int lda, int ldc,
    const bf16* __restrict__ ao, const void* __restrict__ xsrc, size_t xoff,
    const int* __restrict__ flag, int pn)
{
  __shared__ short As[128 * 32];
  __shared__ short Bs[128 * 32];
  const short* A = (const short*)Ab;
  const short* B = (const short*)Bw;
  const int tid = threadIdx.x;
  const int m0 = blockIdx.x * 128, n0 = blockIdx.y * 128;
  const int wave = tid >> 6, lane = tid & 63;
  const int wm = (wave & 1) * 64, wn = (wave >> 1) * 64;
  const int fm = lane & 15;
  const int fk = (lane >> 4) * 8;

  const int srow = tid >> 2, scol = (tid & 3) * 8;
  const short* gA0 = A + (size_t)(m0 + srow) * lda + scol;
  const short* gA1 = A + (size_t)(m0 + 64 + srow) * lda + scol;
  const short* gB0 = B + (size_t)(n0 + srow) * K + scol;
  const short* gB1 = B + (size_t)(n0 + 64 + srow) * K + scol;
  short* lA0 = As + tid * 8;
  short* lA1 = As + (256 + tid) * 8;
  short* lB0 = Bs + tid * 8;
  short* lB1 = Bs + (256 + tid) * 8;

  f32x4 acc[4][4] = {};

  for (int k0 = 0; k0 < K; k0 += 32) {
    gl_lds16(gA0 + k0, lA0);
    gl_lds16(gA1 + k0, lA1);
    gl_lds16(gB0 + k0, lB0);
    gl_lds16(gB1 + k0, lB1);
    __syncthreads();
    bf16x8 af[4], bfr[4];
#pragma unroll
    for (int i = 0; i < 4; ++i)
      af[i] = *(const bf16x8*)&As[(wm + i * 16 + fm) * 32 + fk];
#pragma unroll
    for (int j = 0; j < 4; ++j)
      bfr[j] = *(const bf16x8*)&Bs[(wn + j * 16 + fm) * 32 + fk];
#pragma unroll
    for (int i = 0; i < 4; ++i)
#pragma unroll
      for (int j = 0; j < 4; ++j)
        acc[i][j] = __builtin_amdgcn_mfma_f32_16x16x32_bf16(af[i], bfr[j], acc[i][j], 0, 0, 0);
    __syncthreads();
  }

  const int rg = (lane >> 4) * 4;
#pragma unroll
  for (int i = 0; i < 4; ++i) {
#pragma unroll
    for (int j = 0; j < 4; ++j) {
      const int n = n0 + wn + j * 16 + fm;
      float bv = 0.f;
      if (HAS_BIAS) bv = b2f(bias[n]);
#pragma unroll
      for (int r = 0; r < 4; ++r) {
        const int m = m0 + wm + i * 16 + rg + r;
        float v = acc[i][j][r] + bv;
        if (ACT == ACT_SILU) v = v / (1.f + __expf(-v));
        if (ACT == ACT_PSILU) { if (n >= pn) v = v / (1.f + __expf(-v)); }
        if (ACT == ACT_SIGMOID) v = 1.f / (1.f + __expf(-v));
        if (ACT == ACT_GATE) {
          v = 1.f / (1.f + __expf(-v));
          const size_t e = (size_t)m * 1024 + n;
          const float xv = *flag ? b2f(((const bf16*)xsrc)[xoff + e])
                                 : ((const float*)xsrc)[xoff + e];
          v = v * b2f(ao[e]) + xv;
        }
        stf(&C[(size_t)m * ldc + n], v);
      }
    }
  }
}

// ---- K-split fold GEMM (preamble): P[z] = A @ B^T over K-slice z (KS=4) ----
__global__ __launch_bounds__(256) void kgemm(
    const bf16* __restrict__ Ab, const bf16* __restrict__ Bw,
    float* __restrict__ P, int M, int N, int K, int lda)
{
  __shared__ short As[128 * 32];
  __shared__ short Bs[128 * 32];
  const short* A = (const short*)Ab;
  const short* B = (const short*)Bw;
  const int tid = threadIdx.x;
  const int m0 = blockIdx.x * 128, n0 = blockIdx.y * 128;
  const int kb = blockIdx.z * (K >> 2), ke = kb + (K >> 2);
  const int wave = tid >> 6, lane = tid & 63;
  const int wm = (wave & 1) * 64, wn = (wave >> 1) * 64;
  const int fm = lane & 15;
  const int fk = (lane >> 4) * 8;

  const int srow = tid >> 2, scol = (tid & 3) * 8;
  const short* gA0 = A + (size_t)(m0 + srow) * lda + scol;
  const short* gA1 = A + (size_t)(m0 + 64 + srow) * lda + scol;
  const short* gB0 = B + (size_t)(n0 + srow) * K + scol;
  const short* gB1 = B + (size_t)(n0 + 64 + srow) * K + scol;
  short* lA0 = As + tid * 8;
  short* lA1 = As + (256 + tid) * 8;
  short* lB0 = Bs + tid * 8;
  short* lB1 = Bs + (256 + tid) * 8;

  f32x4 acc[4][4] = {};

  for (int k0 = kb; k0 < ke; k0 += 32) {
    gl_lds16(gA0 + k0, lA0);
    gl_lds16(gA1 + k0, lA1);
    gl_lds16(gB0 + k0, lB0);
    gl_lds16(gB1 + k0, lB1);
    __syncthreads();
    bf16x8 af[4], bfr[4];
#pragma unroll
    for (int i = 0; i < 4; ++i)
      af[i] = *(const bf16x8*)&As[(wm + i * 16 + fm) * 32 + fk];
#pragma unroll
    for (int j = 0; j < 4; ++j)
      bfr[j] = *(const bf16x8*)&Bs[(wn + j * 16 + fm) * 32 + fk];
#pragma unroll
    for (int i = 0; i < 4; ++i)
#pragma unroll
      for (int j = 0; j < 4; ++j)
        acc[i][j] = __builtin_amdgcn_mfma_f32_16x16x32_bf16(af[i], bfr[j], acc[i][j], 0, 0, 0);
    __syncthreads();
  }

  float* Cp = P + (size_t)blockIdx.z * ((size_t)M * N);
  const int rg = (lane >> 4) * 4;
#pragma unroll
  for (int i = 0; i < 4; ++i)
#pragma unroll
    for (int j = 0; j < 4; ++j) {
      const int n = n0 + wn + j * 16 + fm;
#pragma unroll
      for (int r = 0; r < 4; ++r) {
        const int m = m0 + wm + i * 16 + rg + r;
        Cp[(size_t)m * N + n] = acc[i][j][r];
      }
    }
}

// sum 4 K-slice partials -> bf16
__global__ __launch_bounds__(256) void foldfin_kernel(
    const float* __restrict__ P, bf16* __restrict__ o, int MN) {
  int i = blockIdx.x * 256 + threadIdx.x;
  if (i >= MN) return;
  float s = P[i] + P[i + (size_t)MN] + P[i + 2 * (size_t)MN] + P[i + 3 * (size_t)MN];
  o[i] = __float2bfloat16(s);
}

// Row LayerNorm over width W; optional post-LN add of a bf16 vector.
template <typename TI, typename TO, bool ADD, int W, int BS>
__global__ __launch_bounds__(BS) void ln_kernel(
    const TI* __restrict__ in, const bf16* __restrict__ g, const bf16* __restrict__ b,
    const bf16* __restrict__ addv, TO* __restrict__ out, int ldin)
{
  __shared__ float red[BS];
  const int row = blockIdx.x;
  const TI* rin = in + (size_t)row * ldin;
  TO* rout = out + (size_t)row * W;
  const int NP = W / BS;
  float v[NP];
  float s = 0.f;
#pragma unroll
  for (int i = 0; i < NP; ++i) { v[i] = ldf(&rin[threadIdx.x + i * BS]); s += v[i]; }
  red[threadIdx.x] = s; __syncthreads();
  for (int o = BS / 2; o > 0; o >>= 1) {
    if (threadIdx.x < o) red[threadIdx.x] += red[threadIdx.x + o];
    __syncthreads();
  }
  const float mean = red[0] / W;
  __syncthreads();
  float sq = 0.f;
#pragma unroll
  for (int i = 0; i < NP; ++i) { float d = v[i] - mean; sq += d * d; }
  red[threadIdx.x] = sq; __syncthreads();
  for (int o = BS / 2; o > 0; o >>= 1) {
    if (threadIdx.x < o) red[threadIdx.x] += red[threadIdx.x + o];
    __syncthreads();
  }
  const float rstd = rsqrtf(red[0] / W + 1e-5f);
#pragma unroll
  for (int i = 0; i < NP; ++i) {
    int c = threadIdx.x + i * BS;
    float o_ = (v[i] - mean) * rstd * b2f(g[c]) + b2f(b[c]);
    if (ADD) o_ += b2f(addv[c]);
    stf(&rout[c], o_);
  }
}

// ---------------- MFMA attention (XCD-chunked bid swizzle) ------------------
__global__ __launch_bounds__(512) void attn_kernel(
    const bf16* __restrict__ qg, int str_q,
    const bf16* __restrict__ krv, int str_r,
    const bf16* __restrict__ kxv, int str_x, const bf16* __restrict__ kpg,
    const bf16* __restrict__ vpg, bf16* __restrict__ outg)
{
  __shared__ short qs[4 * 64 * 32];
  __shared__ short ksl[4 * 144 * 32];
  __shared__ short vt[128 * 168];
  __shared__ short pl[64 * 168];

  const int tid = threadIdx.x;
  unsigned bid = blockIdx.x;
  {
    const unsigned nwg = gridDim.x;
    const unsigned q_ = nwg >> 3, r_ = nwg & 7;
    const unsigned xcd = bid & 7, loc = bid >> 3;
    bid = (xcd < r_ ? xcd * (q_ + 1) : r_ * (q_ + 1) + (xcd - r_) * q_) + loc;
  }
  const int seg = (int)(bid >> 3), h = (int)(bid & 7);
  const unsigned short* q = (const unsigned short*)qg + (size_t)seg * 64 * str_q + h * 128;
  const unsigned short* kv_r = (const unsigned short*)krv + (size_t)seg * 64 * str_r + h * 128;
  const unsigned short* kv_x = (const unsigned short*)kxv + (size_t)seg * 64 * str_x + h * 128;
  const unsigned short* kp = (const unsigned short*)kpg;
  const unsigned short* vp = (const unsigned short*)vpg;
  const size_t obase = (size_t)seg * 64 * 1024 + h * 128;

  for (int ch = tid; ch < 64 * 16; ch += 512) {
    int row = ch >> 4, k8 = ch & 15;
    uint4 v = *(const uint4*)(q + (size_t)row * str_q + k8 * 8);
    *(uint4*)&qs[((k8 >> 2) * 64 + row) * 32 + (k8 & 3) * 8] = v;
  }
  for (int ch = tid; ch < 132 * 16; ch += 512) {
    int t = ch >> 4, k8 = ch & 15;
    const unsigned short* src;
    if (t < 64) src = kv_r + (size_t)t * str_r;
    else if (t < 68) src = kp + (size_t)(t - 64) * 1024 + h * 128;
    else src = kv_x + (size_t)(t - 68) * str_x;
    uint4 v = *(const uint4*)(src + k8 * 8);
    *(uint4*)&ksl[((k8 >> 2) * 144 + t) * 32 + (k8 & 3) * 8] = v;
  }
  __syncthreads();

  const int wave = tid >> 6, lane = tid & 63;
  const int fm = lane & 15, fq = lane >> 4;

  if (wave < 4) {
    const int s0 = wave * 16;
    f32x4 acc[10];
#pragma unroll
    for (int tt = 0; tt < 10; ++tt) acc[tt] = (f32x4){0.f, 0.f, 0.f, 0.f};
#pragma unroll
    for (int kb = 0; kb < 4; ++kb) {
      const bf16x8 a = *(const bf16x8*)&qs[(kb * 64 + s0 + fm) * 32 + fq * 8];
#pragma unroll
      for (int tt = 0; tt < 9; ++tt) {
        const bf16x8 b = *(const bf16x8*)&ksl[(kb * 144 + tt * 16 + fm) * 32 + fq * 8];
        acc[tt] = __builtin_amdgcn_mfma_f32_16x16x32_bf16(a, b, acc[tt], 0, 0, 0);
      }
    }
    const float scale = 0.08838834764831845f;
#pragma unroll
    for (int r = 0; r < 4; ++r) {
      float m = -3.0e38f;
#pragma unroll
      for (int tt = 0; tt < 9; ++tt) {
        int t = tt * 16 + fm;
        if (t < 132) m = fmaxf(m, acc[tt][r] * scale);
      }
      for (int d = 1; d < 16; d <<= 1) m = fmaxf(m, __shfl_xor(m, d));
      float e[10];
      float sum = 0.f;
#pragma unroll
      for (int tt = 0; tt < 10; ++tt) {
        int t = tt * 16 + fm;
        float ev = 0.f;
        if (t < 132) ev = __expf(acc[tt][r] * scale - m);
        e[tt] = ev; sum += ev;
      }
      for (int d = 1; d < 16; d <<= 1) sum += __shfl_xor(sum, d);
      const float inv = 1.f / sum;
      const int s = s0 + fq * 4 + r;
#pragma unroll
      for (int tt = 0; tt < 10; ++tt) {
        bf16 pv = __float2bfloat16(e[tt] * inv);
        pl[s * 168 + tt * 16 + fm] = *(const short*)&pv;
      }
    }
  } else {
    for (int ch = tid - 256; ch < 132 * 32; ch += 256) {
      int t = ch >> 5, d4 = (ch & 31) * 4;
      const unsigned short* src;
      if (t < 64) src = kv_r + 1024 + (size_t)t * str_r;
      else if (t < 68) src = vp + (size_t)(t - 64) * 1024 + h * 128;
      else src = kv_x + 1024 + (size_t)(t - 68) * str_x;
      uint2 w = *(const uint2*)(src + d4);
      vt[(d4 + 0) * 168 + t] = (short)(w.x & 0xffffu);
      vt[(d4 + 1) * 168 + t] = (short)(w.x >> 16);
      vt[(d4 + 2) * 168 + t] = (short)(w.y & 0xffffu);
      vt[(d4 + 3) * 168 + t] = (short)(w.y >> 16);
    }
    for (int ch = tid - 256; ch < 128 * 32; ch += 256) {
      int d = ch >> 5, tp = 132 + (ch & 31);
      vt[d * 168 + tp] = 0;
    }
  }
  __syncthreads();

  const int dt = wave;
  bf16x8 af[5];
#pragma unroll
  for (int kb = 0; kb < 5; ++kb)
    af[kb] = *(const bf16x8*)&vt[(dt * 16 + fm) * 168 + kb * 32 + fq * 8];
#pragma unroll
  for (int st = 0; st < 4; ++st) {
    f32x4 o = (f32x4){0.f, 0.f, 0.f, 0.f};
#pragma unroll
    for (int kb = 0; kb < 5; ++kb) {
      const bf16x8 bp = *(const bf16x8*)&pl[(st * 16 + fm) * 168 + kb * 32 + fq * 8];
      o = __builtin_amdgcn_mfma_f32_16x16x32_bf16(af[kb], bp, o, 0, 0, 0);
    }
    const int s = st * 16 + fm;
    bf16 b0 = __float2bfloat16(o[0]), b1 = __float2bfloat16(o[1]);
    bf16 b2 = __float2bfloat16(o[2]), b3 = __float2bfloat16(o[3]);
    uint2 w;
    w.x = ((unsigned)(*(unsigned short*)&b1) << 16) | (*(unsigned short*)&b0);
    w.y = ((unsigned)(*(unsigned short*)&b3) << 16) | (*(unsigned short*)&b2);
    *(uint2*)((unsigned short*)outg + obase + (size_t)s * 1024 + dt * 16 + fq * 4) = w;
  }
}

extern "C" void kernel_launch(void* const* d_in, const int* in_sizes, int n_in,
                              void* d_out, int out_size, void* d_ws, size_t ws_size,
                              hipStream_t stream)
{
  (void)n_in; (void)out_size;
  const int R = 16384, Cd = 1024;

  char* ws = (char*)d_ws;
  size_t off = 0;
  auto alloc = [&](size_t bytes) -> void* {
    void* p = ws + off;
    off += (bytes + 255) & ~(size_t)255;
    return p;
  };

  int* flag = (int*)alloc(256);
  // packed x-projection weights [Wkk | Wvv | Wqq | Wm1] rows (3200 x 1024)
  bf16* W4    = (bf16*)alloc((size_t)3200 * Cd * sizeof(bf16));
  bf16* bias4 = (bf16*)alloc(3200 * sizeof(bf16));
  bf16* T     = (bf16*)alloc((size_t)Cd * Cd * sizeof(bf16));  // transpose scratch
  bf16* Wc    = (bf16*)alloc((size_t)2048 * 128 * sizeof(bf16));
  bf16* kp    = (bf16*)alloc((size_t)4 * Cd * sizeof(bf16));
  bf16* vp    = (bf16*)alloc((size_t)4 * Cd * sizeof(bf16));
  bf16* bkv   = (bf16*)alloc(2048 * sizeof(bf16));
  bf16* WqStk = (bf16*)alloc((size_t)1152 * Cd * sizeof(bf16)); // [mhaWq; mem_W1]
  bf16* nb[30];
  nb[0] = nullptr;
  for (int i = 1; i < 30; ++i) nb[i] = (bf16*)alloc((size_t)in_sizes[i] * sizeof(bf16));
  nb[16] = WqStk;                          // mhaWq -> rows 0..1023 of stack
  nb[5]  = WqStk + (size_t)1024 * Cd;      // mem_W1 -> rows 1024..1151
  const size_t fixed_end = off;

  // balanced chunk sizing; per-row scratch = 17152 B
  size_t avail = (ws_size > fixed_end + (1u << 20)) ? (ws_size - fixed_end - (1u << 20)) : 0;
  int crmax = (int)(avail / 17152);
  if (crmax > R) crmax = R;
  if (crmax < 128) crmax = 128;
  int nch = (R + crmax - 1) / crmax;
  int CR = ((R / nch + 127) / 128) * 128;
  while (CR * nch < R) CR += 128;

  const size_t chunk_start = off;
  const size_t RB = (size_t)CR * Cd * sizeof(bf16);
  bf16* Xc  = (bf16*)alloc(RB);                               // x(bf16) -> attn out
  bf16* QS4 = (bf16*)alloc((size_t)CR * 3200 * sizeof(bf16)); // [k_x|v_x|q|h1]
  bf16* h1b = (bf16*)alloc((size_t)CR * 128 * sizeof(bf16));
  bf16* h2b = (bf16*)alloc((size_t)CR * 128 * sizeof(bf16));
  bf16* Bb  = (bf16*)alloc(RB);                               // ao
  bf16* KVr = (bf16*)alloc(2 * RB);                           // [k_r | v_r]
  bf16* Cc  = (bf16*)alloc(RB);                               // gin
  const size_t chunk_bytes = off - chunk_start;

  dim3 blk(256);
  // grid = (Mt, Nt): m-tile fastest -> xcd = m_tile % 8 (Mt % 8 == 0)
  auto g128 = [](int M_, int N_) { return dim3((unsigned)(M_ / 128), (unsigned)(N_ / 128)); };

  // ---- preamble ----
  detect_kernel<<<1, 64, 0, stream>>>((const unsigned short*)d_in[24], flag);
  {
    ConvArgs a;
    int bs = 0;
    for (int i = 1; i < 30; ++i) {
      a.src[i - 1] = d_in[i];
      a.dst[i - 1] = nb[i];
      a.n[i - 1] = in_sizes[i];
      a.bstart[i - 1] = bs;
      bs += (in_sizes[i] + 255) / 256;
    }
    a.bstart[29] = bs;
    convall_kernel<<<dim3((unsigned)bs), blk, 0, stream>>>(a, flag);
  }
  const bf16 *pm = nb[1], *Wq = nb[2], *Wk = nb[3], *Wv = nb[4];
  const bf16 *mem_W1 = nb[5], *mem_b1 = nb[6], *ln1g = nb[7], *ln1b = nb[8];
  const bf16 *mem_W2 = nb[9], *mem_b2 = nb[10], *ln2g = nb[11], *ln2b = nb[12];
  const bf16 *mem_oW = nb[13], *mem_ob = nb[14], *mstate = nb[15];
  const bf16 *mhaWq = nb[16], *mhabq = nb[17], *mhaWk = nb[18], *mhabk = nb[19];
  const bf16 *mhaWv = nb[20], *mhabv = nb[21], *mhaWo = nb[22], *mhabo = nb[23];
  const bf16 *gn_g = nb[24], *gn_b = nb[25], *gateW = nb[26], *gateb = nb[27];
  const bf16 *outW = nb[28], *outb = nb[29];
  bf16* Wkk = W4;
  bf16* Wvv = W4 + (size_t)1024 * Cd;
  bf16* Wqq = W4 + (size_t)2048 * Cd;
  bf16* Wm1 = W4 + (size_t)3072 * Cd;

  // weight folds
  const bool use_ks = chunk_bytes >= (size_t)4 * 1152 * 1024 * sizeof(float);
  if (use_ks) {
    float* P = (float*)Xc;  // aliases dead chunk scratch
    transpose_kernel<<<dim3(16, 16), blk, 0, stream>>>(Wq, T, 1024, 1024);
    kgemm<<<dim3(9, 8, 4), blk, 0, stream>>>(WqStk, T, P, 1152, 1024, 1024, 1024);
    foldfin_kernel<<<dim3(4608), blk, 0, stream>>>(P, Wqq, 1152 * 1024);
    transpose_kernel<<<dim3(16, 16), blk, 0, stream>>>(Wk, T, 1024, 1024);
    kgemm<<<dim3(8, 8, 4), blk, 0, stream>>>(mhaWk, T, P, 1024, 1024, 1024, 1024);
    foldfin_kernel<<<dim3(4096), blk, 0, stream>>>(P, Wkk, 1024 * 1024);
    transpose_kernel<<<dim3(16, 16), blk, 0, stream>>>(Wv, T, 1024, 1024);
    kgemm<<<dim3(8, 8, 4), blk, 0, stream>>>(mhaWv, T, P, 1024, 1024, 1024, 1024);
    foldfin_kernel<<<dim3(4096), blk, 0, stream>>>(P, Wvv, 1024 * 1024);
    transpose_kernel<<<dim3(2, 16), blk, 0, stream>>>(mem_oW, T, 1024, 128);
    kgemm<<<dim3(16, 1, 4), blk, 0, stream>>>(W4, T, P, 2048, 128, 1024, 1024);
    foldfin_kernel<<<dim3(1024), blk, 0, stream>>>(P, Wc, 2048 * 128);
  } else {
    transpose_kernel<<<dim3(16, 16), blk, 0, stream>>>(Wq, T, 1024, 1024);
    mgemm<bf16, ACT_NONE, false><<<g128(1024, 1024), blk, 0, stream>>>(
        mhaWq, T, nullptr, Wqq, 1024, 1024, 1024, 1024, 1024, nullptr, nullptr, 0, nullptr, 0);
    mgemm<bf16, ACT_NONE, false><<<g128(128, 1024), blk, 0, stream>>>(
        mem_W1, T, nullptr, Wm1, 128, 1024, 1024, 1024, 1024, nullptr, nullptr, 0, nullptr, 0);
    transpose_kernel<<<dim3(16, 16), blk, 0, stream>>>(Wk, T, 1024, 1024);
    mgemm<bf16, ACT_NONE, false><<<g128(1024, 1024), blk, 0, stream>>>(
        mhaWk, T, nullptr, Wkk, 1024, 1024, 1024, 1024, 1024, nullptr, nullptr, 0, nullptr, 0);
    transpose_kernel<<<dim3(16, 16), blk, 0, stream>>>(Wv, T, 1024, 1024);
    mgemm<bf16, ACT_NONE, false><<<g128(1024, 1024), blk, 0, stream>>>(
        mhaWv, T, nullptr, Wvv, 1024, 1024, 1024, 1024, 1024, nullptr, nullptr, 0, nullptr, 0);
    transpose_kernel<<<dim3(2, 16), blk, 0, stream>>>(mem_oW, T, 1024, 128);
    mgemm<bf16, ACT_NONE, false><<<g128(2048, 128), blk, 0, stream>>>(
        W4, T, nullptr, Wc, 2048, 128, 1024, 1024, 128, nullptr, nullptr, 0, nullptr, 0);
  }
  pack_bias4<<<13, blk, 0, stream>>>(mhabk, mhabv, mhabq, mem_b1, bias4);
  kpvp_kernel<<<dim3(512), blk, 0, stream>>>(pm, mem_ob, W4, bias4, kp, vp, bkv);

  for (int r0 = 0; r0 < R; r0 += CR) {
    const int cr = (R - r0 < CR) ? (R - r0) : CR;
    const int n = cr * Cd;
    conv_kernel<<<dim3((n + 255) / 256), blk, 0, stream>>>(d_in[0], Xc, n, (size_t)r0 * Cd, flag);

    // packed x-projection: [k_x | v_x | q | h1=silu(...)]
    mgemm<bf16, ACT_PSILU, true><<<g128(cr, 3200), blk, 0, stream>>>(
        Xc, W4, bias4, QS4, cr, 3200, 1024, 1024, 3200, nullptr, nullptr, 0, nullptr, 3072);

    // memory net tail: ln1 -> W2 -> ln2(+mstate) -> folded KVr (K=128)
    ln_kernel<bf16, bf16, false, 128, 128><<<cr, 128, 0, stream>>>(
        QS4 + 3072, ln1g, ln1b, nullptr, h2b, 3200);
    mgemm<bf16, ACT_NONE, true><<<g128(cr, 128), blk, 0, stream>>>(
        h2b, mem_W2, mem_b2, h1b, cr, 128, 128, 128, 128, nullptr, nullptr, 0, nullptr, 0);
    ln_kernel<bf16, bf16, true, 128, 128><<<cr, 128, 0, stream>>>(h1b, ln2g, ln2b, mstate, h2b, 128);
    mgemm<bf16, ACT_NONE, true><<<g128(cr, 2048), blk, 0, stream>>>(
        h2b, Wc, bkv, KVr, cr, 2048, 128, 128, 2048, nullptr, nullptr, 0, nullptr, 0);

    attn_kernel<<<dim3((cr / 64) * 8), dim3(512), 0, stream>>>(
        QS4 + 2048, 3200, KVr, 2048, QS4, 3200, kp, vp, Xc);

    // ao, gate-norm, fused gate*ao+x, final projection
    mgemm<bf16, ACT_NONE, true><<<g128(cr, Cd), blk, 0, stream>>>(
        Xc, mhaWo, mhabo, Bb, cr, Cd, Cd, Cd, Cd, nullptr, nullptr, 0, nullptr, 0);
    ln_kernel<bf16, bf16, false, 1024, 256><<<cr, 256, 0, stream>>>(Bb, gn_g, gn_b, nullptr, Cc, Cd);
    mgemm<bf16, ACT_GATE, true><<<g128(cr, Cd), blk, 0, stream>>>(
        Cc, gateW, gateb, Xc, cr, Cd, Cd, Cd, Cd, Bb, d_in[0], (size_t)r0 * Cd, flag, 0);
    mgemm<float, ACT_NONE, true><<<g128(cr, Cd), blk, 0, stream>>>(
        Xc, outW, outb, (float*)d_out + (size_t)r0 * Cd, cr, Cd, Cd, Cd, Cd,
        nullptr, nullptr, 0, nullptr, 0);
  }
}

// Round 6
// 878.749 us; speedup vs baseline: 1.3793x; 1.0061x over previous
//
#include <hip/hip_runtime.h>
#include <hip/hip_bf16.h>
#include <math.h>

// TitanLongTermMemory — round 12 (resubmit; bench hit GPUAcquisitionTimeout).
// r11 post-mortem: x-proj locality fixed (FETCH 49.5MB) but engine-bound at
// 557 TF / MfmaUtil 23% / 6.5M LDS bank conflicts. This round:
//  - mgemm: LDS double-buffer + counted s_waitcnt vmcnt(4) (never 0 in-loop)
//    + raw s_barrier — loads for tile t+2 stay in flight across barriers.
//  - T2 XOR swizzle (G^=(row>>1)&3 on 16B groups), applied BOTH sides:
//    pre-swizzled global source col for global_load_lds + same XOR on read.
//    8-way conflict -> 2-way (free).
//  - conv_kernel vectorized (float4x2 -> short8).
// Expected: 884 -> ~780us; x-proj 98.5 -> ~75us, conflicts <0.5M.

using bf16 = __hip_bfloat16;

typedef __attribute__((ext_vector_type(8))) short bf16x8;
typedef __attribute__((ext_vector_type(4))) float f32x4;

__device__ __forceinline__ float ldf(const bf16* p) { return __bfloat162float(*p); }
__device__ __forceinline__ float ldf(const float* p) { return *p; }
__device__ __forceinline__ void stf(bf16* p, float v) { *p = __float2bfloat16(v); }
__device__ __forceinline__ void stf(float* p, float v) { *p = v; }
__device__ __forceinline__ float b2f(const bf16& b) { return __bfloat162float(b); }
__device__ __forceinline__ float bsf(short s) {
  union { unsigned u; float f; } cv;
  cv.u = (unsigned)(unsigned short)s << 16;
  return cv.f;
}

enum { ACT_NONE = 0, ACT_SILU = 1, ACT_SIGMOID = 2, ACT_GATE = 3, ACT_PSILU = 4 };

__global__ void detect_kernel(const unsigned short* g, int* flag) {
  if (threadIdx.x == 0) *flag = (g[0] != 0) ? 1 : 0;
}

// ---- single fused dtype-normalize for all non-x inputs ----------------------
struct ConvArgs {
  const void* src[29];
  bf16* dst[29];
  int n[29];
  int bstart[30];
};

__global__ __launch_bounds__(256) void convall_kernel(ConvArgs a, const int* __restrict__ flag) {
  int b = blockIdx.x;
  int ti = 0;
  while (ti < 28 && b >= a.bstart[ti + 1]) ++ti;
  int i = (b - a.bstart[ti]) * 256 + threadIdx.x;
  if (i >= a.n[ti]) return;
  if (*flag) a.dst[ti][i] = ((const bf16*)a.src[ti])[i];
  else a.dst[ti][i] = __float2bfloat16(((const float*)a.src[ti])[i]);
}

// vectorized x-chunk convert: 8 elems/thread
__global__ __launch_bounds__(256) void conv_kernel(
    const void* __restrict__ src, bf16* __restrict__ dst, int n, size_t src_off,
    const int* __restrict__ flag) {
  int i = (blockIdx.x * 256 + threadIdx.x) * 8;
  if (i >= n) return;
  if (*flag) {
    *(uint4*)((unsigned short*)dst + i) =
        *(const uint4*)((const unsigned short*)src + src_off + i);
  } else {
    const float* s = (const float*)src + src_off + i;
    const float4 a = *(const float4*)s;
    const float4 b = *(const float4*)(s + 4);
    bf16 t[8] = {__float2bfloat16(a.x), __float2bfloat16(a.y),
                 __float2bfloat16(a.z), __float2bfloat16(a.w),
                 __float2bfloat16(b.x), __float2bfloat16(b.y),
                 __float2bfloat16(b.z), __float2bfloat16(b.w)};
    *(uint4*)((unsigned short*)dst + i) = *(const uint4*)t;
  }
}

// bias4 = [bk(1024) | bv(1024) | bq(1024) | mem_b1(128)]
__global__ __launch_bounds__(256) void pack_bias4(
    const bf16* __restrict__ bk, const bf16* __restrict__ bv,
    const bf16* __restrict__ bq, const bf16* __restrict__ b1,
    bf16* __restrict__ o) {
  int j = blockIdx.x * 256 + threadIdx.x;
  if (j >= 3200) return;
  float v;
  if (j < 1024) v = b2f(bk[j]);
  else if (j < 2048) v = b2f(bv[j - 1024]);
  else if (j < 3072) v = b2f(bq[j - 2048]);
  else v = b2f(b1[j - 3072]);
  o[j] = __float2bfloat16(v);
}

// 64x64-tile transpose: dst[c][r] = src[r][c]; src rows x cols (ld=cols).
__global__ __launch_bounds__(256) void transpose_kernel(
    const bf16* __restrict__ srcb, bf16* __restrict__ dstb, int rows, int cols) {
  __shared__ unsigned short t[64][72];  // 144B row stride (16B-aligned)
  const unsigned short* src = (const unsigned short*)srcb;
  unsigned short* dst = (unsigned short*)dstb;
  const int r0 = blockIdx.y * 64, c0 = blockIdx.x * 64;
  for (int e = threadIdx.x; e < 64 * 8; e += 256) {
    int r = e >> 3, c8 = e & 7;
    uint4 v = *(const uint4*)(src + (size_t)(r0 + r) * cols + c0 + c8 * 8);
    *(uint4*)&t[r][c8 * 8] = v;
  }
  __syncthreads();
  for (int e = threadIdx.x; e < 64 * 8; e += 256) {
    int c = e >> 3, r8 = (e & 7) * 8;
    unsigned short v[8];
#pragma unroll
    for (int j = 0; j < 8; ++j) v[j] = t[r8 + j][c];
    *(uint4*)(dst + (size_t)(c0 + c) * rows + r0 + r8) = *(uint4*)v;
  }
}

// ---- fused kp/vp/bkv GEMV over W4 rows 0..2047 ([Wkk|Wvv]) ------------------
__global__ __launch_bounds__(256) void kpvp_kernel(
    const bf16* __restrict__ pmb, const bf16* __restrict__ mobb,
    const bf16* __restrict__ Wb, const bf16* __restrict__ bias4b,
    bf16* __restrict__ kp, bf16* __restrict__ vp, bf16* __restrict__ bkv)
{
  const short* pm = (const short*)pmb;
  const short* mob = (const short*)mobb;
  const short* W = (const short*)Wb;
  const int wave = threadIdx.x >> 6, lane = threadIdx.x & 63;
  const int c = blockIdx.x * 4 + wave;  // 0..2047
  const short* wrow = W + (size_t)c * 1024 + lane * 16;
  const bf16x8 w0 = *(const bf16x8*)wrow;
  const bf16x8 w1 = *(const bf16x8*)(wrow + 8);
  float acc[5];
#pragma unroll
  for (int m = 0; m < 5; ++m) {
    const short* prow = (m < 4) ? (pm + m * 1024 + lane * 16) : (mob + lane * 16);
    const bf16x8 p0 = *(const bf16x8*)prow;
    const bf16x8 p1 = *(const bf16x8*)(prow + 8);
    float s = 0.f;
#pragma unroll
    for (int j = 0; j < 8; ++j) s += bsf(w0[j]) * bsf(p0[j]) + bsf(w1[j]) * bsf(p1[j]);
    acc[m] = s;
  }
#pragma unroll
  for (int d = 1; d < 64; d <<= 1) {
#pragma unroll
    for (int m = 0; m < 5; ++m) acc[m] += __shfl_xor(acc[m], d);
  }
  if (lane == 0) {
    const float bv = b2f(bias4b[c]);
    bf16* dst = (c < 1024) ? (kp + c) : (vp + (c - 1024));
#pragma unroll
    for (int m = 0; m < 4; ++m) stf(dst + m * 1024, acc[m] + bv);
    stf(&bkv[c], acc[4] + bv);
  }
}

// ---------------- MFMA GEMM: C[M,N] = act(A[M,K] @ B[N,K]^T + bias) ----------
// Grid = (Mt, Nt): m-tile fastest => xcd = m_tile % 8 fixed.
// K-loop: 2-deep LDS double-buffer, counted vmcnt(4) (drain 0 only on the last
// tile), raw s_barrier. LDS 16B-group XOR swizzle (G ^= (row>>1)&3), applied
// on the global SOURCE col (gl_lds writes linearly) and on the ds_read col.
__device__ __forceinline__ void gl_lds16(const short* g, short* l) {
  __builtin_amdgcn_global_load_lds(
      (const __attribute__((address_space(1))) void*)g,
      (__attribute__((address_space(3))) void*)l, 16, 0, 0);
}

template <typename TC, int ACT, bool HAS_BIAS>
__global__ __launch_bounds__(256) void mgemm(
    const bf16* __restrict__ Ab, const bf16* __restrict__ Bw,
    const bf16* __restrict__ bias, TC* __restrict__ C,
    int M, int N, int K, int lda, int ldc,
    const bf16* __restrict__ ao, const void* __restrict__ xsrc, size_t xoff,
    const int* __restrict__ flag, int pn)
{
  __shared__ short As[2][128 * 32];
  __shared__ short Bs[2][128 * 32];
  const short* A = (const short*)Ab;
  const short* B = (const short*)Bw;
  const int tid = threadIdx.x;
  const int m0 = blockIdx.x * 128, n0 = blockIdx.y * 128;
  const int wave = tid >> 6, lane = tid & 63;
  const int wm = (wave & 1) * 64, wn = (wave >> 1) * 64;
  const int fm = lane & 15;
  const int fq = lane >> 4;
  const int fks = (fq ^ ((fm >> 1) & 3)) * 8;   // swizzled read col (shorts)

  const int srow = tid >> 2;
  const int scol = ((tid & 3) ^ ((tid >> 3) & 3)) * 8;  // swizzled source col
  const short* gA0 = A + (size_t)(m0 + srow) * lda + scol;
  const short* gA1 = A + (size_t)(m0 + 64 + srow) * lda + scol;
  const short* gB0 = B + (size_t)(n0 + srow) * K + scol;
  const short* gB1 = B + (size_t)(n0 + 64 + srow) * K + scol;

  f32x4 acc[4][4] = {};
  const int NT = K >> 5;

#define STAGE(buf, k0)                              \
  do {                                              \
    gl_lds16(gA0 + (k0), &As[buf][tid * 8]);        \
    gl_lds16(gA1 + (k0), &As[buf][(256 + tid) * 8]);\
    gl_lds16(gB0 + (k0), &Bs[buf][tid * 8]);        \
    gl_lds16(gB1 + (k0), &Bs[buf][(256 + tid) * 8]);\
  } while (0)

  STAGE(0, 0);
  STAGE(1, 32);

  for (int kt = 0; kt < NT; ++kt) {
    const int cur = kt & 1;
    if (kt == NT - 1) asm volatile("s_waitcnt vmcnt(0)" ::: "memory");
    else              asm volatile("s_waitcnt vmcnt(4)" ::: "memory");
    __builtin_amdgcn_s_barrier();
    bf16x8 af[4], bfr[4];
#pragma unroll
    for (int i = 0; i < 4; ++i)
      af[i] = *(const bf16x8*)&As[cur][(wm + i * 16 + fm) * 32 + fks];
#pragma unroll
    for (int j = 0; j < 4; ++j)
      bfr[j] = *(const bf16x8*)&Bs[cur][(wn + j * 16 + fm) * 32 + fks];
#pragma unroll
    for (int i = 0; i < 4; ++i)
#pragma unroll
      for (int j = 0; j < 4; ++j)
        acc[i][j] = __builtin_amdgcn_mfma_f32_16x16x32_bf16(af[i], bfr[j], acc[i][j], 0, 0, 0);
    asm volatile("s_waitcnt lgkmcnt(0)" ::: "memory");
    __builtin_amdgcn_s_barrier();
    if (kt + 2 < NT) STAGE(cur, (kt + 2) * 32);
  }
#undef STAGE

  const int rg = fq * 4;
#pragma unroll
  for (int i = 0; i < 4; ++i) {
#pragma unroll
    for (int j = 0; j < 4; ++j) {
      const int n = n0 + wn + j * 16 + fm;
      float bv = 0.f;
      if (HAS_BIAS) bv = b2f(bias[n]);
#pragma unroll
      for (int r = 0; r < 4; ++r) {
        const int m = m0 + wm + i * 16 + rg + r;
        float v = acc[i][j][r] + bv;
        if (ACT == ACT_SILU) v = v / (1.f + __expf(-v));
        if (ACT == ACT_PSILU) { if (n >= pn) v = v / (1.f + __expf(-v)); }
        if (ACT == ACT_SIGMOID) v = 1.f / (1.f + __expf(-v));
        if (ACT == ACT_GATE) {
          v = 1.f / (1.f + __expf(-v));
          const size_t e = (size_t)m * 1024 + n;
          const float xv = *flag ? b2f(((const bf16*)xsrc)[xoff + e])
                                 : ((const float*)xsrc)[xoff + e];
          v = v * b2f(ao[e]) + xv;
        }
        stf(&C[(size_t)m * ldc + n], v);
      }
    }
  }
}

// ---- K-split fold GEMM (preamble): P[z] = A @ B^T over K-slice z (KS=4) ----
__global__ __launch_bounds__(256) void kgemm(
    const bf16* __restrict__ Ab, const bf16* __restrict__ Bw,
    float* __restrict__ P, int M, int N, int K, int lda)
{
  __shared__ short As[128 * 32];
  __shared__ short Bs[128 * 32];
  const short* A = (const short*)Ab;
  const short* B = (const short*)Bw;
  const int tid = threadIdx.x;
  const int m0 = blockIdx.x * 128, n0 = blockIdx.y * 128;
  const int kb = blockIdx.z * (K >> 2), ke = kb + (K >> 2);
  const int wave = tid >> 6, lane = tid & 63;
  const int wm = (wave & 1) * 64, wn = (wave >> 1) * 64;
  const int fm = lane & 15;
  const int fk = (lane >> 4) * 8;

  const int srow = tid >> 2, scol = (tid & 3) * 8;
  const short* gA0 = A + (size_t)(m0 + srow) * lda + scol;
  const short* gA1 = A + (size_t)(m0 + 64 + srow) * lda + scol;
  const short* gB0 = B + (size_t)(n0 + srow) * K + scol;
  const short* gB1 = B + (size_t)(n0 + 64 + srow) * K + scol;
  short* lA0 = As + tid * 8;
  short* lA1 = As + (256 + tid) * 8;
  short* lB0 = Bs + tid * 8;
  short* lB1 = Bs + (256 + tid) * 8;

  f32x4 acc[4][4] = {};

  for (int k0 = kb; k0 < ke; k0 += 32) {
    gl_lds16(gA0 + k0, lA0);
    gl_lds16(gA1 + k0, lA1);
    gl_lds16(gB0 + k0, lB0);
    gl_lds16(gB1 + k0, lB1);
    __syncthreads();
    bf16x8 af[4], bfr[4];
#pragma unroll
    for (int i = 0; i < 4; ++i)
      af[i] = *(const bf16x8*)&As[(wm + i * 16 + fm) * 32 + fk];
#pragma unroll
    for (int j = 0; j < 4; ++j)
      bfr[j] = *(const bf16x8*)&Bs[(wn + j * 16 + fm) * 32 + fk];
#pragma unroll
    for (int i = 0; i < 4; ++i)
#pragma unroll
      for (int j = 0; j < 4; ++j)
        acc[i][j] = __builtin_amdgcn_mfma_f32_16x16x32_bf16(af[i], bfr[j], acc[i][j], 0, 0, 0);
    __syncthreads();
  }

  float* Cp = P + (size_t)blockIdx.z * ((size_t)M * N);
  const int rg = (lane >> 4) * 4;
#pragma unroll
  for (int i = 0; i < 4; ++i)
#pragma unroll
    for (int j = 0; j < 4; ++j) {
      const int n = n0 + wn + j * 16 + fm;
#pragma unroll
      for (int r = 0; r < 4; ++r) {
        const int m = m0 + wm + i * 16 + rg + r;
        Cp[(size_t)m * N + n] = acc[i][j][r];
      }
    }
}

// sum 4 K-slice partials -> bf16
__global__ __launch_bounds__(256) void foldfin_kernel(
    const float* __restrict__ P, bf16* __restrict__ o, int MN) {
  int i = blockIdx.x * 256 + threadIdx.x;
  if (i >= MN) return;
  float s = P[i] + P[i + (size_t)MN] + P[i + 2 * (size_t)MN] + P[i + 3 * (size_t)MN];
  o[i] = __float2bfloat16(s);
}

// Row LayerNorm over width W; optional post-LN add of a bf16 vector.
template <typename TI, typename TO, bool ADD, int W, int BS>
__global__ __launch_bounds__(BS) void ln_kernel(
    const TI* __restrict__ in, const bf16* __restrict__ g, const bf16* __restrict__ b,
    const bf16* __restrict__ addv, TO* __restrict__ out, int ldin)
{
  __shared__ float red[BS];
  const int row = blockIdx.x;
  const TI* rin = in + (size_t)row * ldin;
  TO* rout = out + (size_t)row * W;
  const int NP = W / BS;
  float v[NP];
  float s = 0.f;
#pragma unroll
  for (int i = 0; i < NP; ++i) { v[i] = ldf(&rin[threadIdx.x + i * BS]); s += v[i]; }
  red[threadIdx.x] = s; __syncthreads();
  for (int o = BS / 2; o > 0; o >>= 1) {
    if (threadIdx.x < o) red[threadIdx.x] += red[threadIdx.x + o];
    __syncthreads();
  }
  const float mean = red[0] / W;
  __syncthreads();
  float sq = 0.f;
#pragma unroll
  for (int i = 0; i < NP; ++i) { float d = v[i] - mean; sq += d * d; }
  red[threadIdx.x] = sq; __syncthreads();
  for (int o = BS / 2; o > 0; o >>= 1) {
    if (threadIdx.x < o) red[threadIdx.x] += red[threadIdx.x + o];
    __syncthreads();
  }
  const float rstd = rsqrtf(red[0] / W + 1e-5f);
#pragma unroll
  for (int i = 0; i < NP; ++i) {
    int c = threadIdx.x + i * BS;
    float o_ = (v[i] - mean) * rstd * b2f(g[c]) + b2f(b[c]);
    if (ADD) o_ += b2f(addv[c]);
    stf(&rout[c], o_);
  }
}

// ---------------- MFMA attention (XCD-chunked bid swizzle) ------------------
__global__ __launch_bounds__(512) void attn_kernel(
    const bf16* __restrict__ qg, int str_q,
    const bf16* __restrict__ krv, int str_r,
    const bf16* __restrict__ kxv, int str_x, const bf16* __restrict__ kpg,
    const bf16* __restrict__ vpg, bf16* __restrict__ outg)
{
  __shared__ short qs[4 * 64 * 32];
  __shared__ short ksl[4 * 144 * 32];
  __shared__ short vt[128 * 168];
  __shared__ short pl[64 * 168];

  const int tid = threadIdx.x;
  unsigned bid = blockIdx.x;
  {
    const unsigned nwg = gridDim.x;
    const unsigned q_ = nwg >> 3, r_ = nwg & 7;
    const unsigned xcd = bid & 7, loc = bid >> 3;
    bid = (xcd < r_ ? xcd * (q_ + 1) : r_ * (q_ + 1) + (xcd - r_) * q_) + loc;
  }
  const int seg = (int)(bid >> 3), h = (int)(bid & 7);
  const unsigned short* q = (const unsigned short*)qg + (size_t)seg * 64 * str_q + h * 128;
  const unsigned short* kv_r = (const unsigned short*)krv + (size_t)seg * 64 * str_r + h * 128;
  const unsigned short* kv_x = (const unsigned short*)kxv + (size_t)seg * 64 * str_x + h * 128;
  const unsigned short* kp = (const unsigned short*)kpg;
  const unsigned short* vp = (const unsigned short*)vpg;
  const size_t obase = (size_t)seg * 64 * 1024 + h * 128;

  for (int ch = tid; ch < 64 * 16; ch += 512) {
    int row = ch >> 4, k8 = ch & 15;
    uint4 v = *(const uint4*)(q + (size_t)row * str_q + k8 * 8);
    *(uint4*)&qs[((k8 >> 2) * 64 + row) * 32 + (k8 & 3) * 8] = v;
  }
  for (int ch = tid; ch < 132 * 16; ch += 512) {
    int t = ch >> 4, k8 = ch & 15;
    const unsigned short* src;
    if (t < 64) src = kv_r + (size_t)t * str_r;
    else if (t < 68) src = kp + (size_t)(t - 64) * 1024 + h * 128;
    else src = kv_x + (size_t)(t - 68) * str_x;
    uint4 v = *(const uint4*)(src + k8 * 8);
    *(uint4*)&ksl[((k8 >> 2) * 144 + t) * 32 + (k8 & 3) * 8] = v;
  }
  __syncthreads();

  const int wave = tid >> 6, lane = tid & 63;
  const int fm = lane & 15, fq = lane >> 4;

  if (wave < 4) {
    const int s0 = wave * 16;
    f32x4 acc[10];
#pragma unroll
    for (int tt = 0; tt < 10; ++tt) acc[tt] = (f32x4){0.f, 0.f, 0.f, 0.f};
#pragma unroll
    for (int kb = 0; kb < 4; ++kb) {
      const bf16x8 a = *(const bf16x8*)&qs[(kb * 64 + s0 + fm) * 32 + fq * 8];
#pragma unroll
      for (int tt = 0; tt < 9; ++tt) {
        const bf16x8 b = *(const bf16x8*)&ksl[(kb * 144 + tt * 16 + fm) * 32 + fq * 8];
        acc[tt] = __builtin_amdgcn_mfma_f32_16x16x32_bf16(a, b, acc[tt], 0, 0, 0);
      }
    }
    const float scale = 0.08838834764831845f;
#pragma unroll
    for (int r = 0; r < 4; ++r) {
      float m = -3.0e38f;
#pragma unroll
      for (int tt = 0; tt < 9; ++tt) {
        int t = tt * 16 + fm;
        if (t < 132) m = fmaxf(m, acc[tt][r] * scale);
      }
      for (int d = 1; d < 16; d <<= 1) m = fmaxf(m, __shfl_xor(m, d));
      float e[10];
      float sum = 0.f;
#pragma unroll
      for (int tt = 0; tt < 10; ++tt) {
        int t = tt * 16 + fm;
        float ev = 0.f;
        if (t < 132) ev = __expf(acc[tt][r] * scale - m);
        e[tt] = ev; sum += ev;
      }
      for (int d = 1; d < 16; d <<= 1) sum += __shfl_xor(sum, d);
      const float inv = 1.f / sum;
      const int s = s0 + fq * 4 + r;
#pragma unroll
      for (int tt = 0; tt < 10; ++tt) {
        bf16 pv = __float2bfloat16(e[tt] * inv);
        pl[s * 168 + tt * 16 + fm] = *(const short*)&pv;
      }
    }
  } else {
    for (int ch = tid - 256; ch < 132 * 32; ch += 256) {
      int t = ch >> 5, d4 = (ch & 31) * 4;
      const unsigned short* src;
      if (t < 64) src = kv_r + 1024 + (size_t)t * str_r;
      else if (t < 68) src = vp + (size_t)(t - 64) * 1024 + h * 128;
      else src = kv_x + 1024 + (size_t)(t - 68) * str_x;
      uint2 w = *(const uint2*)(src + d4);
      vt[(d4 + 0) * 168 + t] = (short)(w.x & 0xffffu);
      vt[(d4 + 1) * 168 + t] = (short)(w.x >> 16);
      vt[(d4 + 2) * 168 + t] = (short)(w.y & 0xffffu);
      vt[(d4 + 3) * 168 + t] = (short)(w.y >> 16);
    }
    for (int ch = tid - 256; ch < 128 * 32; ch += 256) {
      int d = ch >> 5, tp = 132 + (ch & 31);
      vt[d * 168 + tp] = 0;
    }
  }
  __syncthreads();

  const int dt = wave;
  bf16x8 af[5];
#pragma unroll
  for (int kb = 0; kb < 5; ++kb)
    af[kb] = *(const bf16x8*)&vt[(dt * 16 + fm) * 168 + kb * 32 + fq * 8];
#pragma unroll
  for (int st = 0; st < 4; ++st) {
    f32x4 o = (f32x4){0.f, 0.f, 0.f, 0.f};
#pragma unroll
    for (int kb = 0; kb < 5; ++kb) {
      const bf16x8 bp = *(const bf16x8*)&pl[(st * 16 + fm) * 168 + kb * 32 + fq * 8];
      o = __builtin_amdgcn_mfma_f32_16x16x32_bf16(af[kb], bp, o, 0, 0, 0);
    }
    const int s = st * 16 + fm;
    bf16 b0 = __float2bfloat16(o[0]), b1 = __float2bfloat16(o[1]);
    bf16 b2 = __float2bfloat16(o[2]), b3 = __float2bfloat16(o[3]);
    uint2 w;
    w.x = ((unsigned)(*(unsigned short*)&b1) << 16) | (*(unsigned short*)&b0);
    w.y = ((unsigned)(*(unsigned short*)&b3) << 16) | (*(unsigned short*)&b2);
    *(uint2*)((unsigned short*)outg + obase + (size_t)s * 1024 + dt * 16 + fq * 4) = w;
  }
}

extern "C" void kernel_launch(void* const* d_in, const int* in_sizes, int n_in,
                              void* d_out, int out_size, void* d_ws, size_t ws_size,
                              hipStream_t stream)
{
  (void)n_in; (void)out_size;
  const int R = 16384, Cd = 1024;

  char* ws = (char*)d_ws;
  size_t off = 0;
  auto alloc = [&](size_t bytes) -> void* {
    void* p = ws + off;
    off += (bytes + 255) & ~(size_t)255;
    return p;
  };

  int* flag = (int*)alloc(256);
  // packed x-projection weights [Wkk | Wvv | Wqq | Wm1] rows (3200 x 1024)
  bf16* W4    = (bf16*)alloc((size_t)3200 * Cd * sizeof(bf16));
  bf16* bias4 = (bf16*)alloc(3200 * sizeof(bf16));
  bf16* T     = (bf16*)alloc((size_t)Cd * Cd * sizeof(bf16));  // transpose scratch
  bf16* Wc    = (bf16*)alloc((size_t)2048 * 128 * sizeof(bf16));
  bf16* kp    = (bf16*)alloc((size_t)4 * Cd * sizeof(bf16));
  bf16* vp    = (bf16*)alloc((size_t)4 * Cd * sizeof(bf16));
  bf16* bkv   = (bf16*)alloc(2048 * sizeof(bf16));
  bf16* WqStk = (bf16*)alloc((size_t)1152 * Cd * sizeof(bf16)); // [mhaWq; mem_W1]
  bf16* nb[30];
  nb[0] = nullptr;
  for (int i = 1; i < 30; ++i) nb[i] = (bf16*)alloc((size_t)in_sizes[i] * sizeof(bf16));
  nb[16] = WqStk;                          // mhaWq -> rows 0..1023 of stack
  nb[5]  = WqStk + (size_t)1024 * Cd;      // mem_W1 -> rows 1024..1151
  const size_t fixed_end = off;

  // balanced chunk sizing; per-row scratch = 17152 B
  size_t avail = (ws_size > fixed_end + (1u << 20)) ? (ws_size - fixed_end - (1u << 20)) : 0;
  int crmax = (int)(avail / 17152);
  if (crmax > R) crmax = R;
  if (crmax < 128) crmax = 128;
  int nch = (R + crmax - 1) / crmax;
  int CR = ((R / nch + 127) / 128) * 128;
  while (CR * nch < R) CR += 128;

  const size_t chunk_start = off;
  const size_t RB = (size_t)CR * Cd * sizeof(bf16);
  bf16* Xc  = (bf16*)alloc(RB);                               // x(bf16) -> attn out
  bf16* QS4 = (bf16*)alloc((size_t)CR * 3200 * sizeof(bf16)); // [k_x|v_x|q|h1]
  bf16* h1b = (bf16*)alloc((size_t)CR * 128 * sizeof(bf16));
  bf16* h2b = (bf16*)alloc((size_t)CR * 128 * sizeof(bf16));
  bf16* Bb  = (bf16*)alloc(RB);                               // ao
  bf16* KVr = (bf16*)alloc(2 * RB);                           // [k_r | v_r]
  bf16* Cc  = (bf16*)alloc(RB);                               // gin
  const size_t chunk_bytes = off - chunk_start;

  dim3 blk(256);
  // grid = (Mt, Nt): m-tile fastest -> xcd = m_tile % 8 (Mt % 8 == 0)
  auto g128 = [](int M_, int N_) { return dim3((unsigned)(M_ / 128), (unsigned)(N_ / 128)); };

  // ---- preamble ----
  detect_kernel<<<1, 64, 0, stream>>>((const unsigned short*)d_in[24], flag);
  {
    ConvArgs a;
    int bs = 0;
    for (int i = 1; i < 30; ++i) {
      a.src[i - 1] = d_in[i];
      a.dst[i - 1] = nb[i];
      a.n[i - 1] = in_sizes[i];
      a.bstart[i - 1] = bs;
      bs += (in_sizes[i] + 255) / 256;
    }
    a.bstart[29] = bs;
    convall_kernel<<<dim3((unsigned)bs), blk, 0, stream>>>(a, flag);
  }
  const bf16 *pm = nb[1], *Wq = nb[2], *Wk = nb[3], *Wv = nb[4];
  const bf16 *mem_W1 = nb[5], *mem_b1 = nb[6], *ln1g = nb[7], *ln1b = nb[8];
  const bf16 *mem_W2 = nb[9], *mem_b2 = nb[10], *ln2g = nb[11], *ln2b = nb[12];
  const bf16 *mem_oW = nb[13], *mem_ob = nb[14], *mstate = nb[15];
  const bf16 *mhaWq = nb[16], *mhabq = nb[17], *mhaWk = nb[18], *mhabk = nb[19];
  const bf16 *mhaWv = nb[20], *mhabv = nb[21], *mhaWo = nb[22], *mhabo = nb[23];
  const bf16 *gn_g = nb[24], *gn_b = nb[25], *gateW = nb[26], *gateb = nb[27];
  const bf16 *outW = nb[28], *outb = nb[29];
  bf16* Wkk = W4;
  bf16* Wvv = W4 + (size_t)1024 * Cd;
  bf16* Wqq = W4 + (size_t)2048 * Cd;
  bf16* Wm1 = W4 + (size_t)3072 * Cd;

  // weight folds
  const bool use_ks = chunk_bytes >= (size_t)4 * 1152 * 1024 * sizeof(float);
  if (use_ks) {
    float* P = (float*)Xc;  // aliases dead chunk scratch
    transpose_kernel<<<dim3(16, 16), blk, 0, stream>>>(Wq, T, 1024, 1024);
    kgemm<<<dim3(9, 8, 4), blk, 0, stream>>>(WqStk, T, P, 1152, 1024, 1024, 1024);
    foldfin_kernel<<<dim3(4608), blk, 0, stream>>>(P, Wqq, 1152 * 1024);
    transpose_kernel<<<dim3(16, 16), blk, 0, stream>>>(Wk, T, 1024, 1024);
    kgemm<<<dim3(8, 8, 4), blk, 0, stream>>>(mhaWk, T, P, 1024, 1024, 1024, 1024);
    foldfin_kernel<<<dim3(4096), blk, 0, stream>>>(P, Wkk, 1024 * 1024);
    transpose_kernel<<<dim3(16, 16), blk, 0, stream>>>(Wv, T, 1024, 1024);
    kgemm<<<dim3(8, 8, 4), blk, 0, stream>>>(mhaWv, T, P, 1024, 1024, 1024, 1024);
    foldfin_kernel<<<dim3(4096), blk, 0, stream>>>(P, Wvv, 1024 * 1024);
    transpose_kernel<<<dim3(2, 16), blk, 0, stream>>>(mem_oW, T, 1024, 128);
    kgemm<<<dim3(16, 1, 4), blk, 0, stream>>>(W4, T, P, 2048, 128, 1024, 1024);
    foldfin_kernel<<<dim3(1024), blk, 0, stream>>>(P, Wc, 2048 * 128);
  } else {
    transpose_kernel<<<dim3(16, 16), blk, 0, stream>>>(Wq, T, 1024, 1024);
    mgemm<bf16, ACT_NONE, false><<<g128(1024, 1024), blk, 0, stream>>>(
        mhaWq, T, nullptr, Wqq, 1024, 1024, 1024, 1024, 1024, nullptr, nullptr, 0, nullptr, 0);
    mgemm<bf16, ACT_NONE, false><<<g128(128, 1024), blk, 0, stream>>>(
        mem_W1, T, nullptr, Wm1, 128, 1024, 1024, 1024, 1024, nullptr, nullptr, 0, nullptr, 0);
    transpose_kernel<<<dim3(16, 16), blk, 0, stream>>>(Wk, T, 1024, 1024);
    mgemm<bf16, ACT_NONE, false><<<g128(1024, 1024), blk, 0, stream>>>(
        mhaWk, T, nullptr, Wkk, 1024, 1024, 1024, 1024, 1024, nullptr, nullptr, 0, nullptr, 0);
    transpose_kernel<<<dim3(16, 16), blk, 0, stream>>>(Wv, T, 1024, 1024);
    mgemm<bf16, ACT_NONE, false><<<g128(1024, 1024), blk, 0, stream>>>(
        mhaWv, T, nullptr, Wvv, 1024, 1024, 1024, 1024, 1024, nullptr, nullptr, 0, nullptr, 0);
    transpose_kernel<<<dim3(2, 16), blk, 0, stream>>>(mem_oW, T, 1024, 128);
    mgemm<bf16, ACT_NONE, false><<<g128(2048, 128), blk, 0, stream>>>(
        W4, T, nullptr, Wc, 2048, 128, 1024, 1024, 128, nullptr, nullptr, 0, nullptr, 0);
  }
  pack_bias4<<<13, blk, 0, stream>>>(mhabk, mhabv, mhabq, mem_b1, bias4);
  kpvp_kernel<<<dim3(512), blk, 0, stream>>>(pm, mem_ob, W4, bias4, kp, vp, bkv);

  for (int r0 = 0; r0 < R; r0 += CR) {
    const int cr = (R - r0 < CR) ? (R - r0) : CR;
    const int n = cr * Cd;
    conv_kernel<<<dim3((n / 8 + 255) / 256), blk, 0, stream>>>(
        d_in[0], Xc, n, (size_t)r0 * Cd, flag);

    // packed x-projection: [k_x | v_x | q | h1=silu(...)]
    mgemm<bf16, ACT_PSILU, true><<<g128(cr, 3200), blk, 0, stream>>>(
        Xc, W4, bias4, QS4, cr, 3200, 1024, 1024, 3200, nullptr, nullptr, 0, nullptr, 3072);

    // memory net tail: ln1 -> W2 -> ln2(+mstate) -> folded KVr (K=128)
    ln_kernel<bf16, bf16, false, 128, 128><<<cr, 128, 0, stream>>>(
        QS4 + 3072, ln1g, ln1b, nullptr, h2b, 3200);
    mgemm<bf16, ACT_NONE, true><<<g128(cr, 128), blk, 0, stream>>>(
        h2b, mem_W2, mem_b2, h1b, cr, 128, 128, 128, 128, nullptr, nullptr, 0, nullptr, 0);
    ln_kernel<bf16, bf16, true, 128, 128><<<cr, 128, 0, stream>>>(h1b, ln2g, ln2b, mstate, h2b, 128);
    mgemm<bf16, ACT_NONE, true><<<g128(cr, 2048), blk, 0, stream>>>(
        h2b, Wc, bkv, KVr, cr, 2048, 128, 128, 2048, nullptr, nullptr, 0, nullptr, 0);

    attn_kernel<<<dim3((cr / 64) * 8), dim3(512), 0, stream>>>(
        QS4 + 2048, 3200, KVr, 2048, QS4, 3200, kp, vp, Xc);

    // ao, gate-norm, fused gate*ao+x, final projection
    mgemm<bf16, ACT_NONE, true><<<g128(cr, Cd), blk, 0, stream>>>(
        Xc, mhaWo, mhabo, Bb, cr, Cd, Cd, Cd, Cd, nullptr, nullptr, 0, nullptr, 0);
    ln_kernel<bf16, bf16, false, 1024, 256><<<cr, 256, 0, stream>>>(Bb, gn_g, gn_b, nullptr, Cc, Cd);
    mgemm<bf16, ACT_GATE, true><<<g128(cr, Cd), blk, 0, stream>>>(
        Cc, gateW, gateb, Xc, cr, Cd, Cd, Cd, Cd, Bb, d_in[0], (size_t)r0 * Cd, flag, 0);
    mgemm<float, ACT_NONE, true><<<g128(cr, Cd), blk, 0, stream>>>(
        Xc, outW, outb, (float*)d_out + (size_t)r0 * Cd, cr, Cd, Cd, Cd, Cd,
        nullptr, nullptr, 0, nullptr, 0);
  }
}

// Round 7
// 878.281 us; speedup vs baseline: 1.3801x; 1.0005x over previous
//
#include <hip/hip_runtime.h>
#include <hip/hip_bf16.h>
#include <math.h>

// TitanLongTermMemory — round 13: escape the 2-phase GEMM gate.
// r12 post-mortem: swizzle killed bank conflicts (6.5M->0) but duration flat
// (~100us, MfmaUtil 22%) — the 2-phase stage+vmcnt+barrier skeleton IS the
// critical path (regime gate). This round: new tgemm engine for the four big
// K=1024 GEMMs: 256x128 tile, BK=64, 8 waves, THREE LDS buffers (144KB),
// counted vmcnt(6) at tile boundaries (never drain mid-loop), T2 swizzle,
// setprio around MFMA. KVr/memW2/preamble keep the verified r12 mgemm.
// Expected: 878 -> ~700us; x-proj 100 -> ~60us, MfmaUtil -> ~40%.

using bf16 = __hip_bfloat16;

typedef __attribute__((ext_vector_type(8))) short bf16x8;
typedef __attribute__((ext_vector_type(4))) float f32x4;

__device__ __forceinline__ float ldf(const bf16* p) { return __bfloat162float(*p); }
__device__ __forceinline__ float ldf(const float* p) { return *p; }
__device__ __forceinline__ void stf(bf16* p, float v) { *p = __float2bfloat16(v); }
__device__ __forceinline__ void stf(float* p, float v) { *p = v; }
__device__ __forceinline__ float b2f(const bf16& b) { return __bfloat162float(b); }
__device__ __forceinline__ float bsf(short s) {
  union { unsigned u; float f; } cv;
  cv.u = (unsigned)(unsigned short)s << 16;
  return cv.f;
}

enum { ACT_NONE = 0, ACT_SILU = 1, ACT_SIGMOID = 2, ACT_GATE = 3, ACT_PSILU = 4 };

__global__ void detect_kernel(const unsigned short* g, int* flag) {
  if (threadIdx.x == 0) *flag = (g[0] != 0) ? 1 : 0;
}

// ---- single fused dtype-normalize for all non-x inputs ----------------------
struct ConvArgs {
  const void* src[29];
  bf16* dst[29];
  int n[29];
  int bstart[30];
};

__global__ __launch_bounds__(256) void convall_kernel(ConvArgs a, const int* __restrict__ flag) {
  int b = blockIdx.x;
  int ti = 0;
  while (ti < 28 && b >= a.bstart[ti + 1]) ++ti;
  int i = (b - a.bstart[ti]) * 256 + threadIdx.x;
  if (i >= a.n[ti]) return;
  if (*flag) a.dst[ti][i] = ((const bf16*)a.src[ti])[i];
  else a.dst[ti][i] = __float2bfloat16(((const float*)a.src[ti])[i]);
}

// vectorized x-chunk convert: 8 elems/thread
__global__ __launch_bounds__(256) void conv_kernel(
    const void* __restrict__ src, bf16* __restrict__ dst, int n, size_t src_off,
    const int* __restrict__ flag) {
  int i = (blockIdx.x * 256 + threadIdx.x) * 8;
  if (i >= n) return;
  if (*flag) {
    *(uint4*)((unsigned short*)dst + i) =
        *(const uint4*)((const unsigned short*)src + src_off + i);
  } else {
    const float* s = (const float*)src + src_off + i;
    const float4 a = *(const float4*)s;
    const float4 b = *(const float4*)(s + 4);
    bf16 t[8] = {__float2bfloat16(a.x), __float2bfloat16(a.y),
                 __float2bfloat16(a.z), __float2bfloat16(a.w),
                 __float2bfloat16(b.x), __float2bfloat16(b.y),
                 __float2bfloat16(b.z), __float2bfloat16(b.w)};
    *(uint4*)((unsigned short*)dst + i) = *(const uint4*)t;
  }
}

// bias4 = [bk(1024) | bv(1024) | bq(1024) | mem_b1(128)]
__global__ __launch_bounds__(256) void pack_bias4(
    const bf16* __restrict__ bk, const bf16* __restrict__ bv,
    const bf16* __restrict__ bq, const bf16* __restrict__ b1,
    bf16* __restrict__ o) {
  int j = blockIdx.x * 256 + threadIdx.x;
  if (j >= 3200) return;
  float v;
  if (j < 1024) v = b2f(bk[j]);
  else if (j < 2048) v = b2f(bv[j - 1024]);
  else if (j < 3072) v = b2f(bq[j - 2048]);
  else v = b2f(b1[j - 3072]);
  o[j] = __float2bfloat16(v);
}

// 64x64-tile transpose: dst[c][r] = src[r][c]; src rows x cols (ld=cols).
__global__ __launch_bounds__(256) void transpose_kernel(
    const bf16* __restrict__ srcb, bf16* __restrict__ dstb, int rows, int cols) {
  __shared__ unsigned short t[64][72];  // 144B row stride (16B-aligned)
  const unsigned short* src = (const unsigned short*)srcb;
  unsigned short* dst = (unsigned short*)dstb;
  const int r0 = blockIdx.y * 64, c0 = blockIdx.x * 64;
  for (int e = threadIdx.x; e < 64 * 8; e += 256) {
    int r = e >> 3, c8 = e & 7;
    uint4 v = *(const uint4*)(src + (size_t)(r0 + r) * cols + c0 + c8 * 8);
    *(uint4*)&t[r][c8 * 8] = v;
  }
  __syncthreads();
  for (int e = threadIdx.x; e < 64 * 8; e += 256) {
    int c = e >> 3, r8 = (e & 7) * 8;
    unsigned short v[8];
#pragma unroll
    for (int j = 0; j < 8; ++j) v[j] = t[r8 + j][c];
    *(uint4*)(dst + (size_t)(c0 + c) * rows + r0 + r8) = *(uint4*)v;
  }
}

// ---- fused kp/vp/bkv GEMV over W4 rows 0..2047 ([Wkk|Wvv]) ------------------
__global__ __launch_bounds__(256) void kpvp_kernel(
    const bf16* __restrict__ pmb, const bf16* __restrict__ mobb,
    const bf16* __restrict__ Wb, const bf16* __restrict__ bias4b,
    bf16* __restrict__ kp, bf16* __restrict__ vp, bf16* __restrict__ bkv)
{
  const short* pm = (const short*)pmb;
  const short* mob = (const short*)mobb;
  const short* W = (const short*)Wb;
  const int wave = threadIdx.x >> 6, lane = threadIdx.x & 63;
  const int c = blockIdx.x * 4 + wave;  // 0..2047
  const short* wrow = W + (size_t)c * 1024 + lane * 16;
  const bf16x8 w0 = *(const bf16x8*)wrow;
  const bf16x8 w1 = *(const bf16x8*)(wrow + 8);
  float acc[5];
#pragma unroll
  for (int m = 0; m < 5; ++m) {
    const short* prow = (m < 4) ? (pm + m * 1024 + lane * 16) : (mob + lane * 16);
    const bf16x8 p0 = *(const bf16x8*)prow;
    const bf16x8 p1 = *(const bf16x8*)(prow + 8);
    float s = 0.f;
#pragma unroll
    for (int j = 0; j < 8; ++j) s += bsf(w0[j]) * bsf(p0[j]) + bsf(w1[j]) * bsf(p1[j]);
    acc[m] = s;
  }
#pragma unroll
  for (int d = 1; d < 64; d <<= 1) {
#pragma unroll
    for (int m = 0; m < 5; ++m) acc[m] += __shfl_xor(acc[m], d);
  }
  if (lane == 0) {
    const float bv = b2f(bias4b[c]);
    bf16* dst = (c < 1024) ? (kp + c) : (vp + (c - 1024));
#pragma unroll
    for (int m = 0; m < 4; ++m) stf(dst + m * 1024, acc[m] + bv);
    stf(&bkv[c], acc[4] + bv);
  }
}

__device__ __forceinline__ void gl_lds16(const short* g, short* l) {
  __builtin_amdgcn_global_load_lds(
      (const __attribute__((address_space(1))) void*)g,
      (__attribute__((address_space(3))) void*)l, 16, 0, 0);
}

// ---------------- r12 MFMA GEMM (verified) — small/fallback shapes ----------
template <typename TC, int ACT, bool HAS_BIAS>
__global__ __launch_bounds__(256) void mgemm(
    const bf16* __restrict__ Ab, const bf16* __restrict__ Bw,
    const bf16* __restrict__ bias, TC* __restrict__ C,
    int M, int N, int K, int lda, int ldc,
    const bf16* __restrict__ ao, const void* __restrict__ xsrc, size_t xoff,
    const int* __restrict__ flag, int pn)
{
  __shared__ short As[2][128 * 32];
  __shared__ short Bs[2][128 * 32];
  const short* A = (const short*)Ab;
  const short* B = (const short*)Bw;
  const int tid = threadIdx.x;
  const int m0 = blockIdx.x * 128, n0 = blockIdx.y * 128;
  const int wave = tid >> 6, lane = tid & 63;
  const int wm = (wave & 1) * 64, wn = (wave >> 1) * 64;
  const int fm = lane & 15;
  const int fq = lane >> 4;
  const int fks = (fq ^ ((fm >> 1) & 3)) * 8;   // swizzled read col (shorts)

  const int srow = tid >> 2;
  const int scol = ((tid & 3) ^ ((tid >> 3) & 3)) * 8;  // swizzled source col
  const short* gA0 = A + (size_t)(m0 + srow) * lda + scol;
  const short* gA1 = A + (size_t)(m0 + 64 + srow) * lda + scol;
  const short* gB0 = B + (size_t)(n0 + srow) * K + scol;
  const short* gB1 = B + (size_t)(n0 + 64 + srow) * K + scol;

  f32x4 acc[4][4] = {};
  const int NT = K >> 5;

#define STAGE(buf, k0)                              \
  do {                                              \
    gl_lds16(gA0 + (k0), &As[buf][tid * 8]);        \
    gl_lds16(gA1 + (k0), &As[buf][(256 + tid) * 8]);\
    gl_lds16(gB0 + (k0), &Bs[buf][tid * 8]);        \
    gl_lds16(gB1 + (k0), &Bs[buf][(256 + tid) * 8]);\
  } while (0)

  STAGE(0, 0);
  STAGE(1, 32);

  for (int kt = 0; kt < NT; ++kt) {
    const int cur = kt & 1;
    if (kt == NT - 1) asm volatile("s_waitcnt vmcnt(0)" ::: "memory");
    else              asm volatile("s_waitcnt vmcnt(4)" ::: "memory");
    __builtin_amdgcn_s_barrier();
    bf16x8 af[4], bfr[4];
#pragma unroll
    for (int i = 0; i < 4; ++i)
      af[i] = *(const bf16x8*)&As[cur][(wm + i * 16 + fm) * 32 + fks];
#pragma unroll
    for (int j = 0; j < 4; ++j)
      bfr[j] = *(const bf16x8*)&Bs[cur][(wn + j * 16 + fm) * 32 + fks];
#pragma unroll
    for (int i = 0; i < 4; ++i)
#pragma unroll
      for (int j = 0; j < 4; ++j)
        acc[i][j] = __builtin_amdgcn_mfma_f32_16x16x32_bf16(af[i], bfr[j], acc[i][j], 0, 0, 0);
    asm volatile("s_waitcnt lgkmcnt(0)" ::: "memory");
    __builtin_amdgcn_s_barrier();
    if (kt + 2 < NT) STAGE(cur, (kt + 2) * 32);
  }
#undef STAGE

  const int rg = fq * 4;
#pragma unroll
  for (int i = 0; i < 4; ++i) {
#pragma unroll
    for (int j = 0; j < 4; ++j) {
      const int n = n0 + wn + j * 16 + fm;
      float bv = 0.f;
      if (HAS_BIAS) bv = b2f(bias[n]);
#pragma unroll
      for (int r = 0; r < 4; ++r) {
        const int m = m0 + wm + i * 16 + rg + r;
        float v = acc[i][j][r] + bv;
        if (ACT == ACT_SILU) v = v / (1.f + __expf(-v));
        if (ACT == ACT_PSILU) { if (n >= pn) v = v / (1.f + __expf(-v)); }
        if (ACT == ACT_SIGMOID) v = 1.f / (1.f + __expf(-v));
        if (ACT == ACT_GATE) {
          v = 1.f / (1.f + __expf(-v));
          const size_t e = (size_t)m * 1024 + n;
          const float xv = *flag ? b2f(((const bf16*)xsrc)[xoff + e])
                                 : ((const float*)xsrc)[xoff + e];
          v = v * b2f(ao[e]) + xv;
        }
        stf(&C[(size_t)m * ldc + n], v);
      }
    }
  }
}

// ---------------- tgemm: 256x128 tile, BK=64, 8 waves, 3-deep pipeline ------
// Requires M%256==0, N%128==0, K%64==0, K>=128.
// LDS: LA[3][256*64], LB[3][128*64] shorts = 144KB -> 1 block/CU.
// Swizzle: LDS slot (row r, 16B-group g') holds global group g = g' ^ (r&7);
// applied on global source col (gl_lds dst is linear) and on ds_read col.
// Pipeline: compute tile t (buf t%3) while tile t+1 staged and tile t+2's 6
// loads in flight; boundary waits vmcnt(6) (counted), vmcnt(0) only at tail.
template <typename TC, int ACT, bool HAS_BIAS>
__global__ __launch_bounds__(512, 2) void tgemm(
    const bf16* __restrict__ Ab, const bf16* __restrict__ Bw,
    const bf16* __restrict__ bias, TC* __restrict__ C,
    int M, int N, int K, int lda, int ldc,
    const bf16* __restrict__ ao, const void* __restrict__ xsrc, size_t xoff,
    const int* __restrict__ flag, int pn)
{
  __shared__ short LA[3][256 * 64];
  __shared__ short LB[3][128 * 64];
  const short* A = (const short*)Ab;
  const short* B = (const short*)Bw;
  const int tid = threadIdx.x;
  const int m0 = blockIdx.x * 256, n0 = blockIdx.y * 128;
  const int wave = tid >> 6, lane = tid & 63;
  const int wm = (wave & 1) * 128;          // 2 m-halves
  const int wn = (wave >> 1) * 32;          // 4 n-quarters
  const int fm = lane & 15;
  const int fq = lane >> 4;

  // staging addresses: row srowA = tid>>3 within each 64-row issue,
  // source col-group inverse-swizzled so linear LDS dst lands swizzled.
  const int srowA = tid >> 3;
  const int sgrp = ((tid & 7) ^ ((tid >> 3) & 7)) * 8;
  const short* tA0 = A + (size_t)(m0 + srowA) * lda + sgrp;
  const short* tA1 = A + (size_t)(m0 + 64 + srowA) * lda + sgrp;
  const short* tA2 = A + (size_t)(m0 + 128 + srowA) * lda + sgrp;
  const short* tA3 = A + (size_t)(m0 + 192 + srowA) * lda + sgrp;
  const short* tB0 = B + (size_t)(n0 + srowA) * K + sgrp;
  const short* tB1 = B + (size_t)(n0 + 64 + srowA) * K + sgrp;

  f32x4 acc[8][2] = {};
  const int NT = K >> 6;

#define TSTAGE(buf, t)                                   \
  do {                                                   \
    const int k0_ = (t) * 64;                            \
    gl_lds16(tA0 + k0_, &LA[buf][tid * 8]);              \
    gl_lds16(tA1 + k0_, &LA[buf][4096 + tid * 8]);       \
    gl_lds16(tA2 + k0_, &LA[buf][8192 + tid * 8]);       \
    gl_lds16(tA3 + k0_, &LA[buf][12288 + tid * 8]);      \
    gl_lds16(tB0 + k0_, &LB[buf][tid * 8]);              \
    gl_lds16(tB1 + k0_, &LB[buf][4096 + tid * 8]);       \
  } while (0)

  TSTAGE(0, 0);
  TSTAGE(1, 1);
  asm volatile("s_waitcnt vmcnt(6)" ::: "memory");   // tile 0 retired
  __builtin_amdgcn_s_barrier();

  for (int t = 0; t < NT; ++t) {
    const int buf = t % 3;
    if (t + 2 < NT) TSTAGE((t + 2) % 3, t + 2);
    const short* la = &LA[buf][0];
    const short* lb = &LB[buf][0];
#pragma unroll
    for (int kk = 0; kk < 2; ++kk) {
      const int sw = ((kk * 4 + fq) ^ (fm & 7)) * 8;
      bf16x8 af[8], bfr[2];
#pragma unroll
      for (int mi = 0; mi < 8; ++mi)
        af[mi] = *(const bf16x8*)&la[(wm + mi * 16 + fm) * 64 + sw];
#pragma unroll
      for (int nj = 0; nj < 2; ++nj)
        bfr[nj] = *(const bf16x8*)&lb[(wn + nj * 16 + fm) * 64 + sw];
      __builtin_amdgcn_s_setprio(1);
#pragma unroll
      for (int mi = 0; mi < 8; ++mi)
#pragma unroll
        for (int nj = 0; nj < 2; ++nj)
          acc[mi][nj] = __builtin_amdgcn_mfma_f32_16x16x32_bf16(af[mi], bfr[nj], acc[mi][nj], 0, 0, 0);
      __builtin_amdgcn_s_setprio(0);
    }
    if (t + 1 < NT) {
      if (t + 2 < NT) asm volatile("s_waitcnt vmcnt(6)" ::: "memory");
      else            asm volatile("s_waitcnt vmcnt(0)" ::: "memory");
      __builtin_amdgcn_s_barrier();
    }
  }
#undef TSTAGE

#pragma unroll
  for (int mi = 0; mi < 8; ++mi) {
#pragma unroll
    for (int nj = 0; nj < 2; ++nj) {
      const int n = n0 + wn + nj * 16 + fm;
      float bv = 0.f;
      if (HAS_BIAS) bv = b2f(bias[n]);
#pragma unroll
      for (int r = 0; r < 4; ++r) {
        const int m = m0 + wm + mi * 16 + fq * 4 + r;
        float v = acc[mi][nj][r] + bv;
        if (ACT == ACT_SILU) v = v / (1.f + __expf(-v));
        if (ACT == ACT_PSILU) { if (n >= pn) v = v / (1.f + __expf(-v)); }
        if (ACT == ACT_SIGMOID) v = 1.f / (1.f + __expf(-v));
        if (ACT == ACT_GATE) {
          v = 1.f / (1.f + __expf(-v));
          const size_t e = (size_t)m * 1024 + n;
          const float xv = *flag ? b2f(((const bf16*)xsrc)[xoff + e])
                                 : ((const float*)xsrc)[xoff + e];
          v = v * b2f(ao[e]) + xv;
        }
        stf(&C[(size_t)m * ldc + n], v);
      }
    }
  }
}

// ---- K-split fold GEMM (preamble): P[z] = A @ B^T over K-slice z (KS=4) ----
__global__ __launch_bounds__(256) void kgemm(
    const bf16* __restrict__ Ab, const bf16* __restrict__ Bw,
    float* __restrict__ P, int M, int N, int K, int lda)
{
  __shared__ short As[128 * 32];
  __shared__ short Bs[128 * 32];
  const short* A = (const short*)Ab;
  const short* B = (const short*)Bw;
  const int tid = threadIdx.x;
  const int m0 = blockIdx.x * 128, n0 = blockIdx.y * 128;
  const int kb = blockIdx.z * (K >> 2), ke = kb + (K >> 2);
  const int wave = tid >> 6, lane = tid & 63;
  const int wm = (wave & 1) * 64, wn = (wave >> 1) * 64;
  const int fm = lane & 15;
  const int fk = (lane >> 4) * 8;

  const int srow = tid >> 2, scol = (tid & 3) * 8;
  const short* gA0 = A + (size_t)(m0 + srow) * lda + scol;
  const short* gA1 = A + (size_t)(m0 + 64 + srow) * lda + scol;
  const short* gB0 = B + (size_t)(n0 + srow) * K + scol;
  const short* gB1 = B + (size_t)(n0 + 64 + srow) * K + scol;
  short* lA0 = As + tid * 8;
  short* lA1 = As + (256 + tid) * 8;
  short* lB0 = Bs + tid * 8;
  short* lB1 = Bs + (256 + tid) * 8;

  f32x4 acc[4][4] = {};

  for (int k0 = kb; k0 < ke; k0 += 32) {
    gl_lds16(gA0 + k0, lA0);
    gl_lds16(gA1 + k0, lA1);
    gl_lds16(gB0 + k0, lB0);
    gl_lds16(gB1 + k0, lB1);
    __syncthreads();
    bf16x8 af[4], bfr[4];
#pragma unroll
    for (int i = 0; i < 4; ++i)
      af[i] = *(const bf16x8*)&As[(wm + i * 16 + fm) * 32 + fk];
#pragma unroll
    for (int j = 0; j < 4; ++j)
      bfr[j] = *(const bf16x8*)&Bs[(wn + j * 16 + fm) * 32 + fk];
#pragma unroll
    for (int i = 0; i < 4; ++i)
#pragma unroll
      for (int j = 0; j < 4; ++j)
        acc[i][j] = __builtin_amdgcn_mfma_f32_16x16x32_bf16(af[i], bfr[j], acc[i][j], 0, 0, 0);
    __syncthreads();
  }

  float* Cp = P + (size_t)blockIdx.z * ((size_t)M * N);
  const int rg = (lane >> 4) * 4;
#pragma unroll
  for (int i = 0; i < 4; ++i)
#pragma unroll
    for (int j = 0; j < 4; ++j) {
      const int n = n0 + wn + j * 16 + fm;
#pragma unroll
      for (int r = 0; r < 4; ++r) {
        const int m = m0 + wm + i * 16 + rg + r;
        Cp[(size_t)m * N + n] = acc[i][j][r];
      }
    }
}

// sum 4 K-slice partials -> bf16
__global__ __launch_bounds__(256) void foldfin_kernel(
    const float* __restrict__ P, bf16* __restrict__ o, int MN) {
  int i = blockIdx.x * 256 + threadIdx.x;
  if (i >= MN) return;
  float s = P[i] + P[i + (size_t)MN] + P[i + 2 * (size_t)MN] + P[i + 3 * (size_t)MN];
  o[i] = __float2bfloat16(s);
}

// Row LayerNorm over width W; optional post-LN add of a bf16 vector.
template <typename TI, typename TO, bool ADD, int W, int BS>
__global__ __launch_bounds__(BS) void ln_kernel(
    const TI* __restrict__ in, const bf16* __restrict__ g, const bf16* __restrict__ b,
    const bf16* __restrict__ addv, TO* __restrict__ out, int ldin)
{
  __shared__ float red[BS];
  const int row = blockIdx.x;
  const TI* rin = in + (size_t)row * ldin;
  TO* rout = out + (size_t)row * W;
  const int NP = W / BS;
  float v[NP];
  float s = 0.f;
#pragma unroll
  for (int i = 0; i < NP; ++i) { v[i] = ldf(&rin[threadIdx.x + i * BS]); s += v[i]; }
  red[threadIdx.x] = s; __syncthreads();
  for (int o = BS / 2; o > 0; o >>= 1) {
    if (threadIdx.x < o) red[threadIdx.x] += red[threadIdx.x + o];
    __syncthreads();
  }
  const float mean = red[0] / W;
  __syncthreads();
  float sq = 0.f;
#pragma unroll
  for (int i = 0; i < NP; ++i) { float d = v[i] - mean; sq += d * d; }
  red[threadIdx.x] = sq; __syncthreads();
  for (int o = BS / 2; o > 0; o >>= 1) {
    if (threadIdx.x < o) red[threadIdx.x] += red[threadIdx.x + o];
    __syncthreads();
  }
  const float rstd = rsqrtf(red[0] / W + 1e-5f);
#pragma unroll
  for (int i = 0; i < NP; ++i) {
    int c = threadIdx.x + i * BS;
    float o_ = (v[i] - mean) * rstd * b2f(g[c]) + b2f(b[c]);
    if (ADD) o_ += b2f(addv[c]);
    stf(&rout[c], o_);
  }
}

// ---------------- MFMA attention (XCD-chunked bid swizzle) ------------------
__global__ __launch_bounds__(512) void attn_kernel(
    const bf16* __restrict__ qg, int str_q,
    const bf16* __restrict__ krv, int str_r,
    const bf16* __restrict__ kxv, int str_x, const bf16* __restrict__ kpg,
    const bf16* __restrict__ vpg, bf16* __restrict__ outg)
{
  __shared__ short qs[4 * 64 * 32];
  __shared__ short ksl[4 * 144 * 32];
  __shared__ short vt[128 * 168];
  __shared__ short pl[64 * 168];

  const int tid = threadIdx.x;
  unsigned bid = blockIdx.x;
  {
    const unsigned nwg = gridDim.x;
    const unsigned q_ = nwg >> 3, r_ = nwg & 7;
    const unsigned xcd = bid & 7, loc = bid >> 3;
    bid = (xcd < r_ ? xcd * (q_ + 1) : r_ * (q_ + 1) + (xcd - r_) * q_) + loc;
  }
  const int seg = (int)(bid >> 3), h = (int)(bid & 7);
  const unsigned short* q = (const unsigned short*)qg + (size_t)seg * 64 * str_q + h * 128;
  const unsigned short* kv_r = (const unsigned short*)krv + (size_t)seg * 64 * str_r + h * 128;
  const unsigned short* kv_x = (const unsigned short*)kxv + (size_t)seg * 64 * str_x + h * 128;
  const unsigned short* kp = (const unsigned short*)kpg;
  const unsigned short* vp = (const unsigned short*)vpg;
  const size_t obase = (size_t)seg * 64 * 1024 + h * 128;

  for (int ch = tid; ch < 64 * 16; ch += 512) {
    int row = ch >> 4, k8 = ch & 15;
    uint4 v = *(const uint4*)(q + (size_t)row * str_q + k8 * 8);
    *(uint4*)&qs[((k8 >> 2) * 64 + row) * 32 + (k8 & 3) * 8] = v;
  }
  for (int ch = tid; ch < 132 * 16; ch += 512) {
    int t = ch >> 4, k8 = ch & 15;
    const unsigned short* src;
    if (t < 64) src = kv_r + (size_t)t * str_r;
    else if (t < 68) src = kp + (size_t)(t - 64) * 1024 + h * 128;
    else src = kv_x + (size_t)(t - 68) * str_x;
    uint4 v = *(const uint4*)(src + k8 * 8);
    *(uint4*)&ksl[((k8 >> 2) * 144 + t) * 32 + (k8 & 3) * 8] = v;
  }
  __syncthreads();

  const int wave = tid >> 6, lane = tid & 63;
  const int fm = lane & 15, fq = lane >> 4;

  if (wave < 4) {
    const int s0 = wave * 16;
    f32x4 acc[10];
#pragma unroll
    for (int tt = 0; tt < 10; ++tt) acc[tt] = (f32x4){0.f, 0.f, 0.f, 0.f};
#pragma unroll
    for (int kb = 0; kb < 4; ++kb) {
      const bf16x8 a = *(const bf16x8*)&qs[(kb * 64 + s0 + fm) * 32 + fq * 8];
#pragma unroll
      for (int tt = 0; tt < 9; ++tt) {
        const bf16x8 b = *(const bf16x8*)&ksl[(kb * 144 + tt * 16 + fm) * 32 + fq * 8];
        acc[tt] = __builtin_amdgcn_mfma_f32_16x16x32_bf16(a, b, acc[tt], 0, 0, 0);
      }
    }
    const float scale = 0.08838834764831845f;
#pragma unroll
    for (int r = 0; r < 4; ++r) {
      float m = -3.0e38f;
#pragma unroll
      for (int tt = 0; tt < 9; ++tt) {
        int t = tt * 16 + fm;
        if (t < 132) m = fmaxf(m, acc[tt][r] * scale);
      }
      for (int d = 1; d < 16; d <<= 1) m = fmaxf(m, __shfl_xor(m, d));
      float e[10];
      float sum = 0.f;
#pragma unroll
      for (int tt = 0; tt < 10; ++tt) {
        int t = tt * 16 + fm;
        float ev = 0.f;
        if (t < 132) ev = __expf(acc[tt][r] * scale - m);
        e[tt] = ev; sum += ev;
      }
      for (int d = 1; d < 16; d <<= 1) sum += __shfl_xor(sum, d);
      const float inv = 1.f / sum;
      const int s = s0 + fq * 4 + r;
#pragma unroll
      for (int tt = 0; tt < 10; ++tt) {
        bf16 pv = __float2bfloat16(e[tt] * inv);
        pl[s * 168 + tt * 16 + fm] = *(const short*)&pv;
      }
    }
  } else {
    for (int ch = tid - 256; ch < 132 * 32; ch += 256) {
      int t = ch >> 5, d4 = (ch & 31) * 4;
      const unsigned short* src;
      if (t < 64) src = kv_r + 1024 + (size_t)t * str_r;
      else if (t < 68) src = vp + (size_t)(t - 64) * 1024 + h * 128;
      else src = kv_x + 1024 + (size_t)(t - 68) * str_x;
      uint2 w = *(const uint2*)(src + d4);
      vt[(d4 + 0) * 168 + t] = (short)(w.x & 0xffffu);
      vt[(d4 + 1) * 168 + t] = (short)(w.x >> 16);
      vt[(d4 + 2) * 168 + t] = (short)(w.y & 0xffffu);
      vt[(d4 + 3) * 168 + t] = (short)(w.y >> 16);
    }
    for (int ch = tid - 256; ch < 128 * 32; ch += 256) {
      int d = ch >> 5, tp = 132 + (ch & 31);
      vt[d * 168 + tp] = 0;
    }
  }
  __syncthreads();

  const int dt = wave;
  bf16x8 af[5];
#pragma unroll
  for (int kb = 0; kb < 5; ++kb)
    af[kb] = *(const bf16x8*)&vt[(dt * 16 + fm) * 168 + kb * 32 + fq * 8];
#pragma unroll
  for (int st = 0; st < 4; ++st) {
    f32x4 o = (f32x4){0.f, 0.f, 0.f, 0.f};
#pragma unroll
    for (int kb = 0; kb < 5; ++kb) {
      const bf16x8 bp = *(const bf16x8*)&pl[(st * 16 + fm) * 168 + kb * 32 + fq * 8];
      o = __builtin_amdgcn_mfma_f32_16x16x32_bf16(af[kb], bp, o, 0, 0, 0);
    }
    const int s = st * 16 + fm;
    bf16 b0 = __float2bfloat16(o[0]), b1 = __float2bfloat16(o[1]);
    bf16 b2 = __float2bfloat16(o[2]), b3 = __float2bfloat16(o[3]);
    uint2 w;
    w.x = ((unsigned)(*(unsigned short*)&b1) << 16) | (*(unsigned short*)&b0);
    w.y = ((unsigned)(*(unsigned short*)&b3) << 16) | (*(unsigned short*)&b2);
    *(uint2*)((unsigned short*)outg + obase + (size_t)s * 1024 + dt * 16 + fq * 4) = w;
  }
}

extern "C" void kernel_launch(void* const* d_in, const int* in_sizes, int n_in,
                              void* d_out, int out_size, void* d_ws, size_t ws_size,
                              hipStream_t stream)
{
  (void)n_in; (void)out_size;
  const int R = 16384, Cd = 1024;

  char* ws = (char*)d_ws;
  size_t off = 0;
  auto alloc = [&](size_t bytes) -> void* {
    void* p = ws + off;
    off += (bytes + 255) & ~(size_t)255;
    return p;
  };

  int* flag = (int*)alloc(256);
  // packed x-projection weights [Wkk | Wvv | Wqq | Wm1] rows (3200 x 1024)
  bf16* W4    = (bf16*)alloc((size_t)3200 * Cd * sizeof(bf16));
  bf16* bias4 = (bf16*)alloc(3200 * sizeof(bf16));
  bf16* T     = (bf16*)alloc((size_t)Cd * Cd * sizeof(bf16));  // transpose scratch
  bf16* Wc    = (bf16*)alloc((size_t)2048 * 128 * sizeof(bf16));
  bf16* kp    = (bf16*)alloc((size_t)4 * Cd * sizeof(bf16));
  bf16* vp    = (bf16*)alloc((size_t)4 * Cd * sizeof(bf16));
  bf16* bkv   = (bf16*)alloc(2048 * sizeof(bf16));
  bf16* WqStk = (bf16*)alloc((size_t)1152 * Cd * sizeof(bf16)); // [mhaWq; mem_W1]
  bf16* nb[30];
  nb[0] = nullptr;
  for (int i = 1; i < 30; ++i) nb[i] = (bf16*)alloc((size_t)in_sizes[i] * sizeof(bf16));
  nb[16] = WqStk;                          // mhaWq -> rows 0..1023 of stack
  nb[5]  = WqStk + (size_t)1024 * Cd;      // mem_W1 -> rows 1024..1151
  const size_t fixed_end = off;

  // balanced chunk sizing; per-row scratch = 17152 B
  size_t avail = (ws_size > fixed_end + (1u << 20)) ? (ws_size - fixed_end - (1u << 20)) : 0;
  int crmax = (int)(avail / 17152);
  if (crmax > R) crmax = R;
  if (crmax < 128) crmax = 128;
  int nch = (R + crmax - 1) / crmax;
  int CR = ((R / nch + 127) / 128) * 128;
  while (CR * nch < R) CR += 128;

  const size_t chunk_start = off;
  const size_t RB = (size_t)CR * Cd * sizeof(bf16);
  bf16* Xc  = (bf16*)alloc(RB);                               // x(bf16) -> attn out
  bf16* QS4 = (bf16*)alloc((size_t)CR * 3200 * sizeof(bf16)); // [k_x|v_x|q|h1]
  bf16* h1b = (bf16*)alloc((size_t)CR * 128 * sizeof(bf16));
  bf16* h2b = (bf16*)alloc((size_t)CR * 128 * sizeof(bf16));
  bf16* Bb  = (bf16*)alloc(RB);                               // ao
  bf16* KVr = (bf16*)alloc(2 * RB);                           // [k_r | v_r]
  bf16* Cc  = (bf16*)alloc(RB);                               // gin
  const size_t chunk_bytes = off - chunk_start;

  dim3 blk(256);
  // grid = (Mt, Nt): m-tile fastest -> xcd = m_tile % 8 fixed
  auto g128 = [](int M_, int N_) { return dim3((unsigned)(M_ / 128), (unsigned)(N_ / 128)); };
  auto g256 = [](int M_, int N_) { return dim3((unsigned)(M_ / 256), (unsigned)(N_ / 128)); };

  // ---- preamble ----
  detect_kernel<<<1, 64, 0, stream>>>((const unsigned short*)d_in[24], flag);
  {
    ConvArgs a;
    int bs = 0;
    for (int i = 1; i < 30; ++i) {
      a.src[i - 1] = d_in[i];
      a.dst[i - 1] = nb[i];
      a.n[i - 1] = in_sizes[i];
      a.bstart[i - 1] = bs;
      bs += (in_sizes[i] + 255) / 256;
    }
    a.bstart[29] = bs;
    convall_kernel<<<dim3((unsigned)bs), blk, 0, stream>>>(a, flag);
  }
  const bf16 *pm = nb[1], *Wq = nb[2], *Wk = nb[3], *Wv = nb[4];
  const bf16 *mem_W1 = nb[5], *mem_b1 = nb[6], *ln1g = nb[7], *ln1b = nb[8];
  const bf16 *mem_W2 = nb[9], *mem_b2 = nb[10], *ln2g = nb[11], *ln2b = nb[12];
  const bf16 *mem_oW = nb[13], *mem_ob = nb[14], *mstate = nb[15];
  const bf16 *mhaWq = nb[16], *mhabq = nb[17], *mhaWk = nb[18], *mhabk = nb[19];
  const bf16 *mhaWv = nb[20], *mhabv = nb[21], *mhaWo = nb[22], *mhabo = nb[23];
  const bf16 *gn_g = nb[24], *gn_b = nb[25], *gateW = nb[26], *gateb = nb[27];
  const bf16 *outW = nb[28], *outb = nb[29];
  bf16* Wkk = W4;
  bf16* Wvv = W4 + (size_t)1024 * Cd;
  bf16* Wqq = W4 + (size_t)2048 * Cd;
  bf16* Wm1 = W4 + (size_t)3072 * Cd;

  // weight folds
  const bool use_ks = chunk_bytes >= (size_t)4 * 1152 * 1024 * sizeof(float);
  if (use_ks) {
    float* P = (float*)Xc;  // aliases dead chunk scratch
    transpose_kernel<<<dim3(16, 16), blk, 0, stream>>>(Wq, T, 1024, 1024);
    kgemm<<<dim3(9, 8, 4), blk, 0, stream>>>(WqStk, T, P, 1152, 1024, 1024, 1024);
    foldfin_kernel<<<dim3(4608), blk, 0, stream>>>(P, Wqq, 1152 * 1024);
    transpose_kernel<<<dim3(16, 16), blk, 0, stream>>>(Wk, T, 1024, 1024);
    kgemm<<<dim3(8, 8, 4), blk, 0, stream>>>(mhaWk, T, P, 1024, 1024, 1024, 1024);
    foldfin_kernel<<<dim3(4096), blk, 0, stream>>>(P, Wkk, 1024 * 1024);
    transpose_kernel<<<dim3(16, 16), blk, 0, stream>>>(Wv, T, 1024, 1024);
    kgemm<<<dim3(8, 8, 4), blk, 0, stream>>>(mhaWv, T, P, 1024, 1024, 1024, 1024);
    foldfin_kernel<<<dim3(4096), blk, 0, stream>>>(P, Wvv, 1024 * 1024);
    transpose_kernel<<<dim3(2, 16), blk, 0, stream>>>(mem_oW, T, 1024, 128);
    kgemm<<<dim3(16, 1, 4), blk, 0, stream>>>(W4, T, P, 2048, 128, 1024, 1024);
    foldfin_kernel<<<dim3(1024), blk, 0, stream>>>(P, Wc, 2048 * 128);
  } else {
    transpose_kernel<<<dim3(16, 16), blk, 0, stream>>>(Wq, T, 1024, 1024);
    mgemm<bf16, ACT_NONE, false><<<g128(1024, 1024), blk, 0, stream>>>(
        mhaWq, T, nullptr, Wqq, 1024, 1024, 1024, 1024, 1024, nullptr, nullptr, 0, nullptr, 0);
    mgemm<bf16, ACT_NONE, false><<<g128(128, 1024), blk, 0, stream>>>(
        mem_W1, T, nullptr, Wm1, 128, 1024, 1024, 1024, 1024, nullptr, nullptr, 0, nullptr, 0);
    transpose_kernel<<<dim3(16, 16), blk, 0, stream>>>(Wk, T, 1024, 1024);
    mgemm<bf16, ACT_NONE, false><<<g128(1024, 1024), blk, 0, stream>>>(
        mhaWk, T, nullptr, Wkk, 1024, 1024, 1024, 1024, 1024, nullptr, nullptr, 0, nullptr, 0);
    transpose_kernel<<<dim3(16, 16), blk, 0, stream>>>(Wv, T, 1024, 1024);
    mgemm<bf16, ACT_NONE, false><<<g128(1024, 1024), blk, 0, stream>>>(
        mhaWv, T, nullptr, Wvv, 1024, 1024, 1024, 1024, 1024, nullptr, nullptr, 0, nullptr, 0);
    transpose_kernel<<<dim3(2, 16), blk, 0, stream>>>(mem_oW, T, 1024, 128);
    mgemm<bf16, ACT_NONE, false><<<g128(2048, 128), blk, 0, stream>>>(
        W4, T, nullptr, Wc, 2048, 128, 1024, 1024, 128, nullptr, nullptr, 0, nullptr, 0);
  }
  pack_bias4<<<13, blk, 0, stream>>>(mhabk, mhabv, mhabq, mem_b1, bias4);
  kpvp_kernel<<<dim3(512), blk, 0, stream>>>(pm, mem_ob, W4, bias4, kp, vp, bkv);

  for (int r0 = 0; r0 < R; r0 += CR) {
    const int cr = (R - r0 < CR) ? (R - r0) : CR;
    const int n = cr * Cd;
    const bool big = (cr % 256) == 0;
    conv_kernel<<<dim3((n / 8 + 255) / 256), blk, 0, stream>>>(
        d_in[0], Xc, n, (size_t)r0 * Cd, flag);

    // packed x-projection: [k_x | v_x | q | h1=silu(...)]
    if (big)
      tgemm<bf16, ACT_PSILU, true><<<g256(cr, 3200), dim3(512), 0, stream>>>(
          Xc, W4, bias4, QS4, cr, 3200, 1024, 1024, 3200, nullptr, nullptr, 0, nullptr, 3072);
    else
      mgemm<bf16, ACT_PSILU, true><<<g128(cr, 3200), blk, 0, stream>>>(
          Xc, W4, bias4, QS4, cr, 3200, 1024, 1024, 3200, nullptr, nullptr, 0, nullptr, 3072);

    // memory net tail: ln1 -> W2 -> ln2(+mstate) -> folded KVr (K=128)
    ln_kernel<bf16, bf16, false, 128, 128><<<cr, 128, 0, stream>>>(
        QS4 + 3072, ln1g, ln1b, nullptr, h2b, 3200);
    mgemm<bf16, ACT_NONE, true><<<g128(cr, 128), blk, 0, stream>>>(
        h2b, mem_W2, mem_b2, h1b, cr, 128, 128, 128, 128, nullptr, nullptr, 0, nullptr, 0);
    ln_kernel<bf16, bf16, true, 128, 128><<<cr, 128, 0, stream>>>(h1b, ln2g, ln2b, mstate, h2b, 128);
    mgemm<bf16, ACT_NONE, true><<<g128(cr, 2048), blk, 0, stream>>>(
        h2b, Wc, bkv, KVr, cr, 2048, 128, 128, 2048, nullptr, nullptr, 0, nullptr, 0);

    attn_kernel<<<dim3((cr / 64) * 8), dim3(512), 0, stream>>>(
        QS4 + 2048, 3200, KVr, 2048, QS4, 3200, kp, vp, Xc);

    // ao, gate-norm, fused gate*ao+x, final projection
    if (big)
      tgemm<bf16, ACT_NONE, true><<<g256(cr, Cd), dim3(512), 0, stream>>>(
          Xc, mhaWo, mhabo, Bb, cr, Cd, Cd, Cd, Cd, nullptr, nullptr, 0, nullptr, 0);
    else
      mgemm<bf16, ACT_NONE, true><<<g128(cr, Cd), blk, 0, stream>>>(
          Xc, mhaWo, mhabo, Bb, cr, Cd, Cd, Cd, Cd, nullptr, nullptr, 0, nullptr, 0);
    ln_kernel<bf16, bf16, false, 1024, 256><<<cr, 256, 0, stream>>>(Bb, gn_g, gn_b, nullptr, Cc, Cd);
    if (big) {
      tgemm<bf16, ACT_GATE, true><<<g256(cr, Cd), dim3(512), 0, stream>>>(
          Cc, gateW, gateb, Xc, cr, Cd, Cd, Cd, Cd, Bb, d_in[0], (size_t)r0 * Cd, flag, 0);
      tgemm<float, ACT_NONE, true><<<g256(cr, Cd), dim3(512), 0, stream>>>(
          Xc, outW, outb, (float*)d_out + (size_t)r0 * Cd, cr, Cd, Cd, Cd, Cd,
          nullptr, nullptr, 0, nullptr, 0);
    } else {
      mgemm<bf16, ACT_GATE, true><<<g128(cr, Cd), blk, 0, stream>>>(
          Cc, gateW, gateb, Xc, cr, Cd, Cd, Cd, Cd, Bb, d_in[0], (size_t)r0 * Cd, flag, 0);
      mgemm<float, ACT_NONE, true><<<g128(cr, Cd), blk, 0, stream>>>(
          Xc, outW, outb, (float*)d_out + (size_t)r0 * Cd, cr, Cd, Cd, Cd, Cd,
          nullptr, nullptr, 0, nullptr, 0);
    }
  }
}

// Round 8
// 828.600 us; speedup vs baseline: 1.4628x; 1.0600x over previous
//
#include <hip/hip_runtime.h>
#include <hip/hip_bf16.h>
#include <math.h>

// TitanLongTermMemory — round 14: real 8-phase schedule (m201 port).
// r13 post-mortem: tgemm's monolithic 2-barrier tiles at 1 block/CU
// serialized LDS and MFMA (MfmaUtil 19.6%, VALUBusy 15.8%) — the fine
// per-phase interleave is the prerequisite (m196/m218/m233). This round:
// pgemm = 256x128, BK=64, 8 waves (4Mx2N, per-wave 64x64), 3 LDS bufs,
// TWO fine phases per K-tile, each: {8 ds_read ∥ 3 gl_lds -> barrier ->
// lgkmcnt(0) -> setprio(1) 16 MFMA setprio(0) -> barrier}; vmcnt(6) only
// at tile boundaries. Expected: 878 -> ~740us; x-proj 100 -> ~60us.

using bf16 = __hip_bfloat16;

typedef __attribute__((ext_vector_type(8))) short bf16x8;
typedef __attribute__((ext_vector_type(4))) float f32x4;

__device__ __forceinline__ float ldf(const bf16* p) { return __bfloat162float(*p); }
__device__ __forceinline__ float ldf(const float* p) { return *p; }
__device__ __forceinline__ void stf(bf16* p, float v) { *p = __float2bfloat16(v); }
__device__ __forceinline__ void stf(float* p, float v) { *p = v; }
__device__ __forceinline__ float b2f(const bf16& b) { return __bfloat162float(b); }
__device__ __forceinline__ float bsf(short s) {
  union { unsigned u; float f; } cv;
  cv.u = (unsigned)(unsigned short)s << 16;
  return cv.f;
}

enum { ACT_NONE = 0, ACT_SILU = 1, ACT_SIGMOID = 2, ACT_GATE = 3, ACT_PSILU = 4 };

__global__ void detect_kernel(const unsigned short* g, int* flag) {
  if (threadIdx.x == 0) *flag = (g[0] != 0) ? 1 : 0;
}

// ---- single fused dtype-normalize for all non-x inputs ----------------------
struct ConvArgs {
  const void* src[29];
  bf16* dst[29];
  int n[29];
  int bstart[30];
};

__global__ __launch_bounds__(256) void convall_kernel(ConvArgs a, const int* __restrict__ flag) {
  int b = blockIdx.x;
  int ti = 0;
  while (ti < 28 && b >= a.bstart[ti + 1]) ++ti;
  int i = (b - a.bstart[ti]) * 256 + threadIdx.x;
  if (i >= a.n[ti]) return;
  if (*flag) a.dst[ti][i] = ((const bf16*)a.src[ti])[i];
  else a.dst[ti][i] = __float2bfloat16(((const float*)a.src[ti])[i]);
}

// vectorized x-chunk convert: 8 elems/thread
__global__ __launch_bounds__(256) void conv_kernel(
    const void* __restrict__ src, bf16* __restrict__ dst, int n, size_t src_off,
    const int* __restrict__ flag) {
  int i = (blockIdx.x * 256 + threadIdx.x) * 8;
  if (i >= n) return;
  if (*flag) {
    *(uint4*)((unsigned short*)dst + i) =
        *(const uint4*)((const unsigned short*)src + src_off + i);
  } else {
    const float* s = (const float*)src + src_off + i;
    const float4 a = *(const float4*)s;
    const float4 b = *(const float4*)(s + 4);
    bf16 t[8] = {__float2bfloat16(a.x), __float2bfloat16(a.y),
                 __float2bfloat16(a.z), __float2bfloat16(a.w),
                 __float2bfloat16(b.x), __float2bfloat16(b.y),
                 __float2bfloat16(b.z), __float2bfloat16(b.w)};
    *(uint4*)((unsigned short*)dst + i) = *(const uint4*)t;
  }
}

// bias4 = [bk(1024) | bv(1024) | bq(1024) | mem_b1(128)]
__global__ __launch_bounds__(256) void pack_bias4(
    const bf16* __restrict__ bk, const bf16* __restrict__ bv,
    const bf16* __restrict__ bq, const bf16* __restrict__ b1,
    bf16* __restrict__ o) {
  int j = blockIdx.x * 256 + threadIdx.x;
  if (j >= 3200) return;
  float v;
  if (j < 1024) v = b2f(bk[j]);
  else if (j < 2048) v = b2f(bv[j - 1024]);
  else if (j < 3072) v = b2f(bq[j - 2048]);
  else v = b2f(b1[j - 3072]);
  o[j] = __float2bfloat16(v);
}

// 64x64-tile transpose: dst[c][r] = src[r][c]; src rows x cols (ld=cols).
__global__ __launch_bounds__(256) void transpose_kernel(
    const bf16* __restrict__ srcb, bf16* __restrict__ dstb, int rows, int cols) {
  __shared__ unsigned short t[64][72];  // 144B row stride (16B-aligned)
  const unsigned short* src = (const unsigned short*)srcb;
  unsigned short* dst = (unsigned short*)dstb;
  const int r0 = blockIdx.y * 64, c0 = blockIdx.x * 64;
  for (int e = threadIdx.x; e < 64 * 8; e += 256) {
    int r = e >> 3, c8 = e & 7;
    uint4 v = *(const uint4*)(src + (size_t)(r0 + r) * cols + c0 + c8 * 8);
    *(uint4*)&t[r][c8 * 8] = v;
  }
  __syncthreads();
  for (int e = threadIdx.x; e < 64 * 8; e += 256) {
    int c = e >> 3, r8 = (e & 7) * 8;
    unsigned short v[8];
#pragma unroll
    for (int j = 0; j < 8; ++j) v[j] = t[r8 + j][c];
    *(uint4*)(dst + (size_t)(c0 + c) * rows + r0 + r8) = *(uint4*)v;
  }
}

// ---- fused kp/vp/bkv GEMV over W4 rows 0..2047 ([Wkk|Wvv]) ------------------
__global__ __launch_bounds__(256) void kpvp_kernel(
    const bf16* __restrict__ pmb, const bf16* __restrict__ mobb,
    const bf16* __restrict__ Wb, const bf16* __restrict__ bias4b,
    bf16* __restrict__ kp, bf16* __restrict__ vp, bf16* __restrict__ bkv)
{
  const short* pm = (const short*)pmb;
  const short* mob = (const short*)mobb;
  const short* W = (const short*)Wb;
  const int wave = threadIdx.x >> 6, lane = threadIdx.x & 63;
  const int c = blockIdx.x * 4 + wave;  // 0..2047
  const short* wrow = W + (size_t)c * 1024 + lane * 16;
  const bf16x8 w0 = *(const bf16x8*)wrow;
  const bf16x8 w1 = *(const bf16x8*)(wrow + 8);
  float acc[5];
#pragma unroll
  for (int m = 0; m < 5; ++m) {
    const short* prow = (m < 4) ? (pm + m * 1024 + lane * 16) : (mob + lane * 16);
    const bf16x8 p0 = *(const bf16x8*)prow;
    const bf16x8 p1 = *(const bf16x8*)(prow + 8);
    float s = 0.f;
#pragma unroll
    for (int j = 0; j < 8; ++j) s += bsf(w0[j]) * bsf(p0[j]) + bsf(w1[j]) * bsf(p1[j]);
    acc[m] = s;
  }
#pragma unroll
  for (int d = 1; d < 64; d <<= 1) {
#pragma unroll
    for (int m = 0; m < 5; ++m) acc[m] += __shfl_xor(acc[m], d);
  }
  if (lane == 0) {
    const float bv = b2f(bias4b[c]);
    bf16* dst = (c < 1024) ? (kp + c) : (vp + (c - 1024));
#pragma unroll
    for (int m = 0; m < 4; ++m) stf(dst + m * 1024, acc[m] + bv);
    stf(&bkv[c], acc[4] + bv);
  }
}

__device__ __forceinline__ void gl_lds16(const short* g, short* l) {
  __builtin_amdgcn_global_load_lds(
      (const __attribute__((address_space(1))) void*)g,
      (__attribute__((address_space(3))) void*)l, 16, 0, 0);
}

// ---------------- r12 MFMA GEMM (verified) — small/fallback shapes ----------
template <typename TC, int ACT, bool HAS_BIAS>
__global__ __launch_bounds__(256) void mgemm(
    const bf16* __restrict__ Ab, const bf16* __restrict__ Bw,
    const bf16* __restrict__ bias, TC* __restrict__ C,
    int M, int N, int K, int lda, int ldc,
    const bf16* __restrict__ ao, const void* __restrict__ xsrc, size_t xoff,
    const int* __restrict__ flag, int pn)
{
  __shared__ short As[2][128 * 32];
  __shared__ short Bs[2][128 * 32];
  const short* A = (const short*)Ab;
  const short* B = (const short*)Bw;
  const int tid = threadIdx.x;
  const int m0 = blockIdx.x * 128, n0 = blockIdx.y * 128;
  const int wave = tid >> 6, lane = tid & 63;
  const int wm = (wave & 1) * 64, wn = (wave >> 1) * 64;
  const int fm = lane & 15;
  const int fq = lane >> 4;
  const int fks = (fq ^ ((fm >> 1) & 3)) * 8;   // swizzled read col (shorts)

  const int srow = tid >> 2;
  const int scol = ((tid & 3) ^ ((tid >> 3) & 3)) * 8;  // swizzled source col
  const short* gA0 = A + (size_t)(m0 + srow) * lda + scol;
  const short* gA1 = A + (size_t)(m0 + 64 + srow) * lda + scol;
  const short* gB0 = B + (size_t)(n0 + srow) * K + scol;
  const short* gB1 = B + (size_t)(n0 + 64 + srow) * K + scol;

  f32x4 acc[4][4] = {};
  const int NT = K >> 5;

#define STAGE(buf, k0)                              \
  do {                                              \
    gl_lds16(gA0 + (k0), &As[buf][tid * 8]);        \
    gl_lds16(gA1 + (k0), &As[buf][(256 + tid) * 8]);\
    gl_lds16(gB0 + (k0), &Bs[buf][tid * 8]);        \
    gl_lds16(gB1 + (k0), &Bs[buf][(256 + tid) * 8]);\
  } while (0)

  STAGE(0, 0);
  STAGE(1, 32);

  for (int kt = 0; kt < NT; ++kt) {
    const int cur = kt & 1;
    if (kt == NT - 1) asm volatile("s_waitcnt vmcnt(0)" ::: "memory");
    else              asm volatile("s_waitcnt vmcnt(4)" ::: "memory");
    __builtin_amdgcn_s_barrier();
    bf16x8 af[4], bfr[4];
#pragma unroll
    for (int i = 0; i < 4; ++i)
      af[i] = *(const bf16x8*)&As[cur][(wm + i * 16 + fm) * 32 + fks];
#pragma unroll
    for (int j = 0; j < 4; ++j)
      bfr[j] = *(const bf16x8*)&Bs[cur][(wn + j * 16 + fm) * 32 + fks];
#pragma unroll
    for (int i = 0; i < 4; ++i)
#pragma unroll
      for (int j = 0; j < 4; ++j)
        acc[i][j] = __builtin_amdgcn_mfma_f32_16x16x32_bf16(af[i], bfr[j], acc[i][j], 0, 0, 0);
    asm volatile("s_waitcnt lgkmcnt(0)" ::: "memory");
    __builtin_amdgcn_s_barrier();
    if (kt + 2 < NT) STAGE(cur, (kt + 2) * 32);
  }
#undef STAGE

  const int rg = fq * 4;
#pragma unroll
  for (int i = 0; i < 4; ++i) {
#pragma unroll
    for (int j = 0; j < 4; ++j) {
      const int n = n0 + wn + j * 16 + fm;
      float bv = 0.f;
      if (HAS_BIAS) bv = b2f(bias[n]);
#pragma unroll
      for (int r = 0; r < 4; ++r) {
        const int m = m0 + wm + i * 16 + rg + r;
        float v = acc[i][j][r] + bv;
        if (ACT == ACT_SILU) v = v / (1.f + __expf(-v));
        if (ACT == ACT_PSILU) { if (n >= pn) v = v / (1.f + __expf(-v)); }
        if (ACT == ACT_SIGMOID) v = 1.f / (1.f + __expf(-v));
        if (ACT == ACT_GATE) {
          v = 1.f / (1.f + __expf(-v));
          const size_t e = (size_t)m * 1024 + n;
          const float xv = *flag ? b2f(((const bf16*)xsrc)[xoff + e])
                                 : ((const float*)xsrc)[xoff + e];
          v = v * b2f(ao[e]) + xv;
        }
        stf(&C[(size_t)m * ldc + n], v);
      }
    }
  }
}

// ---------------- pgemm: 256x128, BK=64, 8 waves, 8-phase-style schedule ----
// Per-wave 64x64 output (4Mx2N wave grid, acc[4][4]). 3 LDS buffers (144KB).
// Per K-tile: 2 fine phases (kk halves), each:
//   {8 ds_read ∥ issue 3 gl_lds(next-next tile) -> s_barrier -> lgkmcnt(0)
//    -> setprio(1) 16 MFMA setprio(0) -> s_barrier};
// vmcnt(6) ONLY at tile boundaries (vmcnt(0) only at the tail).
// LDS swizzle: slot group g' holds global group g'^(row&7); source col is
// inverse-swizzled (gl_lds dst linear), ds_read col applies the same XOR.
template <typename TC, int ACT, bool HAS_BIAS>
__global__ __launch_bounds__(512, 1) void pgemm(
    const bf16* __restrict__ Ab, const bf16* __restrict__ Bw,
    const bf16* __restrict__ bias, TC* __restrict__ C,
    int M, int N, int K, int lda, int ldc,
    const bf16* __restrict__ ao, const void* __restrict__ xsrc, size_t xoff,
    const int* __restrict__ flag, int pn)
{
  __shared__ short LA[3][256 * 64];
  __shared__ short LB[3][128 * 64];
  const short* A = (const short*)Ab;
  const short* B = (const short*)Bw;
  const int tid = threadIdx.x;
  const int m0 = blockIdx.x * 256, n0 = blockIdx.y * 128;
  const int wave = tid >> 6, lane = tid & 63;
  const int wm = (wave >> 1) * 64;   // 4 m-quadrants
  const int wn = (wave & 1) * 64;    // 2 n-halves
  const int fm = lane & 15;
  const int fq = lane >> 4;
  const int swz = fm & 7;

  const int srow = tid >> 3;                       // 64 rows / section
  const int sgrp = ((tid & 7) ^ (srow & 7)) * 8;   // inverse-swizzled src col
  const short* tA0 = A + (size_t)(m0 + srow) * lda + sgrp;
  const short* tA1 = A + (size_t)(m0 + 64 + srow) * lda + sgrp;
  const short* tA2 = A + (size_t)(m0 + 128 + srow) * lda + sgrp;
  const short* tA3 = A + (size_t)(m0 + 192 + srow) * lda + sgrp;
  const short* tB0 = B + (size_t)(n0 + srow) * K + sgrp;
  const short* tB1 = B + (size_t)(n0 + 64 + srow) * K + sgrp;

  f32x4 acc[4][4] = {};
  const int NT = K >> 6;

#define PSTG0(buf, k0)                                \
  do {                                                \
    gl_lds16(tA0 + (k0), &LA[buf][tid * 8]);          \
    gl_lds16(tA1 + (k0), &LA[buf][4096 + tid * 8]);   \
    gl_lds16(tA2 + (k0), &LA[buf][8192 + tid * 8]);   \
  } while (0)
#define PSTG1(buf, k0)                                \
  do {                                                \
    gl_lds16(tA3 + (k0), &LA[buf][12288 + tid * 8]);  \
    gl_lds16(tB0 + (k0), &LB[buf][tid * 8]);          \
    gl_lds16(tB1 + (k0), &LB[buf][4096 + tid * 8]);   \
  } while (0)

  PSTG0(0, 0);  PSTG1(0, 0);
  PSTG0(1, 64); PSTG1(1, 64);
  asm volatile("s_waitcnt vmcnt(6)" ::: "memory");   // tile 0 landed
  __builtin_amdgcn_s_barrier();

  for (int t = 0; t < NT; ++t) {
    const int buf = t % 3;
    const int nbuf = (t + 2) % 3;
    const bool stg = (t + 2) < NT;
    const short* la = &LA[buf][0];
    const short* lb = &LB[buf][0];
    const int k2 = (t + 2) * 64;

    // ---- phase 0 (kk = 0): groups fq ----
    {
      bf16x8 af[4], bfr[4];
      const int sw = (fq ^ swz) * 8;
#pragma unroll
      for (int i = 0; i < 4; ++i)
        af[i] = *(const bf16x8*)&la[(wm + i * 16 + fm) * 64 + sw];
#pragma unroll
      for (int j = 0; j < 4; ++j)
        bfr[j] = *(const bf16x8*)&lb[(wn + j * 16 + fm) * 64 + sw];
      if (stg) PSTG0(nbuf, k2);
      __builtin_amdgcn_s_barrier();
      asm volatile("s_waitcnt lgkmcnt(0)" ::: "memory");
      __builtin_amdgcn_s_setprio(1);
#pragma unroll
      for (int i = 0; i < 4; ++i)
#pragma unroll
        for (int j = 0; j < 4; ++j)
          acc[i][j] = __builtin_amdgcn_mfma_f32_16x16x32_bf16(af[i], bfr[j], acc[i][j], 0, 0, 0);
      __builtin_amdgcn_s_setprio(0);
      __builtin_amdgcn_s_barrier();
    }
    // ---- phase 1 (kk = 1): groups 4 + fq ----
    {
      bf16x8 af[4], bfr[4];
      const int sw = ((4 + fq) ^ swz) * 8;
#pragma unroll
      for (int i = 0; i < 4; ++i)
        af[i] = *(const bf16x8*)&la[(wm + i * 16 + fm) * 64 + sw];
#pragma unroll
      for (int j = 0; j < 4; ++j)
        bfr[j] = *(const bf16x8*)&lb[(wn + j * 16 + fm) * 64 + sw];
      if (stg) PSTG1(nbuf, k2);
      __builtin_amdgcn_s_barrier();
      asm volatile("s_waitcnt lgkmcnt(0)" ::: "memory");
      __builtin_amdgcn_s_setprio(1);
#pragma unroll
      for (int i = 0; i < 4; ++i)
#pragma unroll
        for (int j = 0; j < 4; ++j)
          acc[i][j] = __builtin_amdgcn_mfma_f32_16x16x32_bf16(af[i], bfr[j], acc[i][j], 0, 0, 0);
      __builtin_amdgcn_s_setprio(0);
      if (t + 1 < NT) {
        if (stg) asm volatile("s_waitcnt vmcnt(6)" ::: "memory");
        else     asm volatile("s_waitcnt vmcnt(0)" ::: "memory");
      }
      __builtin_amdgcn_s_barrier();
    }
  }
#undef PSTG0
#undef PSTG1

#pragma unroll
  for (int i = 0; i < 4; ++i) {
#pragma unroll
    for (int j = 0; j < 4; ++j) {
      const int n = n0 + wn + j * 16 + fm;
      float bv = 0.f;
      if (HAS_BIAS) bv = b2f(bias[n]);
#pragma unroll
      for (int r = 0; r < 4; ++r) {
        const int m = m0 + wm + i * 16 + fq * 4 + r;
        float v = acc[i][j][r] + bv;
        if (ACT == ACT_SILU) v = v / (1.f + __expf(-v));
        if (ACT == ACT_PSILU) { if (n >= pn) v = v / (1.f + __expf(-v)); }
        if (ACT == ACT_SIGMOID) v = 1.f / (1.f + __expf(-v));
        if (ACT == ACT_GATE) {
          v = 1.f / (1.f + __expf(-v));
          const size_t e = (size_t)m * 1024 + n;
          const float xv = *flag ? b2f(((const bf16*)xsrc)[xoff + e])
                                 : ((const float*)xsrc)[xoff + e];
          v = v * b2f(ao[e]) + xv;
        }
        stf(&C[(size_t)m * ldc + n], v);
      }
    }
  }
}

// ---- K-split fold GEMM (preamble): P[z] = A @ B^T over K-slice z (KS=4) ----
__global__ __launch_bounds__(256) void kgemm(
    const bf16* __restrict__ Ab, const bf16* __restrict__ Bw,
    float* __restrict__ P, int M, int N, int K, int lda)
{
  __shared__ short As[128 * 32];
  __shared__ short Bs[128 * 32];
  const short* A = (const short*)Ab;
  const short* B = (const short*)Bw;
  const int tid = threadIdx.x;
  const int m0 = blockIdx.x * 128, n0 = blockIdx.y * 128;
  const int kb = blockIdx.z * (K >> 2), ke = kb + (K >> 2);
  const int wave = tid >> 6, lane = tid & 63;
  const int wm = (wave & 1) * 64, wn = (wave >> 1) * 64;
  const int fm = lane & 15;
  const int fk = (lane >> 4) * 8;

  const int srow = tid >> 2, scol = (tid & 3) * 8;
  const short* gA0 = A + (size_t)(m0 + srow) * lda + scol;
  const short* gA1 = A + (size_t)(m0 + 64 + srow) * lda + scol;
  const short* gB0 = B + (size_t)(n0 + srow) * K + scol;
  const short* gB1 = B + (size_t)(n0 + 64 + srow) * K + scol;
  short* lA0 = As + tid * 8;
  short* lA1 = As + (256 + tid) * 8;
  short* lB0 = Bs + tid * 8;
  short* lB1 = Bs + (256 + tid) * 8;

  f32x4 acc[4][4] = {};

  for (int k0 = kb; k0 < ke; k0 += 32) {
    gl_lds16(gA0 + k0, lA0);
    gl_lds16(gA1 + k0, lA1);
    gl_lds16(gB0 + k0, lB0);
    gl_lds16(gB1 + k0, lB1);
    __syncthreads();
    bf16x8 af[4], bfr[4];
#pragma unroll
    for (int i = 0; i < 4; ++i)
      af[i] = *(const bf16x8*)&As[(wm + i * 16 + fm) * 32 + fk];
#pragma unroll
    for (int j = 0; j < 4; ++j)
      bfr[j] = *(const bf16x8*)&Bs[(wn + j * 16 + fm) * 32 + fk];
#pragma unroll
    for (int i = 0; i < 4; ++i)
#pragma unroll
      for (int j = 0; j < 4; ++j)
        acc[i][j] = __builtin_amdgcn_mfma_f32_16x16x32_bf16(af[i], bfr[j], acc[i][j], 0, 0, 0);
    __syncthreads();
  }

  float* Cp = P + (size_t)blockIdx.z * ((size_t)M * N);
  const int rg = (lane >> 4) * 4;
#pragma unroll
  for (int i = 0; i < 4; ++i)
#pragma unroll
    for (int j = 0; j < 4; ++j) {
      const int n = n0 + wn + j * 16 + fm;
#pragma unroll
      for (int r = 0; r < 4; ++r) {
        const int m = m0 + wm + i * 16 + rg + r;
        Cp[(size_t)m * N + n] = acc[i][j][r];
      }
    }
}

// sum 4 K-slice partials -> bf16
__global__ __launch_bounds__(256) void foldfin_kernel(
    const float* __restrict__ P, bf16* __restrict__ o, int MN) {
  int i = blockIdx.x * 256 + threadIdx.x;
  if (i >= MN) return;
  float s = P[i] + P[i + (size_t)MN] + P[i + 2 * (size_t)MN] + P[i + 3 * (size_t)MN];
  o[i] = __float2bfloat16(s);
}

// Row LayerNorm over width W; optional post-LN add of a bf16 vector.
template <typename TI, typename TO, bool ADD, int W, int BS>
__global__ __launch_bounds__(BS) void ln_kernel(
    const TI* __restrict__ in, const bf16* __restrict__ g, const bf16* __restrict__ b,
    const bf16* __restrict__ addv, TO* __restrict__ out, int ldin)
{
  __shared__ float red[BS];
  const int row = blockIdx.x;
  const TI* rin = in + (size_t)row * ldin;
  TO* rout = out + (size_t)row * W;
  const int NP = W / BS;
  float v[NP];
  float s = 0.f;
#pragma unroll
  for (int i = 0; i < NP; ++i) { v[i] = ldf(&rin[threadIdx.x + i * BS]); s += v[i]; }
  red[threadIdx.x] = s; __syncthreads();
  for (int o = BS / 2; o > 0; o >>= 1) {
    if (threadIdx.x < o) red[threadIdx.x] += red[threadIdx.x + o];
    __syncthreads();
  }
  const float mean = red[0] / W;
  __syncthreads();
  float sq = 0.f;
#pragma unroll
  for (int i = 0; i < NP; ++i) { float d = v[i] - mean; sq += d * d; }
  red[threadIdx.x] = sq; __syncthreads();
  for (int o = BS / 2; o > 0; o >>= 1) {
    if (threadIdx.x < o) red[threadIdx.x] += red[threadIdx.x + o];
    __syncthreads();
  }
  const float rstd = rsqrtf(red[0] / W + 1e-5f);
#pragma unroll
  for (int i = 0; i < NP; ++i) {
    int c = threadIdx.x + i * BS;
    float o_ = (v[i] - mean) * rstd * b2f(g[c]) + b2f(b[c]);
    if (ADD) o_ += b2f(addv[c]);
    stf(&rout[c], o_);
  }
}

// ---------------- MFMA attention (XCD-chunked bid swizzle) ------------------
__global__ __launch_bounds__(512) void attn_kernel(
    const bf16* __restrict__ qg, int str_q,
    const bf16* __restrict__ krv, int str_r,
    const bf16* __restrict__ kxv, int str_x, const bf16* __restrict__ kpg,
    const bf16* __restrict__ vpg, bf16* __restrict__ outg)
{
  __shared__ short qs[4 * 64 * 32];
  __shared__ short ksl[4 * 144 * 32];
  __shared__ short vt[128 * 168];
  __shared__ short pl[64 * 168];

  const int tid = threadIdx.x;
  unsigned bid = blockIdx.x;
  {
    const unsigned nwg = gridDim.x;
    const unsigned q_ = nwg >> 3, r_ = nwg & 7;
    const unsigned xcd = bid & 7, loc = bid >> 3;
    bid = (xcd < r_ ? xcd * (q_ + 1) : r_ * (q_ + 1) + (xcd - r_) * q_) + loc;
  }
  const int seg = (int)(bid >> 3), h = (int)(bid & 7);
  const unsigned short* q = (const unsigned short*)qg + (size_t)seg * 64 * str_q + h * 128;
  const unsigned short* kv_r = (const unsigned short*)krv + (size_t)seg * 64 * str_r + h * 128;
  const unsigned short* kv_x = (const unsigned short*)kxv + (size_t)seg * 64 * str_x + h * 128;
  const unsigned short* kp = (const unsigned short*)kpg;
  const unsigned short* vp = (const unsigned short*)vpg;
  const size_t obase = (size_t)seg * 64 * 1024 + h * 128;

  for (int ch = tid; ch < 64 * 16; ch += 512) {
    int row = ch >> 4, k8 = ch & 15;
    uint4 v = *(const uint4*)(q + (size_t)row * str_q + k8 * 8);
    *(uint4*)&qs[((k8 >> 2) * 64 + row) * 32 + (k8 & 3) * 8] = v;
  }
  for (int ch = tid; ch < 132 * 16; ch += 512) {
    int t = ch >> 4, k8 = ch & 15;
    const unsigned short* src;
    if (t < 64) src = kv_r + (size_t)t * str_r;
    else if (t < 68) src = kp + (size_t)(t - 64) * 1024 + h * 128;
    else src = kv_x + (size_t)(t - 68) * str_x;
    uint4 v = *(const uint4*)(src + k8 * 8);
    *(uint4*)&ksl[((k8 >> 2) * 144 + t) * 32 + (k8 & 3) * 8] = v;
  }
  __syncthreads();

  const int wave = tid >> 6, lane = tid & 63;
  const int fm = lane & 15, fq = lane >> 4;

  if (wave < 4) {
    const int s0 = wave * 16;
    f32x4 acc[10];
#pragma unroll
    for (int tt = 0; tt < 10; ++tt) acc[tt] = (f32x4){0.f, 0.f, 0.f, 0.f};
#pragma unroll
    for (int kb = 0; kb < 4; ++kb) {
      const bf16x8 a = *(const bf16x8*)&qs[(kb * 64 + s0 + fm) * 32 + fq * 8];
#pragma unroll
      for (int tt = 0; tt < 9; ++tt) {
        const bf16x8 b = *(const bf16x8*)&ksl[(kb * 144 + tt * 16 + fm) * 32 + fq * 8];
        acc[tt] = __builtin_amdgcn_mfma_f32_16x16x32_bf16(a, b, acc[tt], 0, 0, 0);
      }
    }
    const float scale = 0.08838834764831845f;
#pragma unroll
    for (int r = 0; r < 4; ++r) {
      float m = -3.0e38f;
#pragma unroll
      for (int tt = 0; tt < 9; ++tt) {
        int t = tt * 16 + fm;
        if (t < 132) m = fmaxf(m, acc[tt][r] * scale);
      }
      for (int d = 1; d < 16; d <<= 1) m = fmaxf(m, __shfl_xor(m, d));
      float e[10];
      float sum = 0.f;
#pragma unroll
      for (int tt = 0; tt < 10; ++tt) {
        int t = tt * 16 + fm;
        float ev = 0.f;
        if (t < 132) ev = __expf(acc[tt][r] * scale - m);
        e[tt] = ev; sum += ev;
      }
      for (int d = 1; d < 16; d <<= 1) sum += __shfl_xor(sum, d);
      const float inv = 1.f / sum;
      const int s = s0 + fq * 4 + r;
#pragma unroll
      for (int tt = 0; tt < 10; ++tt) {
        bf16 pv = __float2bfloat16(e[tt] * inv);
        pl[s * 168 + tt * 16 + fm] = *(const short*)&pv;
      }
    }
  } else {
    for (int ch = tid - 256; ch < 132 * 32; ch += 256) {
      int t = ch >> 5, d4 = (ch & 31) * 4;
      const unsigned short* src;
      if (t < 64) src = kv_r + 1024 + (size_t)t * str_r;
      else if (t < 68) src = vp + (size_t)(t - 64) * 1024 + h * 128;
      else src = kv_x + 1024 + (size_t)(t - 68) * str_x;
      uint2 w = *(const uint2*)(src + d4);
      vt[(d4 + 0) * 168 + t] = (short)(w.x & 0xffffu);
      vt[(d4 + 1) * 168 + t] = (short)(w.x >> 16);
      vt[(d4 + 2) * 168 + t] = (short)(w.y & 0xffffu);
      vt[(d4 + 3) * 168 + t] = (short)(w.y >> 16);
    }
    for (int ch = tid - 256; ch < 128 * 32; ch += 256) {
      int d = ch >> 5, tp = 132 + (ch & 31);
      vt[d * 168 + tp] = 0;
    }
  }
  __syncthreads();

  const int dt = wave;
  bf16x8 af[5];
#pragma unroll
  for (int kb = 0; kb < 5; ++kb)
    af[kb] = *(const bf16x8*)&vt[(dt * 16 + fm) * 168 + kb * 32 + fq * 8];
#pragma unroll
  for (int st = 0; st < 4; ++st) {
    f32x4 o = (f32x4){0.f, 0.f, 0.f, 0.f};
#pragma unroll
    for (int kb = 0; kb < 5; ++kb) {
      const bf16x8 bp = *(const bf16x8*)&pl[(st * 16 + fm) * 168 + kb * 32 + fq * 8];
      o = __builtin_amdgcn_mfma_f32_16x16x32_bf16(af[kb], bp, o, 0, 0, 0);
    }
    const int s = st * 16 + fm;
    bf16 b0 = __float2bfloat16(o[0]), b1 = __float2bfloat16(o[1]);
    bf16 b2 = __float2bfloat16(o[2]), b3 = __float2bfloat16(o[3]);
    uint2 w;
    w.x = ((unsigned)(*(unsigned short*)&b1) << 16) | (*(unsigned short*)&b0);
    w.y = ((unsigned)(*(unsigned short*)&b3) << 16) | (*(unsigned short*)&b2);
    *(uint2*)((unsigned short*)outg + obase + (size_t)s * 1024 + dt * 16 + fq * 4) = w;
  }
}

extern "C" void kernel_launch(void* const* d_in, const int* in_sizes, int n_in,
                              void* d_out, int out_size, void* d_ws, size_t ws_size,
                              hipStream_t stream)
{
  (void)n_in; (void)out_size;
  const int R = 16384, Cd = 1024;

  char* ws = (char*)d_ws;
  size_t off = 0;
  auto alloc = [&](size_t bytes) -> void* {
    void* p = ws + off;
    off += (bytes + 255) & ~(size_t)255;
    return p;
  };

  int* flag = (int*)alloc(256);
  // packed x-projection weights [Wkk | Wvv | Wqq | Wm1] rows (3200 x 1024)
  bf16* W4    = (bf16*)alloc((size_t)3200 * Cd * sizeof(bf16));
  bf16* bias4 = (bf16*)alloc(3200 * sizeof(bf16));
  bf16* T     = (bf16*)alloc((size_t)Cd * Cd * sizeof(bf16));  // transpose scratch
  bf16* Wc    = (bf16*)alloc((size_t)2048 * 128 * sizeof(bf16));
  bf16* kp    = (bf16*)alloc((size_t)4 * Cd * sizeof(bf16));
  bf16* vp    = (bf16*)alloc((size_t)4 * Cd * sizeof(bf16));
  bf16* bkv   = (bf16*)alloc(2048 * sizeof(bf16));
  bf16* WqStk = (bf16*)alloc((size_t)1152 * Cd * sizeof(bf16)); // [mhaWq; mem_W1]
  bf16* nb[30];
  nb[0] = nullptr;
  for (int i = 1; i < 30; ++i) nb[i] = (bf16*)alloc((size_t)in_sizes[i] * sizeof(bf16));
  nb[16] = WqStk;                          // mhaWq -> rows 0..1023 of stack
  nb[5]  = WqStk + (size_t)1024 * Cd;      // mem_W1 -> rows 1024..1151
  const size_t fixed_end = off;

  // balanced chunk sizing; per-row scratch = 17152 B
  size_t avail = (ws_size > fixed_end + (1u << 20)) ? (ws_size - fixed_end - (1u << 20)) : 0;
  int crmax = (int)(avail / 17152);
  if (crmax > R) crmax = R;
  if (crmax < 128) crmax = 128;
  int nch = (R + crmax - 1) / crmax;
  int CR = ((R / nch + 127) / 128) * 128;
  while (CR * nch < R) CR += 128;

  const size_t chunk_start = off;
  const size_t RB = (size_t)CR * Cd * sizeof(bf16);
  bf16* Xc  = (bf16*)alloc(RB);                               // x(bf16) -> attn out
  bf16* QS4 = (bf16*)alloc((size_t)CR * 3200 * sizeof(bf16)); // [k_x|v_x|q|h1]
  bf16* h1b = (bf16*)alloc((size_t)CR * 128 * sizeof(bf16));
  bf16* h2b = (bf16*)alloc((size_t)CR * 128 * sizeof(bf16));
  bf16* Bb  = (bf16*)alloc(RB);                               // ao
  bf16* KVr = (bf16*)alloc(2 * RB);                           // [k_r | v_r]
  bf16* Cc  = (bf16*)alloc(RB);                               // gin
  const size_t chunk_bytes = off - chunk_start;

  dim3 blk(256);
  // grid = (Mt, Nt): m-tile fastest -> xcd = m_tile % 8 fixed
  auto g128 = [](int M_, int N_) { return dim3((unsigned)(M_ / 128), (unsigned)(N_ / 128)); };
  auto g256 = [](int M_, int N_) { return dim3((unsigned)(M_ / 256), (unsigned)(N_ / 128)); };

  // ---- preamble ----
  detect_kernel<<<1, 64, 0, stream>>>((const unsigned short*)d_in[24], flag);
  {
    ConvArgs a;
    int bs = 0;
    for (int i = 1; i < 30; ++i) {
      a.src[i - 1] = d_in[i];
      a.dst[i - 1] = nb[i];
      a.n[i - 1] = in_sizes[i];
      a.bstart[i - 1] = bs;
      bs += (in_sizes[i] + 255) / 256;
    }
    a.bstart[29] = bs;
    convall_kernel<<<dim3((unsigned)bs), blk, 0, stream>>>(a, flag);
  }
  const bf16 *pm = nb[1], *Wq = nb[2], *Wk = nb[3], *Wv = nb[4];
  const bf16 *mem_W1 = nb[5], *mem_b1 = nb[6], *ln1g = nb[7], *ln1b = nb[8];
  const bf16 *mem_W2 = nb[9], *mem_b2 = nb[10], *ln2g = nb[11], *ln2b = nb[12];
  const bf16 *mem_oW = nb[13], *mem_ob = nb[14], *mstate = nb[15];
  const bf16 *mhaWq = nb[16], *mhabq = nb[17], *mhaWk = nb[18], *mhabk = nb[19];
  const bf16 *mhaWv = nb[20], *mhabv = nb[21], *mhaWo = nb[22], *mhabo = nb[23];
  const bf16 *gn_g = nb[24], *gn_b = nb[25], *gateW = nb[26], *gateb = nb[27];
  const bf16 *outW = nb[28], *outb = nb[29];
  bf16* Wkk = W4;
  bf16* Wvv = W4 + (size_t)1024 * Cd;
  bf16* Wqq = W4 + (size_t)2048 * Cd;
  bf16* Wm1 = W4 + (size_t)3072 * Cd;

  // weight folds
  const bool use_ks = chunk_bytes >= (size_t)4 * 1152 * 1024 * sizeof(float);
  if (use_ks) {
    float* P = (float*)Xc;  // aliases dead chunk scratch
    transpose_kernel<<<dim3(16, 16), blk, 0, stream>>>(Wq, T, 1024, 1024);
    kgemm<<<dim3(9, 8, 4), blk, 0, stream>>>(WqStk, T, P, 1152, 1024, 1024, 1024);
    foldfin_kernel<<<dim3(4608), blk, 0, stream>>>(P, Wqq, 1152 * 1024);
    transpose_kernel<<<dim3(16, 16), blk, 0, stream>>>(Wk, T, 1024, 1024);
    kgemm<<<dim3(8, 8, 4), blk, 0, stream>>>(mhaWk, T, P, 1024, 1024, 1024, 1024);
    foldfin_kernel<<<dim3(4096), blk, 0, stream>>>(P, Wkk, 1024 * 1024);
    transpose_kernel<<<dim3(16, 16), blk, 0, stream>>>(Wv, T, 1024, 1024);
    kgemm<<<dim3(8, 8, 4), blk, 0, stream>>>(mhaWv, T, P, 1024, 1024, 1024, 1024);
    foldfin_kernel<<<dim3(4096), blk, 0, stream>>>(P, Wvv, 1024 * 1024);
    transpose_kernel<<<dim3(2, 16), blk, 0, stream>>>(mem_oW, T, 1024, 128);
    kgemm<<<dim3(16, 1, 4), blk, 0, stream>>>(W4, T, P, 2048, 128, 1024, 1024);
    foldfin_kernel<<<dim3(1024), blk, 0, stream>>>(P, Wc, 2048 * 128);
  } else {
    transpose_kernel<<<dim3(16, 16), blk, 0, stream>>>(Wq, T, 1024, 1024);
    mgemm<bf16, ACT_NONE, false><<<g128(1024, 1024), blk, 0, stream>>>(
        mhaWq, T, nullptr, Wqq, 1024, 1024, 1024, 1024, 1024, nullptr, nullptr, 0, nullptr, 0);
    mgemm<bf16, ACT_NONE, false><<<g128(128, 1024), blk, 0, stream>>>(
        mem_W1, T, nullptr, Wm1, 128, 1024, 1024, 1024, 1024, nullptr, nullptr, 0, nullptr, 0);
    transpose_kernel<<<dim3(16, 16), blk, 0, stream>>>(Wk, T, 1024, 1024);
    mgemm<bf16, ACT_NONE, false><<<g128(1024, 1024), blk, 0, stream>>>(
        mhaWk, T, nullptr, Wkk, 1024, 1024, 1024, 1024, 1024, nullptr, nullptr, 0, nullptr, 0);
    transpose_kernel<<<dim3(16, 16), blk, 0, stream>>>(Wv, T, 1024, 1024);
    mgemm<bf16, ACT_NONE, false><<<g128(1024, 1024), blk, 0, stream>>>(
        mhaWv, T, nullptr, Wvv, 1024, 1024, 1024, 1024, 1024, nullptr, nullptr, 0, nullptr, 0);
    transpose_kernel<<<dim3(2, 16), blk, 0, stream>>>(mem_oW, T, 1024, 128);
    mgemm<bf16, ACT_NONE, false><<<g128(2048, 128), blk, 0, stream>>>(
        W4, T, nullptr, Wc, 2048, 128, 1024, 1024, 128, nullptr, nullptr, 0, nullptr, 0);
  }
  pack_bias4<<<13, blk, 0, stream>>>(mhabk, mhabv, mhabq, mem_b1, bias4);
  kpvp_kernel<<<dim3(512), blk, 0, stream>>>(pm, mem_ob, W4, bias4, kp, vp, bkv);

  for (int r0 = 0; r0 < R; r0 += CR) {
    const int cr = (R - r0 < CR) ? (R - r0) : CR;
    const int n = cr * Cd;
    const bool big = (cr % 256) == 0;
    conv_kernel<<<dim3((n / 8 + 255) / 256), blk, 0, stream>>>(
        d_in[0], Xc, n, (size_t)r0 * Cd, flag);

    // packed x-projection: [k_x | v_x | q | h1=silu(...)]
    if (big)
      pgemm<bf16, ACT_PSILU, true><<<g256(cr, 3200), dim3(512), 0, stream>>>(
          Xc, W4, bias4, QS4, cr, 3200, 1024, 1024, 3200, nullptr, nullptr, 0, nullptr, 3072);
    else
      mgemm<bf16, ACT_PSILU, true><<<g128(cr, 3200), blk, 0, stream>>>(
          Xc, W4, bias4, QS4, cr, 3200, 1024, 1024, 3200, nullptr, nullptr, 0, nullptr, 3072);

    // memory net tail: ln1 -> W2 -> ln2(+mstate) -> folded KVr (K=128)
    ln_kernel<bf16, bf16, false, 128, 128><<<cr, 128, 0, stream>>>(
        QS4 + 3072, ln1g, ln1b, nullptr, h2b, 3200);
    mgemm<bf16, ACT_NONE, true><<<g128(cr, 128), blk, 0, stream>>>(
        h2b, mem_W2, mem_b2, h1b, cr, 128, 128, 128, 128, nullptr, nullptr, 0, nullptr, 0);
    ln_kernel<bf16, bf16, true, 128, 128><<<cr, 128, 0, stream>>>(h1b, ln2g, ln2b, mstate, h2b, 128);
    mgemm<bf16, ACT_NONE, true><<<g128(cr, 2048), blk, 0, stream>>>(
        h2b, Wc, bkv, KVr, cr, 2048, 128, 128, 2048, nullptr, nullptr, 0, nullptr, 0);

    attn_kernel<<<dim3((cr / 64) * 8), dim3(512), 0, stream>>>(
        QS4 + 2048, 3200, KVr, 2048, QS4, 3200, kp, vp, Xc);

    // ao, gate-norm, fused gate*ao+x, final projection
    if (big)
      pgemm<bf16, ACT_NONE, true><<<g256(cr, Cd), dim3(512), 0, stream>>>(
          Xc, mhaWo, mhabo, Bb, cr, Cd, Cd, Cd, Cd, nullptr, nullptr, 0, nullptr, 0);
    else
      mgemm<bf16, ACT_NONE, true><<<g128(cr, Cd), blk, 0, stream>>>(
          Xc, mhaWo, mhabo, Bb, cr, Cd, Cd, Cd, Cd, nullptr, nullptr, 0, nullptr, 0);
    ln_kernel<bf16, bf16, false, 1024, 256><<<cr, 256, 0, stream>>>(Bb, gn_g, gn_b, nullptr, Cc, Cd);
    if (big) {
      pgemm<bf16, ACT_GATE, true><<<g256(cr, Cd), dim3(512), 0, stream>>>(
          Cc, gateW, gateb, Xc, cr, Cd, Cd, Cd, Cd, Bb, d_in[0], (size_t)r0 * Cd, flag, 0);
      pgemm<float, ACT_NONE, true><<<g256(cr, Cd), dim3(512), 0, stream>>>(
          Xc, outW, outb, (float*)d_out + (size_t)r0 * Cd, cr, Cd, Cd, Cd, Cd,
          nullptr, nullptr, 0, nullptr, 0);
    } else {
      mgemm<bf16, ACT_GATE, true><<<g128(cr, Cd), blk, 0, stream>>>(
          Cc, gateW, gateb, Xc, cr, Cd, Cd, Cd, Cd, Bb, d_in[0], (size_t)r0 * Cd, flag, 0);
      mgemm<float, ACT_NONE, true><<<g128(cr, Cd), blk, 0, stream>>>(
          Xc, outW, outb, (float*)d_out + (size_t)r0 * Cd, cr, Cd, Cd, Cd, Cd,
          nullptr, nullptr, 0, nullptr, 0);
    }
  }
}